// Round 7
// baseline (649.053 us; speedup 1.0000x reference)
//
#include <hip/hip_runtime.h>
#include <hip/hip_bf16.h>

// ---------------------------------------------------------------------------
// DepthDeltaNetDecoderLayer: B=1, T=2048, D=1024, H=16, DK=DV=64, FF=4096
// Round 6:
//  (1) phaseB rewrite: 16 blocks/4 waves/barriers -> 64 single-wave blocks
//      (4x v-slice parallelism; rows of S^T evolve independently), zero
//      barriers, register-prefetched Ac/Bc double buffer. Same FMA order.
//  (2) GEMM staging via __builtin_amdgcn_global_load_lds width=16 (m97
//      recipe; lane-linear LDS dest, barrier provides vmcnt drain).
// ---------------------------------------------------------------------------

#define T_SEQ 2048
#define D_MODEL 1024
#define NH 16
#define DK 64
#define DV 64
#define FF 4096
#define NQKV 4224   // q(1024) k(1024) v(1024) gate(1024) g(16@4096) b(16@4112) pad->4224
#define LP 72       // padded LDS stride (shorts) for 64x64 bf16 operand tiles
#define MP 68       // padded stride (floats) for M^T: 16B-aligned rows

typedef __bf16 bf16x8 __attribute__((ext_vector_type(8)));
typedef float  fx4    __attribute__((ext_vector_type(4)));

#if defined(__has_builtin)
#if __has_builtin(__builtin_amdgcn_global_load_lds)
#define HAVE_GLOAD_LDS 1
#endif
#endif

#ifdef HAVE_GLOAD_LDS
#define ASYNC_LDS16(dst, src)                                                   \
    __builtin_amdgcn_global_load_lds(                                           \
        (__attribute__((address_space(1))) void*)(src),                         \
        (__attribute__((address_space(3))) void*)(dst), 16, 0, 0)
#else
#define ASYNC_LDS16(dst, src) (*(int4*)(dst) = *(const int4*)(src))
#endif

// ---------------------------------------------------------------- rope table
__global__ void rope_table_kernel(float2* __restrict__ cs) {
    int idx = blockIdx.x * 256 + threadIdx.x;      // t*32 + i, 65536 total
    int t = idx >> 5, i = idx & 31;
    float freq = (float)t * powf(10000.f, -(float)i / 32.f);
    cs[idx] = make_float2(cosf(freq), sinf(freq));
}

// --------------------------------------- row rmsnorm -> bf16 hi + bf16 lo
__global__ __launch_bounds__(256) void rmsnorm_split_kernel(
    const float* __restrict__ in, const float* __restrict__ w,
    __hip_bfloat16* __restrict__ hi, __hip_bfloat16* __restrict__ lo) {
    int t = blockIdx.x;
    int d = threadIdx.x * 4;
    const float4 v = *(const float4*)(in + (size_t)t * D_MODEL + d);
    float ss = v.x * v.x + v.y * v.y + v.z * v.z + v.w * v.w;
#pragma unroll
    for (int m = 32; m; m >>= 1) ss += __shfl_xor(ss, m, 64);
    __shared__ float wsum[4];
    if ((threadIdx.x & 63) == 0) wsum[threadIdx.x >> 6] = ss;
    __syncthreads();
    float tot = wsum[0] + wsum[1] + wsum[2] + wsum[3];
    float sc = rsqrtf(tot * (1.f / 1024.f) + 1e-6f);
    const float4 wv = *(const float4*)(w + d);
    float xs[4] = {v.x * sc * wv.x, v.y * sc * wv.y, v.z * sc * wv.z, v.w * sc * wv.w};
    __hip_bfloat16* hp = hi + (size_t)t * D_MODEL + d;
    __hip_bfloat16* lp = lo + (size_t)t * D_MODEL + d;
#pragma unroll
    for (int j = 0; j < 4; ++j) {
        __hip_bfloat16 h = __float2bfloat16(xs[j]);
        hp[j] = h;
        lp[j] = __float2bfloat16(xs[j] - __bfloat162float(h));
    }
}

// ------------------------------------------- W (KxN f32) -> Wt (Npad x K bf16)
__global__ void transpose_bf16_kernel(const float* __restrict__ W,
                                      __hip_bfloat16* __restrict__ Wt,
                                      int K, int N, int Npad) {
    __shared__ float tile[32][33];
    int k0 = blockIdx.x * 32, n0 = blockIdx.y * 32;
    int tx = threadIdx.x, ty = threadIdx.y;   // (32,8)
#pragma unroll
    for (int i = 0; i < 32; i += 8) {
        int n = n0 + tx;
        tile[ty + i][tx] = (n < N) ? W[(size_t)(k0 + ty + i) * N + n] : 0.f;
    }
    __syncthreads();
#pragma unroll
    for (int i = 0; i < 32; i += 8) {
        int n = n0 + ty + i;
        if (n < Npad) Wt[(size_t)n * K + k0 + tx] = __float2bfloat16(tile[tx][ty + i]);
    }
}

// ---------------------- W (KxN f32) -> Wt_hi, Wt_lo (Npad x K bf16 each)
__global__ void transpose_split_kernel(const float* __restrict__ W,
                                       __hip_bfloat16* __restrict__ Wt_hi,
                                       __hip_bfloat16* __restrict__ Wt_lo,
                                       int K, int N, int Npad) {
    __shared__ float tile[32][33];
    int k0 = blockIdx.x * 32, n0 = blockIdx.y * 32;
    int tx = threadIdx.x, ty = threadIdx.y;   // (32,8)
#pragma unroll
    for (int i = 0; i < 32; i += 8) {
        int n = n0 + tx;
        tile[ty + i][tx] = (n < N) ? W[(size_t)(k0 + ty + i) * N + n] : 0.f;
    }
    __syncthreads();
#pragma unroll
    for (int i = 0; i < 32; i += 8) {
        int n = n0 + ty + i;
        if (n < Npad) {
            float x = tile[tx][ty + i];
            __hip_bfloat16 h = __float2bfloat16(x);
            Wt_hi[(size_t)n * K + k0 + tx] = h;
            Wt_lo[(size_t)n * K + k0 + tx] = __float2bfloat16(x - __bfloat162float(h));
        }
    }
}

// ------------------------------------------------------------------- GEMM
// A: MxK bf16 row-major; Bt: NxK bf16 row-major (B transposed); C: MxN.
template <bool OUT_BF16>
__global__ __launch_bounds__(256) void gemm_bt(
    const __hip_bfloat16* __restrict__ A, const __hip_bfloat16* __restrict__ Bt,
    void* __restrict__ Cout, int M, int N, int K) {
    __shared__ short sA[128 * 32];
    __shared__ short sB[128 * 32];
    const int tid = threadIdx.x;
    const int w = tid >> 6, lane = tid & 63;
    const int bn0 = blockIdx.x * 128, bm0 = blockIdx.y * 128;
    const int wr = w >> 1, wc = w & 1;

    fx4 acc[4][4];
#pragma unroll
    for (int m = 0; m < 4; ++m)
#pragma unroll
        for (int n = 0; n < 4; ++n) acc[m][n] = {0.f, 0.f, 0.f, 0.f};

    for (int k0 = 0; k0 < K; k0 += 32) {
        __syncthreads();
#pragma unroll
        for (int i = 0; i < 2; ++i) {
            int c = i * 256 + tid;
            int r = c >> 2, kk = (c & 3) * 8;
            ASYNC_LDS16(sA + c * 8, A + (size_t)(bm0 + r) * K + k0 + kk);
            ASYNC_LDS16(sB + c * 8, Bt + (size_t)(bn0 + r) * K + k0 + kk);
        }
        __syncthreads();
        bf16x8 af[4], bfv[4];
#pragma unroll
        for (int m = 0; m < 4; ++m)
            af[m] = *(const bf16x8*)(sA + (wr * 64 + m * 16 + (lane & 15)) * 32 + (lane >> 4) * 8);
#pragma unroll
        for (int n = 0; n < 4; ++n)
            bfv[n] = *(const bf16x8*)(sB + (wc * 64 + n * 16 + (lane & 15)) * 32 + (lane >> 4) * 8);
#pragma unroll
        for (int m = 0; m < 4; ++m)
#pragma unroll
            for (int n = 0; n < 4; ++n)
                acc[m][n] = __builtin_amdgcn_mfma_f32_16x16x32_bf16(af[m], bfv[n], acc[m][n], 0, 0, 0);
    }
#pragma unroll
    for (int m = 0; m < 4; ++m) {
        int row = bm0 + wr * 64 + m * 16 + (lane >> 4) * 4;
#pragma unroll
        for (int n = 0; n < 4; ++n) {
            int col = bn0 + wc * 64 + n * 16 + (lane & 15);
#pragma unroll
            for (int j = 0; j < 4; ++j) {
                float val = acc[m][n][j];
                if (OUT_BF16)
                    ((__hip_bfloat16*)Cout)[(size_t)(row + j) * N + col] = __float2bfloat16(val);
                else
                    ((float*)Cout)[(size_t)(row + j) * N + col] = val;
            }
        }
    }
}

// ------------------------------------- split-precision GEMM (3 bf16 products)
__global__ __launch_bounds__(256) void gemm_bt_split(
    const __hip_bfloat16* __restrict__ Ah, const __hip_bfloat16* __restrict__ Al,
    const __hip_bfloat16* __restrict__ Bth, const __hip_bfloat16* __restrict__ Btl,
    float* __restrict__ Cout, int M, int N, int K) {
    __shared__ short sAh[128 * 32];
    __shared__ short sAl[128 * 32];
    __shared__ short sBh[128 * 32];
    __shared__ short sBl[128 * 32];
    const int tid = threadIdx.x;
    const int w = tid >> 6, lane = tid & 63;
    const int bn0 = blockIdx.x * 128, bm0 = blockIdx.y * 128;
    const int wr = w >> 1, wc = w & 1;

    fx4 acc[4][4];
#pragma unroll
    for (int m = 0; m < 4; ++m)
#pragma unroll
        for (int n = 0; n < 4; ++n) acc[m][n] = {0.f, 0.f, 0.f, 0.f};

    for (int k0 = 0; k0 < K; k0 += 32) {
        __syncthreads();
#pragma unroll
        for (int i = 0; i < 2; ++i) {
            int c = i * 256 + tid;
            int r = c >> 2, kk = (c & 3) * 8;
            size_t ga = (size_t)(bm0 + r) * K + k0 + kk;
            size_t gb = (size_t)(bn0 + r) * K + k0 + kk;
            ASYNC_LDS16(sAh + c * 8, Ah + ga);
            ASYNC_LDS16(sAl + c * 8, Al + ga);
            ASYNC_LDS16(sBh + c * 8, Bth + gb);
            ASYNC_LDS16(sBl + c * 8, Btl + gb);
        }
        __syncthreads();
        bf16x8 ah[4], al[4], bh[4], bl[4];
#pragma unroll
        for (int m = 0; m < 4; ++m) {
            int off = (wr * 64 + m * 16 + (lane & 15)) * 32 + (lane >> 4) * 8;
            ah[m] = *(const bf16x8*)(sAh + off);
            al[m] = *(const bf16x8*)(sAl + off);
        }
#pragma unroll
        for (int n = 0; n < 4; ++n) {
            int off = (wc * 64 + n * 16 + (lane & 15)) * 32 + (lane >> 4) * 8;
            bh[n] = *(const bf16x8*)(sBh + off);
            bl[n] = *(const bf16x8*)(sBl + off);
        }
#pragma unroll
        for (int m = 0; m < 4; ++m)
#pragma unroll
            for (int n = 0; n < 4; ++n) {
                acc[m][n] = __builtin_amdgcn_mfma_f32_16x16x32_bf16(ah[m], bh[n], acc[m][n], 0, 0, 0);
                acc[m][n] = __builtin_amdgcn_mfma_f32_16x16x32_bf16(ah[m], bl[n], acc[m][n], 0, 0, 0);
                acc[m][n] = __builtin_amdgcn_mfma_f32_16x16x32_bf16(al[m], bh[n], acc[m][n], 0, 0, 0);
            }
    }
#pragma unroll
    for (int m = 0; m < 4; ++m) {
        int row = bm0 + wr * 64 + m * 16 + (lane >> 4) * 4;
#pragma unroll
        for (int n = 0; n < 4; ++n) {
            int col = bn0 + wc * 64 + n * 16 + (lane & 15);
#pragma unroll
            for (int j = 0; j < 4; ++j)
                Cout[(size_t)(row + j) * N + col] = acc[m][n][j];
        }
    }
}

// --------------------------------------------- RoPE + L2-normalize q,k in place
__global__ __launch_bounds__(256) void rope_kernel(float* __restrict__ X1,
                                                   const float2* __restrict__ cs) {
    int w = threadIdx.x >> 6, lane = threadIdx.x & 63;
    int p = blockIdx.x * 4 + w;            // (t,h) pair, 32768 total
    int t = p >> 4, h = p & 15;
    float2 c = cs[t * 32 + (lane & 31)];
#pragma unroll
    for (int which = 0; which < 2; ++which) {
        float* base = X1 + (size_t)t * NQKV + which * 1024 + h * 64;
        float x = base[lane];
        float xo = __shfl(x, lane ^ 32, 64);
        float r = (lane < 32) ? -xo : xo;
        float y = x * c.x + r * c.y;
        float ss = y * y;
#pragma unroll
        for (int m = 32; m; m >>= 1) ss += __shfl_xor(ss, m, 64);
        base[lane] = y * rsqrtf(ss + 1e-12f);
    }
}

// ===================== chunked delta-rule: shared helpers =====================
__device__ __forceinline__ void mm64_3p(const short* Ah, const short* Al,
                                        const short* Bh, const short* Bl,
                                        int w, int lane, fx4 acc[4]) {
#pragma unroll
    for (int k0 = 0; k0 < 64; k0 += 32) {
        int ao = (w * 16 + (lane & 15)) * LP + k0 + ((lane >> 4) * 8);
        bf16x8 ah = *(const bf16x8*)(Ah + ao);
        bf16x8 al = *(const bf16x8*)(Al + ao);
#pragma unroll
        for (int n = 0; n < 4; ++n) {
            int bo = (n * 16 + (lane & 15)) * LP + k0 + ((lane >> 4) * 8);
            bf16x8 bh = *(const bf16x8*)(Bh + bo);
            bf16x8 bl = *(const bf16x8*)(Bl + bo);
            acc[n] = __builtin_amdgcn_mfma_f32_16x16x32_bf16(ah, bh, acc[n], 0, 0, 0);
            acc[n] = __builtin_amdgcn_mfma_f32_16x16x32_bf16(ah, bl, acc[n], 0, 0, 0);
            acc[n] = __builtin_amdgcn_mfma_f32_16x16x32_bf16(al, bh, acc[n], 0, 0, 0);
        }
    }
}

__device__ __forceinline__ void split_write(short* h, short* l, int off, float x) {
    __hip_bfloat16 hb = __float2bfloat16(x);
    ((__hip_bfloat16*)h)[off] = hb;
    ((__hip_bfloat16*)l)[off] = __float2bfloat16(x - __bfloat162float(hb));
}

// ------------------------------------------------ phase A1 (solve, parallel)
__global__ __launch_bounds__(128) void phaseA1_kernel(const float* __restrict__ X1,
                                                      __hip_bfloat16* __restrict__ UvWT_hi,
                                                      __hip_bfloat16* __restrict__ UvWT_lo) {
    const int h = blockIdx.x & 15, c = blockIdx.x >> 4;
    const int tid = threadIdx.x, w = tid >> 6, lane = tid & 63;
    const int t0 = c * 64;

    __shared__ short b1h[64 * LP], b1l[64 * LP];   // K hi/lo
    __shared__ float sMT[64 * MP];                 // [s][t] (s<t) holds M[t][s]
    __shared__ float sLa[64], sB[64], sL[65], sGp[64];

    const float* k_g = X1 + (size_t)t0 * NQKV + 1024 + h * 64;
    const float* v_g = X1 + (size_t)t0 * NQKV + 2048 + h * 64;

    if (tid < 64) {
        float ga = X1[(size_t)(t0 + tid) * NQKV + 4096 + h];
        float gb = X1[(size_t)(t0 + tid) * NQKV + 4112 + h];
        float z = -ga;
        sLa[tid] = -(fmaxf(z, 0.f) + log1pf(expf(-fabsf(z))));
        sB[tid] = 1.f / (1.f + expf(-gb));
    }
    __syncthreads();
    if (tid < 64) {
        float v = sLa[tid];
#pragma unroll
        for (int off = 1; off < 64; off <<= 1) {
            float u = __shfl_up(v, off, 64);
            if (tid >= off) v += u;
        }
        sL[tid + 1] = v;
        if (tid == 0) sL[0] = 0.f;
    }
    __syncthreads();
    if (tid < 64) sGp[tid] = expf(sL[tid]);
    // stage K (split)
    for (int idx = tid; idx < 4096; idx += 128) {
        int r = idx >> 6, cc = idx & 63;
        float kv = k_g[(size_t)r * NQKV + cc];
        __hip_bfloat16 hb = __float2bfloat16(kv);
        ((__hip_bfloat16*)b1h)[r * LP + cc] = hb;
        ((__hip_bfloat16*)b1l)[r * LP + cc] = __float2bfloat16(kv - __bfloat162float(hb));
    }
    __syncthreads();

    // G = K K^T strips (2 waves x 2 strips of 16 rows); sMT[s][t] = M[t][s]
#pragma unroll
    for (int m = 0; m < 2; ++m) {
        int r0 = w * 32 + m * 16;
        fx4 acc[4];
#pragma unroll
        for (int n = 0; n < 4; ++n) acc[n] = {0.f, 0.f, 0.f, 0.f};
#pragma unroll
        for (int k0 = 0; k0 < 64; k0 += 32) {
            int ao = (r0 + (lane & 15)) * LP + k0 + ((lane >> 4) * 8);
            bf16x8 ah = *(const bf16x8*)(b1h + ao);
            bf16x8 al = *(const bf16x8*)(b1l + ao);
#pragma unroll
            for (int n = 0; n < 4; ++n) {
                int bo = (n * 16 + (lane & 15)) * LP + k0 + ((lane >> 4) * 8);
                bf16x8 bh = *(const bf16x8*)(b1h + bo);
                bf16x8 bl = *(const bf16x8*)(b1l + bo);
                acc[n] = __builtin_amdgcn_mfma_f32_16x16x32_bf16(ah, bh, acc[n], 0, 0, 0);
                acc[n] = __builtin_amdgcn_mfma_f32_16x16x32_bf16(ah, bl, acc[n], 0, 0, 0);
                acc[n] = __builtin_amdgcn_mfma_f32_16x16x32_bf16(al, bh, acc[n], 0, 0, 0);
            }
        }
#pragma unroll
        for (int n = 0; n < 4; ++n)
#pragma unroll
            for (int jj = 0; jj < 4; ++jj) {
                int t = r0 + (lane >> 4) * 4 + jj, s = n * 16 + (lane & 15);
                if (s < t) sMT[s * MP + t] = sB[t] * expf(sL[t] - sL[s + 1]) * acc[n][jj];
            }
    }
    __syncthreads();

    // register right-looking solve; thread j owns column j (0..127)
    const int j = tid;
    float rhs[64];
#pragma unroll
    for (int t = 0; t < 64; ++t) {
        float base;
        if (j < 64) {
            base = v_g[(size_t)t * NQKV + j];          // V direct from global
        } else {
            int i = j - 64;
            base = (__bfloat162float(((__hip_bfloat16*)b1h)[t * LP + i]) +
                    __bfloat162float(((__hip_bfloat16*)b1l)[t * LP + i])) * sGp[t];
        }
        rhs[t] = sB[t] * base;
    }
#pragma unroll
    for (int t = 0; t < 63; ++t) {
        float x = rhs[t];
        int s = t + 1;
#pragma unroll
        for (; (s & 3) && s < 64; ++s)
            rhs[s] = fmaf(-sMT[t * MP + s], x, rhs[s]);
#pragma unroll
        for (; s < 64; s += 4) {
            float4 m4 = *(const float4*)(sMT + t * MP + s);   // 16B-aligned (MP=68)
            rhs[s]     = fmaf(-m4.x, x, rhs[s]);
            rhs[s + 1] = fmaf(-m4.y, x, rhs[s + 1]);
            rhs[s + 2] = fmaf(-m4.z, x, rhs[s + 2]);
            rhs[s + 3] = fmaf(-m4.w, x, rhs[s + 3]);
        }
    }
    // write out t-major (coalesced): UvWT[hc][t][j]
    size_t obase = (size_t)(h * 32 + c) * 8192;
#pragma unroll
    for (int t = 0; t < 64; ++t) {
        __hip_bfloat16 hb = __float2bfloat16(rhs[t]);
        UvWT_hi[obase + t * 128 + j] = hb;
        UvWT_lo[obase + t * 128 + j] = __float2bfloat16(rhs[t] - __bfloat162float(hb));
    }
}

// ------------------------------------------------ phase A2 (matmuls, parallel)
__global__ __launch_bounds__(256) void phaseA2_kernel(float* __restrict__ X1,
                                                      const __hip_bfloat16* __restrict__ UvWT_hi,
                                                      const __hip_bfloat16* __restrict__ UvWT_lo,
                                                      short* __restrict__ AcBuf,
                                                      float* __restrict__ BcBuf) {
    const int h = blockIdx.x & 15, c = blockIdx.x >> 4;
    const int tid = threadIdx.x, w = tid >> 6, lane = tid & 63;
    const int t0 = c * 64;

    __shared__ short b1h[64 * LP], b1l[64 * LP];   // K
    __shared__ short b2h[64 * LP], b2l[64 * LP];   // Q -> Ptilde -> KhatT
    __shared__ short b3h[64 * LP], b3l[64 * LP];   // UvT
    __shared__ short b4h[64 * LP], b4l[64 * LP];   // WT
    __shared__ float sLa[64], sL[65], sGp[64], sRc[64];

    const float* q_g = X1 + (size_t)t0 * NQKV + h * 64;
    const float* k_g = q_g + 1024;

    if (tid < 64) {
        float ga = X1[(size_t)(t0 + tid) * NQKV + 4096 + h];
        float z = -ga;
        sLa[tid] = -(fmaxf(z, 0.f) + log1pf(expf(-fabsf(z))));
    }
    __syncthreads();
    if (tid < 64) {
        float v = sLa[tid];
#pragma unroll
        for (int off = 1; off < 64; off <<= 1) {
            float u = __shfl_up(v, off, 64);
            if (tid >= off) v += u;
        }
        sL[tid + 1] = v;
        if (tid == 0) sL[0] = 0.f;
    }
    __syncthreads();
    if (tid < 64) {
        sGp[tid] = expf(sL[tid]);
        sRc[tid] = expf(sL[64] - sL[tid + 1]);
    }
    // stage Q, K (split) and UvT/WT
    for (int idx = tid; idx < 4096; idx += 256) {
        int r = idx >> 6, cc = idx & 63;
        split_write(b2h, b2l, r * LP + cc, q_g[(size_t)r * NQKV + cc]);
        split_write(b1h, b1l, r * LP + cc, k_g[(size_t)r * NQKV + cc]);
    }
    const __hip_bfloat16* uh = UvWT_hi + (size_t)(h * 32 + c) * 8192;
    const __hip_bfloat16* ul = UvWT_lo + (size_t)(h * 32 + c) * 8192;
    for (int idx = tid; idx < 8192; idx += 256) {
        int t = idx >> 7, row = idx & 127;
        short* dh = (row < 64) ? b3h : b4h;
        short* dl = (row < 64) ? b3l : b4l;
        ((__hip_bfloat16*)dh)[(row & 63) * LP + t] = uh[idx];
        ((__hip_bfloat16*)dl)[(row & 63) * LP + t] = ul[idx];
    }
    __syncthreads();

    // P = Q K^T
    fx4 pacc[4];
#pragma unroll
    for (int n = 0; n < 4; ++n) pacc[n] = {0.f, 0.f, 0.f, 0.f};
    mm64_3p(b2h, b2l, b1h, b1l, w, lane, pacc);
    __syncthreads();
    // Ptilde -> b2 (masked, scaled)
#pragma unroll
    for (int n = 0; n < 4; ++n)
#pragma unroll
        for (int jj = 0; jj < 4; ++jj) {
            int t = w * 16 + (lane >> 4) * 4 + jj, s = n * 16 + (lane & 15);
            float pv = (s < t) ? expf(sL[t] - sL[s + 1]) * pacc[n][jj] : 0.f;
            split_write(b2h, b2l, t * LP + s, pv);
        }
    __syncthreads();

    // Olocal = Ptilde @ Uv -> overwrite k-region (f32)
    {
        fx4 acc[4];
#pragma unroll
        for (int n = 0; n < 4; ++n) acc[n] = {0.f, 0.f, 0.f, 0.f};
        mm64_3p(b2h, b2l, b3h, b3l, w, lane, acc);
        float* og = X1 + (size_t)t0 * NQKV + 1024 + h * 64;
#pragma unroll
        for (int n = 0; n < 4; ++n)
#pragma unroll
            for (int jj = 0; jj < 4; ++jj) {
                int t = w * 16 + (lane >> 4) * 4 + jj, s = n * 16 + (lane & 15);
                og[(size_t)t * NQKV + s] = acc[n][jj];
            }
    }
    // PW = Ptilde @ W ; Qeff = diag(gprev)Q - PW -> overwrite q-region (f32)
    {
        fx4 acc[4];
#pragma unroll
        for (int n = 0; n < 4; ++n) acc[n] = {0.f, 0.f, 0.f, 0.f};
        mm64_3p(b2h, b2l, b4h, b4l, w, lane, acc);
        float* qg = X1 + (size_t)t0 * NQKV + h * 64;
#pragma unroll
        for (int n = 0; n < 4; ++n)
#pragma unroll
            for (int jj = 0; jj < 4; ++jj) {
                int t = w * 16 + (lane >> 4) * 4 + jj, s = n * 16 + (lane & 15);
                float qv = qg[(size_t)t * NQKV + s];
                qg[(size_t)t * NQKV + s] = sGp[t] * qv - acc[n][jj];
            }
    }
    __syncthreads();   // all reads of b2 (Ptilde) complete
    // KhatT -> b2: [i][s] = rC[s] * K[s][i]
    for (int idx = tid; idx < 4096; idx += 256) {
        int s = idx >> 6, i = idx & 63;
        float kv = __bfloat162float(((__hip_bfloat16*)b1h)[s * LP + i]) +
                   __bfloat162float(((__hip_bfloat16*)b1l)[s * LP + i]);
        split_write(b2h, b2l, i * LP + s, sRc[s] * kv);
    }
    __syncthreads();

    // Ac = gammaEnd*I - KhatT @ W -> AcBuf (bf16 hi/lo, row-major [i][j])
    {
        fx4 acc[4];
#pragma unroll
        for (int n = 0; n < 4; ++n) acc[n] = {0.f, 0.f, 0.f, 0.f};
        mm64_3p(b2h, b2l, b4h, b4l, w, lane, acc);
        float gend = expf(sL[64]);
        size_t abase = (size_t)(h * 32 + c) * 8192;
#pragma unroll
        for (int n = 0; n < 4; ++n)
#pragma unroll
            for (int jj = 0; jj < 4; ++jj) {
                int i = w * 16 + (lane >> 4) * 4 + jj, jd = n * 16 + (lane & 15);
                float av = ((i == jd) ? gend : 0.f) - acc[n][jj];
                __hip_bfloat16 hb = __float2bfloat16(av);
                ((__hip_bfloat16*)AcBuf)[abase + i * 64 + jd] = hb;
                ((__hip_bfloat16*)AcBuf)[abase + 4096 + i * 64 + jd] =
                    __float2bfloat16(av - __bfloat162float(hb));
            }
    }
    // BcT = UvT @ KhatT' -> BcBuf (f32, [v][i])
    {
        fx4 acc[4];
#pragma unroll
        for (int n = 0; n < 4; ++n) acc[n] = {0.f, 0.f, 0.f, 0.f};
        mm64_3p(b3h, b3l, b2h, b2l, w, lane, acc);
        size_t bbase = (size_t)(h * 32 + c) * 4096;
#pragma unroll
        for (int n = 0; n < 4; ++n)
#pragma unroll
            for (int jj = 0; jj < 4; ++jj) {
                int jv = w * 16 + (lane >> 4) * 4 + jj, i = n * 16 + (lane & 15);
                BcBuf[bbase + jv * 64 + i] = acc[n][jj];
            }
    }
}

// --------------------------------------------------- phase B (state recurrence)
// 64 blocks = (head h, v-slice sl). One wave per block; rows of S^T evolve
// independently, so each block owns 16 rows. No barriers; Ac/Bc register
// double-buffer prefetch. FMA order identical to the 4-wave version.
__global__ __launch_bounds__(64) void phaseB_kernel(const short* __restrict__ AcBuf,
                                                    const float* __restrict__ BcBuf,
                                                    float* __restrict__ X1) {
    const int h = blockIdx.x >> 2, sl = blockIdx.x & 3;
    const int lane = threadIdx.x;
    const int r0 = sl * 16;                        // v-rows owned: [r0, r0+16)
    const int lr4 = (lane >> 4) * 4;               // local row base (C-layout)
    const int lc = lane & 15;                      // col within 16-group
    __shared__ short sAh[64 * LP], sAl[64 * LP];   // Ac hi/lo, row-major [i][j]
    __shared__ float sSf[16 * 68];                 // f32 slice staging

    fx4 acc[4];
#pragma unroll
    for (int n = 0; n < 4; ++n) acc[n] = {0.f, 0.f, 0.f, 0.f};

    const size_t hc0 = (size_t)h * 32;
    int4 pre[16];
    {
        const int4* asrc = (const int4*)(AcBuf + hc0 * 8192);
#pragma unroll
        for (int q = 0; q < 16; ++q) pre[q] = asrc[q * 64 + lane];
    }
    float bcur[16];
    {
        const float* bsrc = BcBuf + hc0 * 4096;
#pragma unroll
        for (int n = 0; n < 4; ++n)
#pragma unroll
            for (int jj = 0; jj < 4; ++jj)
                bcur[n * 4 + jj] = bsrc[(r0 + lr4 + jj) * 64 + n * 16 + lc];
    }

#pragma unroll 1
    for (int c = 0; c < 32; ++c) {
        // Ac[c] regs -> LDS (hi rows then lo rows; 8 bf16 per int4)
#pragma unroll
        for (int q = 0; q < 16; ++q) {
            int m = q * 64 + lane;                 // int4 index 0..1023
            int row = (m >> 3) & 63, cc = (m & 7) * 8;
            short* dst = (q < 8) ? sAh : sAl;
            *(int4*)(dst + row * LP + cc) = pre[q];
        }
        // store state entering chunk c (fire & forget)
        float* stg = X1 + (size_t)(c * 64) * NQKV + 2048 + h * 64;
#pragma unroll
        for (int n = 0; n < 4; ++n)
#pragma unroll
            for (int jj = 0; jj < 4; ++jj)
                stg[(size_t)(r0 + lr4 + jj) * NQKV + n * 16 + lc] = acc[n][jj];
        // slice -> LDS f32 (A-operand staging, C-layout -> row-major)
#pragma unroll
        for (int n = 0; n < 4; ++n)
#pragma unroll
            for (int jj = 0; jj < 4; ++jj)
                sSf[(lr4 + jj) * 68 + n * 16 + lc] = acc[n][jj];
        // prefetch next chunk's Ac/Bc
        int cn = (c < 31) ? c + 1 : c;
        const int4* asrc = (const int4*)(AcBuf + (hc0 + cn) * 8192);
#pragma unroll
        for (int q = 0; q < 16; ++q) pre[q] = asrc[q * 64 + lane];
        float bnext[16];
        const float* bsrc = BcBuf + (hc0 + cn) * 4096;
#pragma unroll
        for (int n = 0; n < 4; ++n)
#pragma unroll
            for (int jj = 0; jj < 4; ++jj)
                bnext[n * 4 + jj] = bsrc[(r0 + lr4 + jj) * 64 + n * 16 + lc];
        // A-fragments: read f32 slice, split hi/lo in regs
        bf16x8 afh[2], afl[2];
#pragma unroll
        for (int k0 = 0; k0 < 2; ++k0) {
            const float* ap = sSf + lc * 68 + k0 * 32 + (lane >> 4) * 8;
            float4 f0 = *(const float4*)(ap);
            float4 f1 = *(const float4*)(ap + 4);
            float fv[8] = {f0.x, f0.y, f0.z, f0.w, f1.x, f1.y, f1.z, f1.w};
#pragma unroll
            for (int e = 0; e < 8; ++e) {
                __hip_bfloat16 hb = __float2bfloat16(fv[e]);
                __hip_bfloat16 lb = __float2bfloat16(fv[e] - __bfloat162float(hb));
                afh[k0][e] = *(__bf16*)&hb;
                afl[k0][e] = *(__bf16*)&lb;
            }
        }
        // nacc = Bc[c] + S^T @ Ac[c]^T  (same product order as mm64_3p)
        fx4 nacc[4];
#pragma unroll
        for (int n = 0; n < 4; ++n)
            nacc[n] = {bcur[n * 4 + 0], bcur[n * 4 + 1], bcur[n * 4 + 2], bcur[n * 4 + 3]};
#pragma unroll
        for (int k0 = 0; k0 < 2; ++k0)
#pragma unroll
            for (int n = 0; n < 4; ++n) {
                int bo = (n * 16 + lc) * LP + k0 * 32 + (lane >> 4) * 8;
                bf16x8 bh = *(const bf16x8*)(sAh + bo);
                bf16x8 bl = *(const bf16x8*)(sAl + bo);
                nacc[n] = __builtin_amdgcn_mfma_f32_16x16x32_bf16(afh[k0], bh, nacc[n], 0, 0, 0);
                nacc[n] = __builtin_amdgcn_mfma_f32_16x16x32_bf16(afh[k0], bl, nacc[n], 0, 0, 0);
                nacc[n] = __builtin_amdgcn_mfma_f32_16x16x32_bf16(afl[k0], bh, nacc[n], 0, 0, 0);
            }
#pragma unroll
        for (int n = 0; n < 4; ++n) acc[n] = nacc[n];
#pragma unroll
        for (int e = 0; e < 16; ++e) bcur[e] = bnext[e];
    }
}

// --------------------------------------------- phase C (outputs + epilogue)
__global__ __launch_bounds__(256) void phaseC_kernel(const float* __restrict__ X1,
                                                     const float* __restrict__ onw,
                                                     __hip_bfloat16* __restrict__ attn_bf) {
    const int h = blockIdx.x & 15, c = blockIdx.x >> 4;
    const int tid = threadIdx.x, w = tid >> 6, lane = tid & 63;
    const int t0 = c * 64;
    __shared__ short qh[64 * LP], ql[64 * LP];
    __shared__ short sh_[64 * LP], sl_[64 * LP];
    __shared__ float sO[4096];
    __shared__ float part[64][4];
    const float* qe = X1 + (size_t)t0 * NQKV + h * 64;          // Qeff
    const float* stg = X1 + (size_t)t0 * NQKV + 2048 + h * 64;  // S^T (entering c)
    const float* ol = X1 + (size_t)t0 * NQKV + 1024 + h * 64;   // Olocal
    for (int idx = tid; idx < 4096; idx += 256) {
        int r = idx >> 6, i = idx & 63;
        split_write(qh, ql, r * LP + i, qe[(size_t)r * NQKV + i]);
        split_write(sh_, sl_, r * LP + i, stg[(size_t)r * NQKV + i]);
    }
    __syncthreads();
    fx4 acc[4];
#pragma unroll
    for (int n = 0; n < 4; ++n)
#pragma unroll
        for (int jj = 0; jj < 4; ++jj)
            acc[n][jj] = ol[(size_t)(w * 16 + (lane >> 4) * 4 + jj) * NQKV + n * 16 + (lane & 15)];
    mm64_3p(qh, ql, sh_, sl_, w, lane, acc);
#pragma unroll
    for (int n = 0; n < 4; ++n)
#pragma unroll
        for (int jj = 0; jj < 4; ++jj)
            sO[(w * 16 + (lane >> 4) * 4 + jj) * 64 + n * 16 + (lane & 15)] = acc[n][jj];
    __syncthreads();
    int r = tid >> 2, qq = tid & 3;
    float ss = 0.f;
#pragma unroll
    for (int i2 = 0; i2 < 16; ++i2) { float v = sO[r * 64 + qq * 16 + i2]; ss += v * v; }
    part[r][qq] = ss;
    __syncthreads();
    float tot = part[r][0] + part[r][1] + part[r][2] + part[r][3];
    float sc = rsqrtf(tot * (1.f / 64.f) + 1e-6f);
    const float* gg = X1 + (size_t)(t0 + r) * NQKV + 3072 + h * 64;
#pragma unroll
    for (int i2 = 0; i2 < 16; ++i2) {
        int j = qq * 16 + i2;
        float on = sO[r * 64 + j] * sc * onw[j];
        float g = gg[j];
        float sg = g / (1.f + expf(-g));
        attn_bf[(size_t)(t0 + r) * 1024 + h * 64 + j] = __float2bfloat16(on * sg);
    }
}

// ---------------------------- h = hidden + attn (in place); ybf = rmsnorm(h)
__global__ __launch_bounds__(256) void add_rmsnorm_kernel(
    const float* __restrict__ hidden, float* __restrict__ acc,
    const float* __restrict__ w, __hip_bfloat16* __restrict__ out) {
    int t = blockIdx.x;
    int d = threadIdx.x * 4;
    float4 a = *(const float4*)(acc + (size_t)t * D_MODEL + d);
    float4 hd = *(const float4*)(hidden + (size_t)t * D_MODEL + d);
    float4 h4 = make_float4(a.x + hd.x, a.y + hd.y, a.z + hd.z, a.w + hd.w);
    *(float4*)(acc + (size_t)t * D_MODEL + d) = h4;
    float ss = h4.x * h4.x + h4.y * h4.y + h4.z * h4.z + h4.w * h4.w;
#pragma unroll
    for (int m = 32; m; m >>= 1) ss += __shfl_xor(ss, m, 64);
    __shared__ float wsum[4];
    if ((threadIdx.x & 63) == 0) wsum[threadIdx.x >> 6] = ss;
    __syncthreads();
    float tot = wsum[0] + wsum[1] + wsum[2] + wsum[3];
    float sc = rsqrtf(tot * (1.f / 1024.f) + 1e-6f);
    const float4 wv = *(const float4*)(w + d);
    __hip_bfloat16* op = out + (size_t)t * D_MODEL + d;
    op[0] = __float2bfloat16(h4.x * sc * wv.x);
    op[1] = __float2bfloat16(h4.y * sc * wv.y);
    op[2] = __float2bfloat16(h4.z * sc * wv.z);
    op[3] = __float2bfloat16(h4.w * sc * wv.w);
}

// ---------------------------------------------- m = silu(G) * U (bf16 in/out)
__global__ __launch_bounds__(256) void silu_mul_kernel(const __hip_bfloat16* __restrict__ GU,
                                                       __hip_bfloat16* __restrict__ m) {
    size_t i = (size_t)blockIdx.x * 256 + threadIdx.x;   // 2048*4096
    size_t t = i >> 12, j = i & 4095;
    float g = __bfloat162float(GU[t * 8192 + j]);
    float u = __bfloat162float(GU[t * 8192 + 4096 + j]);
    m[i] = __float2bfloat16(u * g / (1.f + expf(-g)));
}

// ----------------------------------------------------------- out += h
__global__ __launch_bounds__(256) void final_add_kernel(float* __restrict__ out,
                                                        const float* __restrict__ h) {
    size_t i = (size_t)blockIdx.x * 256 + threadIdx.x;
    out[i] += h[i];
}

// ---------------------------------------------------------------------------
extern "C" void kernel_launch(void* const* d_in, const int* in_sizes, int n_in,
                              void* d_out, int out_size, void* d_ws, size_t ws_size,
                              hipStream_t stream) {
    (void)in_sizes; (void)n_in; (void)out_size; (void)ws_size;
    const float* hidden     = (const float*)d_in[0];
    const float* norm1_w    = (const float*)d_in[1];
    const float* q_w        = (const float*)d_in[2];
    const float* k_w        = (const float*)d_in[3];
    const float* v_w        = (const float*)d_in[4];
    const float* g_w        = (const float*)d_in[5];
    const float* b_w        = (const float*)d_in[6];
    const float* gate_w     = (const float*)d_in[7];
    const float* o_norm_w   = (const float*)d_in[8];
    const float* o_w        = (const float*)d_in[9];
    const float* norm2_w    = (const float*)d_in[10];
    const float* mlp_gate_w = (const float*)d_in[11];
    const float* mlp_up_w   = (const float*)d_in[12];
    const float* mlp_down_w = (const float*)d_in[13];

    char* ws = (char*)d_ws;
    // workspace (~92 MiB), timeline-reused:
    const size_t OFF_WT_QKVG = 0;          // wt_qkvg_hi -> AcBuf
    const size_t OFF_WT_O    = 8650752;
    const size_t OFF_WT_GU   = 10747904;
    const size_t OFF_WT_DOWN = 27525120;
    const size_t OFF_X1      = 35913728;   // X1 f32 -> GU bf16
    const size_t OFF_R1      = 70516736;   // wt_qkvg_lo -> BcBuf -> mbf
    const size_t OFF_ATTN    = 79167488;   // UvWT_lo (A1/A2) -> attn_bf+ybf
    const size_t OFF_YBF     = 83361792;
    const size_t OFF_XHI     = 87556096;   // xhi/xlo -> UvWT_hi -> h_buf
    const size_t OFF_XLO     = 91750400;
    const size_t OFF_ROPE    = 95944704;

    __hip_bfloat16* wt_qkvg_hi = (__hip_bfloat16*)(ws + OFF_WT_QKVG);
    __hip_bfloat16* wt_qkvg_lo = (__hip_bfloat16*)(ws + OFF_R1);
    __hip_bfloat16* wt_o    = (__hip_bfloat16*)(ws + OFF_WT_O);
    __hip_bfloat16* wt_gu   = (__hip_bfloat16*)(ws + OFF_WT_GU);
    __hip_bfloat16* wt_down = (__hip_bfloat16*)(ws + OFF_WT_DOWN);
    float*          X1      = (float*)(ws + OFF_X1);
    __hip_bfloat16* GU      = (__hip_bfloat16*)(ws + OFF_X1);
    short*          AcBuf   = (short*)(ws + OFF_WT_QKVG);       // after qkv gemm
    float*          BcBuf   = (float*)(ws + OFF_R1);            // after qkv gemm
    __hip_bfloat16* mbf     = (__hip_bfloat16*)(ws + OFF_R1);   // after phase B/C
    __hip_bfloat16* attn_bf = (__hip_bfloat16*)(ws + OFF_ATTN);
    __hip_bfloat16* xhi     = (__hip_bfloat16*)(ws + OFF_XHI);
    __hip_bfloat16* xlo     = (__hip_bfloat16*)(ws + OFF_XLO);
    __hip_bfloat16* UvWT_hi = (__hip_bfloat16*)(ws + OFF_XHI);  // 8.39MB, after qkv gemm
    __hip_bfloat16* UvWT_lo = (__hip_bfloat16*)(ws + OFF_ATTN); // 8.39MB, until phaseC
    float*          h_buf   = (float*)(ws + OFF_XHI);           // after phaseA2
    __hip_bfloat16* ybf     = (__hip_bfloat16*)(ws + OFF_YBF);
    float2*         rope_cs = (float2*)(ws + OFF_ROPE);

    dim3 tb(32, 8);
    rope_table_kernel<<<256, 256, 0, stream>>>(rope_cs);
    rmsnorm_split_kernel<<<2048, 256, 0, stream>>>(hidden, norm1_w, xhi, xlo);
    transpose_split_kernel<<<dim3(32, 32), tb, 0, stream>>>(q_w,    wt_qkvg_hi,               wt_qkvg_lo,               1024, 1024, 1024);
    transpose_split_kernel<<<dim3(32, 32), tb, 0, stream>>>(k_w,    wt_qkvg_hi + 1024 * 1024, wt_qkvg_lo + 1024 * 1024, 1024, 1024, 1024);
    transpose_split_kernel<<<dim3(32, 32), tb, 0, stream>>>(v_w,    wt_qkvg_hi + 2048 * 1024, wt_qkvg_lo + 2048 * 1024, 1024, 1024, 1024);
    transpose_split_kernel<<<dim3(32, 32), tb, 0, stream>>>(gate_w, wt_qkvg_hi + 3072 * 1024, wt_qkvg_lo + 3072 * 1024, 1024, 1024, 1024);
    transpose_split_kernel<<<dim3(32, 1),  tb, 0, stream>>>(g_w,    wt_qkvg_hi + 4096 * 1024, wt_qkvg_lo + 4096 * 1024, 1024, 16,   16);
    transpose_split_kernel<<<dim3(32, 4),  tb, 0, stream>>>(b_w,    wt_qkvg_hi + 4112 * 1024, wt_qkvg_lo + 4112 * 1024, 1024, 16,   112);
    transpose_bf16_kernel<<<dim3(32, 32),  tb, 0, stream>>>(o_w,        wt_o,                1024, 1024, 1024);
    transpose_bf16_kernel<<<dim3(32, 128), tb, 0, stream>>>(mlp_gate_w, wt_gu,               1024, 4096, 4096);
    transpose_bf16_kernel<<<dim3(32, 128), tb, 0, stream>>>(mlp_up_w,   wt_gu + 4096 * 1024, 1024, 4096, 4096);
    transpose_bf16_kernel<<<dim3(128, 32), tb, 0, stream>>>(mlp_down_w, wt_down,             4096, 1024, 1024);
    // fused q|k|v|gate|g|b projection (split precision)
    gemm_bt_split<<<dim3(33, 16), 256, 0, stream>>>(xhi, xlo, wt_qkvg_hi, wt_qkvg_lo, X1, 2048, NQKV, 1024);
    rope_kernel<<<8192, 256, 0, stream>>>(X1, rope_cs);
    // chunked delta-rule scan
    phaseA1_kernel<<<512, 128, 0, stream>>>(X1, UvWT_hi, UvWT_lo);
    phaseA2_kernel<<<512, 256, 0, stream>>>(X1, UvWT_hi, UvWT_lo, AcBuf, BcBuf);
    phaseB_kernel<<<64, 64, 0, stream>>>(AcBuf, BcBuf, X1);
    phaseC_kernel<<<512, 256, 0, stream>>>(X1, o_norm_w, attn_bf);
    // attn out projection -> h
    gemm_bt<false><<<dim3(8, 16), 256, 0, stream>>>(attn_bf, wt_o, h_buf, 2048, 1024, 1024);
    add_rmsnorm_kernel<<<2048, 256, 0, stream>>>(hidden, h_buf, norm2_w, ybf);
    gemm_bt<true><<<dim3(64, 16), 256, 0, stream>>>(ybf, wt_gu, GU, 2048, 8192, 1024);
    silu_mul_kernel<<<32768, 256, 0, stream>>>(GU, mbf);
    gemm_bt<false><<<dim3(8, 16), 256, 0, stream>>>(mbf, wt_down, (float*)d_out, 2048, 1024, 4096);
    final_add_kernel<<<8192, 256, 0, stream>>>((float*)d_out, h_buf);
}

// Round 8
// 494.713 us; speedup vs baseline: 1.3120x; 1.3120x over previous
//
#include <hip/hip_runtime.h>
#include <hip/hip_bf16.h>

// ---------------------------------------------------------------------------
// DepthDeltaNetDecoderLayer: B=1, T=2048, D=1024, H=16, DK=DV=64, FF=4096
// Round 7: phaseB re-rewrite. Round 6's 1-wave/64-block version spilled its
// int4 pre[16] prefetch (VGPR 88 < needed) -> scratch round-trips on the
// serial chain (6.5us/iter). New: 16 blocks x 4 waves, Ac prefetched via
// global_load_lds double-buffer (zero VGPR), S^T redistribution is intra-wave
// (no barrier), ONE barrier/iter provides the vmcnt drain for the async
// staging (m97 pattern). MFMA product order unchanged.
// ---------------------------------------------------------------------------

#define T_SEQ 2048
#define D_MODEL 1024
#define NH 16
#define DK 64
#define DV 64
#define FF 4096
#define NQKV 4224   // q(1024) k(1024) v(1024) gate(1024) g(16@4096) b(16@4112) pad->4224
#define LP 72       // padded LDS stride (shorts) for 64x64 bf16 operand tiles
#define MP 68       // padded stride (floats) for M^T: 16B-aligned rows

typedef __bf16 bf16x8 __attribute__((ext_vector_type(8)));
typedef float  fx4    __attribute__((ext_vector_type(4)));

#if defined(__has_builtin)
#if __has_builtin(__builtin_amdgcn_global_load_lds)
#define HAVE_GLOAD_LDS 1
#endif
#endif

#ifdef HAVE_GLOAD_LDS
#define ASYNC_LDS16(dst, src)                                                   \
    __builtin_amdgcn_global_load_lds(                                           \
        (__attribute__((address_space(1))) void*)(src),                         \
        (__attribute__((address_space(3))) void*)(dst), 16, 0, 0)
#else
#define ASYNC_LDS16(dst, src) (*(int4*)(dst) = *(const int4*)(src))
#endif

// ---------------------------------------------------------------- rope table
__global__ void rope_table_kernel(float2* __restrict__ cs) {
    int idx = blockIdx.x * 256 + threadIdx.x;      // t*32 + i, 65536 total
    int t = idx >> 5, i = idx & 31;
    float freq = (float)t * powf(10000.f, -(float)i / 32.f);
    cs[idx] = make_float2(cosf(freq), sinf(freq));
}

// --------------------------------------- row rmsnorm -> bf16 hi + bf16 lo
__global__ __launch_bounds__(256) void rmsnorm_split_kernel(
    const float* __restrict__ in, const float* __restrict__ w,
    __hip_bfloat16* __restrict__ hi, __hip_bfloat16* __restrict__ lo) {
    int t = blockIdx.x;
    int d = threadIdx.x * 4;
    const float4 v = *(const float4*)(in + (size_t)t * D_MODEL + d);
    float ss = v.x * v.x + v.y * v.y + v.z * v.z + v.w * v.w;
#pragma unroll
    for (int m = 32; m; m >>= 1) ss += __shfl_xor(ss, m, 64);
    __shared__ float wsum[4];
    if ((threadIdx.x & 63) == 0) wsum[threadIdx.x >> 6] = ss;
    __syncthreads();
    float tot = wsum[0] + wsum[1] + wsum[2] + wsum[3];
    float sc = rsqrtf(tot * (1.f / 1024.f) + 1e-6f);
    const float4 wv = *(const float4*)(w + d);
    float xs[4] = {v.x * sc * wv.x, v.y * sc * wv.y, v.z * sc * wv.z, v.w * sc * wv.w};
    __hip_bfloat16* hp = hi + (size_t)t * D_MODEL + d;
    __hip_bfloat16* lp = lo + (size_t)t * D_MODEL + d;
#pragma unroll
    for (int j = 0; j < 4; ++j) {
        __hip_bfloat16 h = __float2bfloat16(xs[j]);
        hp[j] = h;
        lp[j] = __float2bfloat16(xs[j] - __bfloat162float(h));
    }
}

// ------------------------------------------- W (KxN f32) -> Wt (Npad x K bf16)
__global__ void transpose_bf16_kernel(const float* __restrict__ W,
                                      __hip_bfloat16* __restrict__ Wt,
                                      int K, int N, int Npad) {
    __shared__ float tile[32][33];
    int k0 = blockIdx.x * 32, n0 = blockIdx.y * 32;
    int tx = threadIdx.x, ty = threadIdx.y;   // (32,8)
#pragma unroll
    for (int i = 0; i < 32; i += 8) {
        int n = n0 + tx;
        tile[ty + i][tx] = (n < N) ? W[(size_t)(k0 + ty + i) * N + n] : 0.f;
    }
    __syncthreads();
#pragma unroll
    for (int i = 0; i < 32; i += 8) {
        int n = n0 + ty + i;
        if (n < Npad) Wt[(size_t)n * K + k0 + tx] = __float2bfloat16(tile[tx][ty + i]);
    }
}

// ---------------------- W (KxN f32) -> Wt_hi, Wt_lo (Npad x K bf16 each)
__global__ void transpose_split_kernel(const float* __restrict__ W,
                                       __hip_bfloat16* __restrict__ Wt_hi,
                                       __hip_bfloat16* __restrict__ Wt_lo,
                                       int K, int N, int Npad) {
    __shared__ float tile[32][33];
    int k0 = blockIdx.x * 32, n0 = blockIdx.y * 32;
    int tx = threadIdx.x, ty = threadIdx.y;   // (32,8)
#pragma unroll
    for (int i = 0; i < 32; i += 8) {
        int n = n0 + tx;
        tile[ty + i][tx] = (n < N) ? W[(size_t)(k0 + ty + i) * N + n] : 0.f;
    }
    __syncthreads();
#pragma unroll
    for (int i = 0; i < 32; i += 8) {
        int n = n0 + ty + i;
        if (n < Npad) {
            float x = tile[tx][ty + i];
            __hip_bfloat16 h = __float2bfloat16(x);
            Wt_hi[(size_t)n * K + k0 + tx] = h;
            Wt_lo[(size_t)n * K + k0 + tx] = __float2bfloat16(x - __bfloat162float(h));
        }
    }
}

// ------------------------------------------------------------------- GEMM
// A: MxK bf16 row-major; Bt: NxK bf16 row-major (B transposed); C: MxN.
template <bool OUT_BF16>
__global__ __launch_bounds__(256) void gemm_bt(
    const __hip_bfloat16* __restrict__ A, const __hip_bfloat16* __restrict__ Bt,
    void* __restrict__ Cout, int M, int N, int K) {
    __shared__ short sA[128 * 32];
    __shared__ short sB[128 * 32];
    const int tid = threadIdx.x;
    const int w = tid >> 6, lane = tid & 63;
    const int bn0 = blockIdx.x * 128, bm0 = blockIdx.y * 128;
    const int wr = w >> 1, wc = w & 1;

    fx4 acc[4][4];
#pragma unroll
    for (int m = 0; m < 4; ++m)
#pragma unroll
        for (int n = 0; n < 4; ++n) acc[m][n] = {0.f, 0.f, 0.f, 0.f};

    for (int k0 = 0; k0 < K; k0 += 32) {
        __syncthreads();
#pragma unroll
        for (int i = 0; i < 2; ++i) {
            int c = i * 256 + tid;
            int r = c >> 2, kk = (c & 3) * 8;
            ASYNC_LDS16(sA + c * 8, A + (size_t)(bm0 + r) * K + k0 + kk);
            ASYNC_LDS16(sB + c * 8, Bt + (size_t)(bn0 + r) * K + k0 + kk);
        }
        __syncthreads();
        bf16x8 af[4], bfv[4];
#pragma unroll
        for (int m = 0; m < 4; ++m)
            af[m] = *(const bf16x8*)(sA + (wr * 64 + m * 16 + (lane & 15)) * 32 + (lane >> 4) * 8);
#pragma unroll
        for (int n = 0; n < 4; ++n)
            bfv[n] = *(const bf16x8*)(sB + (wc * 64 + n * 16 + (lane & 15)) * 32 + (lane >> 4) * 8);
#pragma unroll
        for (int m = 0; m < 4; ++m)
#pragma unroll
            for (int n = 0; n < 4; ++n)
                acc[m][n] = __builtin_amdgcn_mfma_f32_16x16x32_bf16(af[m], bfv[n], acc[m][n], 0, 0, 0);
    }
#pragma unroll
    for (int m = 0; m < 4; ++m) {
        int row = bm0 + wr * 64 + m * 16 + (lane >> 4) * 4;
#pragma unroll
        for (int n = 0; n < 4; ++n) {
            int col = bn0 + wc * 64 + n * 16 + (lane & 15);
#pragma unroll
            for (int j = 0; j < 4; ++j) {
                float val = acc[m][n][j];
                if (OUT_BF16)
                    ((__hip_bfloat16*)Cout)[(size_t)(row + j) * N + col] = __float2bfloat16(val);
                else
                    ((float*)Cout)[(size_t)(row + j) * N + col] = val;
            }
        }
    }
}

// ------------------------------------- split-precision GEMM (3 bf16 products)
__global__ __launch_bounds__(256) void gemm_bt_split(
    const __hip_bfloat16* __restrict__ Ah, const __hip_bfloat16* __restrict__ Al,
    const __hip_bfloat16* __restrict__ Bth, const __hip_bfloat16* __restrict__ Btl,
    float* __restrict__ Cout, int M, int N, int K) {
    __shared__ short sAh[128 * 32];
    __shared__ short sAl[128 * 32];
    __shared__ short sBh[128 * 32];
    __shared__ short sBl[128 * 32];
    const int tid = threadIdx.x;
    const int w = tid >> 6, lane = tid & 63;
    const int bn0 = blockIdx.x * 128, bm0 = blockIdx.y * 128;
    const int wr = w >> 1, wc = w & 1;

    fx4 acc[4][4];
#pragma unroll
    for (int m = 0; m < 4; ++m)
#pragma unroll
        for (int n = 0; n < 4; ++n) acc[m][n] = {0.f, 0.f, 0.f, 0.f};

    for (int k0 = 0; k0 < K; k0 += 32) {
        __syncthreads();
#pragma unroll
        for (int i = 0; i < 2; ++i) {
            int c = i * 256 + tid;
            int r = c >> 2, kk = (c & 3) * 8;
            size_t ga = (size_t)(bm0 + r) * K + k0 + kk;
            size_t gb = (size_t)(bn0 + r) * K + k0 + kk;
            ASYNC_LDS16(sAh + c * 8, Ah + ga);
            ASYNC_LDS16(sAl + c * 8, Al + ga);
            ASYNC_LDS16(sBh + c * 8, Bth + gb);
            ASYNC_LDS16(sBl + c * 8, Btl + gb);
        }
        __syncthreads();
        bf16x8 ah[4], al[4], bh[4], bl[4];
#pragma unroll
        for (int m = 0; m < 4; ++m) {
            int off = (wr * 64 + m * 16 + (lane & 15)) * 32 + (lane >> 4) * 8;
            ah[m] = *(const bf16x8*)(sAh + off);
            al[m] = *(const bf16x8*)(sAl + off);
        }
#pragma unroll
        for (int n = 0; n < 4; ++n) {
            int off = (wc * 64 + n * 16 + (lane & 15)) * 32 + (lane >> 4) * 8;
            bh[n] = *(const bf16x8*)(sBh + off);
            bl[n] = *(const bf16x8*)(sBl + off);
        }
#pragma unroll
        for (int m = 0; m < 4; ++m)
#pragma unroll
            for (int n = 0; n < 4; ++n) {
                acc[m][n] = __builtin_amdgcn_mfma_f32_16x16x32_bf16(ah[m], bh[n], acc[m][n], 0, 0, 0);
                acc[m][n] = __builtin_amdgcn_mfma_f32_16x16x32_bf16(ah[m], bl[n], acc[m][n], 0, 0, 0);
                acc[m][n] = __builtin_amdgcn_mfma_f32_16x16x32_bf16(al[m], bh[n], acc[m][n], 0, 0, 0);
            }
    }
#pragma unroll
    for (int m = 0; m < 4; ++m) {
        int row = bm0 + wr * 64 + m * 16 + (lane >> 4) * 4;
#pragma unroll
        for (int n = 0; n < 4; ++n) {
            int col = bn0 + wc * 64 + n * 16 + (lane & 15);
#pragma unroll
            for (int j = 0; j < 4; ++j)
                Cout[(size_t)(row + j) * N + col] = acc[m][n][j];
        }
    }
}

// --------------------------------------------- RoPE + L2-normalize q,k in place
__global__ __launch_bounds__(256) void rope_kernel(float* __restrict__ X1,
                                                   const float2* __restrict__ cs) {
    int w = threadIdx.x >> 6, lane = threadIdx.x & 63;
    int p = blockIdx.x * 4 + w;            // (t,h) pair, 32768 total
    int t = p >> 4, h = p & 15;
    float2 c = cs[t * 32 + (lane & 31)];
#pragma unroll
    for (int which = 0; which < 2; ++which) {
        float* base = X1 + (size_t)t * NQKV + which * 1024 + h * 64;
        float x = base[lane];
        float xo = __shfl(x, lane ^ 32, 64);
        float r = (lane < 32) ? -xo : xo;
        float y = x * c.x + r * c.y;
        float ss = y * y;
#pragma unroll
        for (int m = 32; m; m >>= 1) ss += __shfl_xor(ss, m, 64);
        base[lane] = y * rsqrtf(ss + 1e-12f);
    }
}

// ===================== chunked delta-rule: shared helpers =====================
__device__ __forceinline__ void mm64_3p(const short* Ah, const short* Al,
                                        const short* Bh, const short* Bl,
                                        int w, int lane, fx4 acc[4]) {
#pragma unroll
    for (int k0 = 0; k0 < 64; k0 += 32) {
        int ao = (w * 16 + (lane & 15)) * LP + k0 + ((lane >> 4) * 8);
        bf16x8 ah = *(const bf16x8*)(Ah + ao);
        bf16x8 al = *(const bf16x8*)(Al + ao);
#pragma unroll
        for (int n = 0; n < 4; ++n) {
            int bo = (n * 16 + (lane & 15)) * LP + k0 + ((lane >> 4) * 8);
            bf16x8 bh = *(const bf16x8*)(Bh + bo);
            bf16x8 bl = *(const bf16x8*)(Bl + bo);
            acc[n] = __builtin_amdgcn_mfma_f32_16x16x32_bf16(ah, bh, acc[n], 0, 0, 0);
            acc[n] = __builtin_amdgcn_mfma_f32_16x16x32_bf16(ah, bl, acc[n], 0, 0, 0);
            acc[n] = __builtin_amdgcn_mfma_f32_16x16x32_bf16(al, bh, acc[n], 0, 0, 0);
        }
    }
}

__device__ __forceinline__ void split_write(short* h, short* l, int off, float x) {
    __hip_bfloat16 hb = __float2bfloat16(x);
    ((__hip_bfloat16*)h)[off] = hb;
    ((__hip_bfloat16*)l)[off] = __float2bfloat16(x - __bfloat162float(hb));
}

// ------------------------------------------------ phase A1 (solve, parallel)
__global__ __launch_bounds__(128) void phaseA1_kernel(const float* __restrict__ X1,
                                                      __hip_bfloat16* __restrict__ UvWT_hi,
                                                      __hip_bfloat16* __restrict__ UvWT_lo) {
    const int h = blockIdx.x & 15, c = blockIdx.x >> 4;
    const int tid = threadIdx.x, w = tid >> 6, lane = tid & 63;
    const int t0 = c * 64;

    __shared__ short b1h[64 * LP], b1l[64 * LP];   // K hi/lo
    __shared__ float sMT[64 * MP];                 // [s][t] (s<t) holds M[t][s]
    __shared__ float sLa[64], sB[64], sL[65], sGp[64];

    const float* k_g = X1 + (size_t)t0 * NQKV + 1024 + h * 64;
    const float* v_g = X1 + (size_t)t0 * NQKV + 2048 + h * 64;

    if (tid < 64) {
        float ga = X1[(size_t)(t0 + tid) * NQKV + 4096 + h];
        float gb = X1[(size_t)(t0 + tid) * NQKV + 4112 + h];
        float z = -ga;
        sLa[tid] = -(fmaxf(z, 0.f) + log1pf(expf(-fabsf(z))));
        sB[tid] = 1.f / (1.f + expf(-gb));
    }
    __syncthreads();
    if (tid < 64) {
        float v = sLa[tid];
#pragma unroll
        for (int off = 1; off < 64; off <<= 1) {
            float u = __shfl_up(v, off, 64);
            if (tid >= off) v += u;
        }
        sL[tid + 1] = v;
        if (tid == 0) sL[0] = 0.f;
    }
    __syncthreads();
    if (tid < 64) sGp[tid] = expf(sL[tid]);
    // stage K (split)
    for (int idx = tid; idx < 4096; idx += 128) {
        int r = idx >> 6, cc = idx & 63;
        float kv = k_g[(size_t)r * NQKV + cc];
        __hip_bfloat16 hb = __float2bfloat16(kv);
        ((__hip_bfloat16*)b1h)[r * LP + cc] = hb;
        ((__hip_bfloat16*)b1l)[r * LP + cc] = __float2bfloat16(kv - __bfloat162float(hb));
    }
    __syncthreads();

    // G = K K^T strips (2 waves x 2 strips of 16 rows); sMT[s][t] = M[t][s]
#pragma unroll
    for (int m = 0; m < 2; ++m) {
        int r0 = w * 32 + m * 16;
        fx4 acc[4];
#pragma unroll
        for (int n = 0; n < 4; ++n) acc[n] = {0.f, 0.f, 0.f, 0.f};
#pragma unroll
        for (int k0 = 0; k0 < 64; k0 += 32) {
            int ao = (r0 + (lane & 15)) * LP + k0 + ((lane >> 4) * 8);
            bf16x8 ah = *(const bf16x8*)(b1h + ao);
            bf16x8 al = *(const bf16x8*)(b1l + ao);
#pragma unroll
            for (int n = 0; n < 4; ++n) {
                int bo = (n * 16 + (lane & 15)) * LP + k0 + ((lane >> 4) * 8);
                bf16x8 bh = *(const bf16x8*)(b1h + bo);
                bf16x8 bl = *(const bf16x8*)(b1l + bo);
                acc[n] = __builtin_amdgcn_mfma_f32_16x16x32_bf16(ah, bh, acc[n], 0, 0, 0);
                acc[n] = __builtin_amdgcn_mfma_f32_16x16x32_bf16(ah, bl, acc[n], 0, 0, 0);
                acc[n] = __builtin_amdgcn_mfma_f32_16x16x32_bf16(al, bh, acc[n], 0, 0, 0);
            }
        }
#pragma unroll
        for (int n = 0; n < 4; ++n)
#pragma unroll
            for (int jj = 0; jj < 4; ++jj) {
                int t = r0 + (lane >> 4) * 4 + jj, s = n * 16 + (lane & 15);
                if (s < t) sMT[s * MP + t] = sB[t] * expf(sL[t] - sL[s + 1]) * acc[n][jj];
            }
    }
    __syncthreads();

    // register right-looking solve; thread j owns column j (0..127)
    const int j = tid;
    float rhs[64];
#pragma unroll
    for (int t = 0; t < 64; ++t) {
        float base;
        if (j < 64) {
            base = v_g[(size_t)t * NQKV + j];          // V direct from global
        } else {
            int i = j - 64;
            base = (__bfloat162float(((__hip_bfloat16*)b1h)[t * LP + i]) +
                    __bfloat162float(((__hip_bfloat16*)b1l)[t * LP + i])) * sGp[t];
        }
        rhs[t] = sB[t] * base;
    }
#pragma unroll
    for (int t = 0; t < 63; ++t) {
        float x = rhs[t];
        int s = t + 1;
#pragma unroll
        for (; (s & 3) && s < 64; ++s)
            rhs[s] = fmaf(-sMT[t * MP + s], x, rhs[s]);
#pragma unroll
        for (; s < 64; s += 4) {
            float4 m4 = *(const float4*)(sMT + t * MP + s);   // 16B-aligned (MP=68)
            rhs[s]     = fmaf(-m4.x, x, rhs[s]);
            rhs[s + 1] = fmaf(-m4.y, x, rhs[s + 1]);
            rhs[s + 2] = fmaf(-m4.z, x, rhs[s + 2]);
            rhs[s + 3] = fmaf(-m4.w, x, rhs[s + 3]);
        }
    }
    // write out t-major (coalesced): UvWT[hc][t][j]
    size_t obase = (size_t)(h * 32 + c) * 8192;
#pragma unroll
    for (int t = 0; t < 64; ++t) {
        __hip_bfloat16 hb = __float2bfloat16(rhs[t]);
        UvWT_hi[obase + t * 128 + j] = hb;
        UvWT_lo[obase + t * 128 + j] = __float2bfloat16(rhs[t] - __bfloat162float(hb));
    }
}

// ------------------------------------------------ phase A2 (matmuls, parallel)
__global__ __launch_bounds__(256) void phaseA2_kernel(float* __restrict__ X1,
                                                      const __hip_bfloat16* __restrict__ UvWT_hi,
                                                      const __hip_bfloat16* __restrict__ UvWT_lo,
                                                      short* __restrict__ AcBuf,
                                                      float* __restrict__ BcBuf) {
    const int h = blockIdx.x & 15, c = blockIdx.x >> 4;
    const int tid = threadIdx.x, w = tid >> 6, lane = tid & 63;
    const int t0 = c * 64;

    __shared__ short b1h[64 * LP], b1l[64 * LP];   // K
    __shared__ short b2h[64 * LP], b2l[64 * LP];   // Q -> Ptilde -> KhatT
    __shared__ short b3h[64 * LP], b3l[64 * LP];   // UvT
    __shared__ short b4h[64 * LP], b4l[64 * LP];   // WT
    __shared__ float sLa[64], sL[65], sGp[64], sRc[64];

    const float* q_g = X1 + (size_t)t0 * NQKV + h * 64;
    const float* k_g = q_g + 1024;

    if (tid < 64) {
        float ga = X1[(size_t)(t0 + tid) * NQKV + 4096 + h];
        float z = -ga;
        sLa[tid] = -(fmaxf(z, 0.f) + log1pf(expf(-fabsf(z))));
    }
    __syncthreads();
    if (tid < 64) {
        float v = sLa[tid];
#pragma unroll
        for (int off = 1; off < 64; off <<= 1) {
            float u = __shfl_up(v, off, 64);
            if (tid >= off) v += u;
        }
        sL[tid + 1] = v;
        if (tid == 0) sL[0] = 0.f;
    }
    __syncthreads();
    if (tid < 64) {
        sGp[tid] = expf(sL[tid]);
        sRc[tid] = expf(sL[64] - sL[tid + 1]);
    }
    // stage Q, K (split) and UvT/WT
    for (int idx = tid; idx < 4096; idx += 256) {
        int r = idx >> 6, cc = idx & 63;
        split_write(b2h, b2l, r * LP + cc, q_g[(size_t)r * NQKV + cc]);
        split_write(b1h, b1l, r * LP + cc, k_g[(size_t)r * NQKV + cc]);
    }
    const __hip_bfloat16* uh = UvWT_hi + (size_t)(h * 32 + c) * 8192;
    const __hip_bfloat16* ul = UvWT_lo + (size_t)(h * 32 + c) * 8192;
    for (int idx = tid; idx < 8192; idx += 256) {
        int t = idx >> 7, row = idx & 127;
        short* dh = (row < 64) ? b3h : b4h;
        short* dl = (row < 64) ? b3l : b4l;
        ((__hip_bfloat16*)dh)[(row & 63) * LP + t] = uh[idx];
        ((__hip_bfloat16*)dl)[(row & 63) * LP + t] = ul[idx];
    }
    __syncthreads();

    // P = Q K^T
    fx4 pacc[4];
#pragma unroll
    for (int n = 0; n < 4; ++n) pacc[n] = {0.f, 0.f, 0.f, 0.f};
    mm64_3p(b2h, b2l, b1h, b1l, w, lane, pacc);
    __syncthreads();
    // Ptilde -> b2 (masked, scaled)
#pragma unroll
    for (int n = 0; n < 4; ++n)
#pragma unroll
        for (int jj = 0; jj < 4; ++jj) {
            int t = w * 16 + (lane >> 4) * 4 + jj, s = n * 16 + (lane & 15);
            float pv = (s < t) ? expf(sL[t] - sL[s + 1]) * pacc[n][jj] : 0.f;
            split_write(b2h, b2l, t * LP + s, pv);
        }
    __syncthreads();

    // Olocal = Ptilde @ Uv -> overwrite k-region (f32)
    {
        fx4 acc[4];
#pragma unroll
        for (int n = 0; n < 4; ++n) acc[n] = {0.f, 0.f, 0.f, 0.f};
        mm64_3p(b2h, b2l, b3h, b3l, w, lane, acc);
        float* og = X1 + (size_t)t0 * NQKV + 1024 + h * 64;
#pragma unroll
        for (int n = 0; n < 4; ++n)
#pragma unroll
            for (int jj = 0; jj < 4; ++jj) {
                int t = w * 16 + (lane >> 4) * 4 + jj, s = n * 16 + (lane & 15);
                og[(size_t)t * NQKV + s] = acc[n][jj];
            }
    }
    // PW = Ptilde @ W ; Qeff = diag(gprev)Q - PW -> overwrite q-region (f32)
    {
        fx4 acc[4];
#pragma unroll
        for (int n = 0; n < 4; ++n) acc[n] = {0.f, 0.f, 0.f, 0.f};
        mm64_3p(b2h, b2l, b4h, b4l, w, lane, acc);
        float* qg = X1 + (size_t)t0 * NQKV + h * 64;
#pragma unroll
        for (int n = 0; n < 4; ++n)
#pragma unroll
            for (int jj = 0; jj < 4; ++jj) {
                int t = w * 16 + (lane >> 4) * 4 + jj, s = n * 16 + (lane & 15);
                float qv = qg[(size_t)t * NQKV + s];
                qg[(size_t)t * NQKV + s] = sGp[t] * qv - acc[n][jj];
            }
    }
    __syncthreads();   // all reads of b2 (Ptilde) complete
    // KhatT -> b2: [i][s] = rC[s] * K[s][i]
    for (int idx = tid; idx < 4096; idx += 256) {
        int s = idx >> 6, i = idx & 63;
        float kv = __bfloat162float(((__hip_bfloat16*)b1h)[s * LP + i]) +
                   __bfloat162float(((__hip_bfloat16*)b1l)[s * LP + i]);
        split_write(b2h, b2l, i * LP + s, sRc[s] * kv);
    }
    __syncthreads();

    // Ac = gammaEnd*I - KhatT @ W -> AcBuf (bf16 hi/lo, row-major [i][j])
    {
        fx4 acc[4];
#pragma unroll
        for (int n = 0; n < 4; ++n) acc[n] = {0.f, 0.f, 0.f, 0.f};
        mm64_3p(b2h, b2l, b4h, b4l, w, lane, acc);
        float gend = expf(sL[64]);
        size_t abase = (size_t)(h * 32 + c) * 8192;
#pragma unroll
        for (int n = 0; n < 4; ++n)
#pragma unroll
            for (int jj = 0; jj < 4; ++jj) {
                int i = w * 16 + (lane >> 4) * 4 + jj, jd = n * 16 + (lane & 15);
                float av = ((i == jd) ? gend : 0.f) - acc[n][jj];
                __hip_bfloat16 hb = __float2bfloat16(av);
                ((__hip_bfloat16*)AcBuf)[abase + i * 64 + jd] = hb;
                ((__hip_bfloat16*)AcBuf)[abase + 4096 + i * 64 + jd] =
                    __float2bfloat16(av - __bfloat162float(hb));
            }
    }
    // BcT = UvT @ KhatT' -> BcBuf (f32, [v][i])
    {
        fx4 acc[4];
#pragma unroll
        for (int n = 0; n < 4; ++n) acc[n] = {0.f, 0.f, 0.f, 0.f};
        mm64_3p(b3h, b3l, b2h, b2l, w, lane, acc);
        size_t bbase = (size_t)(h * 32 + c) * 4096;
#pragma unroll
        for (int n = 0; n < 4; ++n)
#pragma unroll
            for (int jj = 0; jj < 4; ++jj) {
                int jv = w * 16 + (lane >> 4) * 4 + jj, i = n * 16 + (lane & 15);
                BcBuf[bbase + jv * 64 + i] = acc[n][jj];
            }
    }
}

// --------------------------------------------------- phase B (state recurrence)
// 16 blocks (1/head) x 4 waves. Wave w owns v-rows [w*16, w*16+16) of S^T.
// Ac double-buffered in LDS via global_load_lds (async; the iteration-top
// barrier's vmcnt(0) drain is the completion wait -> one-iteration overlap).
// S^T C-layout -> A-layout redistribution is INTRA-wave (same 16 rows), so
// only ONE barrier per iteration. MFMA order identical to round 5.
__global__ __launch_bounds__(256) void phaseB_kernel(const short* __restrict__ AcBuf,
                                                     const float* __restrict__ BcBuf,
                                                     float* __restrict__ X1) {
    const int h = blockIdx.x;
    const int tid = threadIdx.x, w = tid >> 6, lane = tid & 63;
    const int lr = (lane >> 4) * 4;                // C-layout row offset
    const int lc = lane & 15;                      // C-layout col offset
    __shared__ short sAc[2][8192];                 // [hi 4096 | lo 4096] shorts, row stride 64
    __shared__ float sST[64 * 68];                 // S^T staging (intra-wave)

    const size_t hc0 = (size_t)h * 32;
    // prologue: async-stage Ac[0] into buf 0 (lane-linear copy, 16KB)
    {
        const char* src = (const char*)AcBuf + hc0 * 16384;
        char* dst = (char*)&sAc[0][0];
        int off = w * 4096 + lane * 16;
#pragma unroll
        for (int q = 0; q < 4; ++q) { ASYNC_LDS16(dst + off, src + off); off += 1024; }
    }
    fx4 acc[4];
#pragma unroll
    for (int n = 0; n < 4; ++n) acc[n] = {0.f, 0.f, 0.f, 0.f};
    float bcur[16];
    {
        const float* bg = BcBuf + hc0 * 4096;
#pragma unroll
        for (int n = 0; n < 4; ++n)
#pragma unroll
            for (int jj = 0; jj < 4; ++jj)
                bcur[n * 4 + jj] = bg[(w * 16 + lr + jj) * 64 + n * 16 + lc];
    }

#pragma unroll 1
    for (int c = 0; c < 32; ++c) {
        // barrier: (a) Ac[c] async loads drained (vmcnt0 before s_barrier),
        // (b) all waves done reading buf[(c+1)&1] from iteration c-1.
        __syncthreads();
        // issue Ac[c+1] into the other buffer (completes by next barrier)
        {
            int cn = (c < 31) ? c + 1 : 31;
            const char* src = (const char*)AcBuf + (hc0 + cn) * 16384;
            char* dst = (char*)&sAc[(c + 1) & 1][0];
            int off = w * 4096 + lane * 16;
#pragma unroll
            for (int q = 0; q < 4; ++q) { ASYNC_LDS16(dst + off, src + off); off += 1024; }
        }
        // prefetch Bc[c+1] (16 regs; latency overlaps this iteration)
        float bnext[16];
        {
            int cn = (c < 31) ? c + 1 : 31;
            const float* bg = BcBuf + (hc0 + cn) * 4096;
#pragma unroll
            for (int n = 0; n < 4; ++n)
#pragma unroll
                for (int jj = 0; jj < 4; ++jj)
                    bnext[n * 4 + jj] = bg[(w * 16 + lr + jj) * 64 + n * 16 + lc];
        }
        // store state entering chunk c (fire & forget; drained at next barrier)
        // and stage S^T rows for the A-operand (intra-wave LDS redistribution)
        float* stg = X1 + (size_t)(c * 64) * NQKV + 2048 + h * 64;
#pragma unroll
        for (int n = 0; n < 4; ++n)
#pragma unroll
            for (int jj = 0; jj < 4; ++jj) {
                int r = w * 16 + lr + jj, i = n * 16 + lc;
                stg[(size_t)r * NQKV + i] = acc[n][jj];
                sST[r * 68 + i] = acc[n][jj];
            }
        // nacc = Bc[c] + S^T @ Ac[c]'  (same product order as round 5)
        const short* bufc = &sAc[c & 1][0];
        fx4 nacc[4];
#pragma unroll
        for (int n = 0; n < 4; ++n)
            nacc[n] = {bcur[n * 4 + 0], bcur[n * 4 + 1], bcur[n * 4 + 2], bcur[n * 4 + 3]};
#pragma unroll
        for (int k0 = 0; k0 < 2; ++k0) {
            const float* ap = sST + (w * 16 + lc) * 68 + k0 * 32 + (lane >> 4) * 8;
            float4 f0 = *(const float4*)ap;
            float4 f1 = *(const float4*)(ap + 4);
            float fv[8] = {f0.x, f0.y, f0.z, f0.w, f1.x, f1.y, f1.z, f1.w};
            bf16x8 afh, afl;
#pragma unroll
            for (int e = 0; e < 8; ++e) {
                __hip_bfloat16 hb = __float2bfloat16(fv[e]);
                __hip_bfloat16 lb = __float2bfloat16(fv[e] - __bfloat162float(hb));
                afh[e] = *(__bf16*)&hb;
                afl[e] = *(__bf16*)&lb;
            }
#pragma unroll
            for (int n = 0; n < 4; ++n) {
                int ro = (n * 16 + lc) * 64 + k0 * 32 + (lane >> 4) * 8;   // shorts
                bf16x8 bh = *(const bf16x8*)(bufc + ro);
                bf16x8 bl = *(const bf16x8*)(bufc + 4096 + ro);
                nacc[n] = __builtin_amdgcn_mfma_f32_16x16x32_bf16(afh, bh, nacc[n], 0, 0, 0);
                nacc[n] = __builtin_amdgcn_mfma_f32_16x16x32_bf16(afh, bl, nacc[n], 0, 0, 0);
                nacc[n] = __builtin_amdgcn_mfma_f32_16x16x32_bf16(afl, bh, nacc[n], 0, 0, 0);
            }
        }
#pragma unroll
        for (int n = 0; n < 4; ++n) acc[n] = nacc[n];
#pragma unroll
        for (int e = 0; e < 16; ++e) bcur[e] = bnext[e];
    }
}

// --------------------------------------------- phase C (outputs + epilogue)
__global__ __launch_bounds__(256) void phaseC_kernel(const float* __restrict__ X1,
                                                     const float* __restrict__ onw,
                                                     __hip_bfloat16* __restrict__ attn_bf) {
    const int h = blockIdx.x & 15, c = blockIdx.x >> 4;
    const int tid = threadIdx.x, w = tid >> 6, lane = tid & 63;
    const int t0 = c * 64;
    __shared__ short qh[64 * LP], ql[64 * LP];
    __shared__ short sh_[64 * LP], sl_[64 * LP];
    __shared__ float sO[4096];
    __shared__ float part[64][4];
    const float* qe = X1 + (size_t)t0 * NQKV + h * 64;          // Qeff
    const float* stg = X1 + (size_t)t0 * NQKV + 2048 + h * 64;  // S^T (entering c)
    const float* ol = X1 + (size_t)t0 * NQKV + 1024 + h * 64;   // Olocal
    for (int idx = tid; idx < 4096; idx += 256) {
        int r = idx >> 6, i = idx & 63;
        split_write(qh, ql, r * LP + i, qe[(size_t)r * NQKV + i]);
        split_write(sh_, sl_, r * LP + i, stg[(size_t)r * NQKV + i]);
    }
    __syncthreads();
    fx4 acc[4];
#pragma unroll
    for (int n = 0; n < 4; ++n)
#pragma unroll
        for (int jj = 0; jj < 4; ++jj)
            acc[n][jj] = ol[(size_t)(w * 16 + (lane >> 4) * 4 + jj) * NQKV + n * 16 + (lane & 15)];
    mm64_3p(qh, ql, sh_, sl_, w, lane, acc);
#pragma unroll
    for (int n = 0; n < 4; ++n)
#pragma unroll
        for (int jj = 0; jj < 4; ++jj)
            sO[(w * 16 + (lane >> 4) * 4 + jj) * 64 + n * 16 + (lane & 15)] = acc[n][jj];
    __syncthreads();
    int r = tid >> 2, qq = tid & 3;
    float ss = 0.f;
#pragma unroll
    for (int i2 = 0; i2 < 16; ++i2) { float v = sO[r * 64 + qq * 16 + i2]; ss += v * v; }
    part[r][qq] = ss;
    __syncthreads();
    float tot = part[r][0] + part[r][1] + part[r][2] + part[r][3];
    float sc = rsqrtf(tot * (1.f / 64.f) + 1e-6f);
    const float* gg = X1 + (size_t)(t0 + r) * NQKV + 3072 + h * 64;
#pragma unroll
    for (int i2 = 0; i2 < 16; ++i2) {
        int j = qq * 16 + i2;
        float on = sO[r * 64 + j] * sc * onw[j];
        float g = gg[j];
        float sg = g / (1.f + expf(-g));
        attn_bf[(size_t)(t0 + r) * 1024 + h * 64 + j] = __float2bfloat16(on * sg);
    }
}

// ---------------------------- h = hidden + attn (in place); ybf = rmsnorm(h)
__global__ __launch_bounds__(256) void add_rmsnorm_kernel(
    const float* __restrict__ hidden, float* __restrict__ acc,
    const float* __restrict__ w, __hip_bfloat16* __restrict__ out) {
    int t = blockIdx.x;
    int d = threadIdx.x * 4;
    float4 a = *(const float4*)(acc + (size_t)t * D_MODEL + d);
    float4 hd = *(const float4*)(hidden + (size_t)t * D_MODEL + d);
    float4 h4 = make_float4(a.x + hd.x, a.y + hd.y, a.z + hd.z, a.w + hd.w);
    *(float4*)(acc + (size_t)t * D_MODEL + d) = h4;
    float ss = h4.x * h4.x + h4.y * h4.y + h4.z * h4.z + h4.w * h4.w;
#pragma unroll
    for (int m = 32; m; m >>= 1) ss += __shfl_xor(ss, m, 64);
    __shared__ float wsum[4];
    if ((threadIdx.x & 63) == 0) wsum[threadIdx.x >> 6] = ss;
    __syncthreads();
    float tot = wsum[0] + wsum[1] + wsum[2] + wsum[3];
    float sc = rsqrtf(tot * (1.f / 1024.f) + 1e-6f);
    const float4 wv = *(const float4*)(w + d);
    __hip_bfloat16* op = out + (size_t)t * D_MODEL + d;
    op[0] = __float2bfloat16(h4.x * sc * wv.x);
    op[1] = __float2bfloat16(h4.y * sc * wv.y);
    op[2] = __float2bfloat16(h4.z * sc * wv.z);
    op[3] = __float2bfloat16(h4.w * sc * wv.w);
}

// ---------------------------------------------- m = silu(G) * U (bf16 in/out)
__global__ __launch_bounds__(256) void silu_mul_kernel(const __hip_bfloat16* __restrict__ GU,
                                                       __hip_bfloat16* __restrict__ m) {
    size_t i = (size_t)blockIdx.x * 256 + threadIdx.x;   // 2048*4096
    size_t t = i >> 12, j = i & 4095;
    float g = __bfloat162float(GU[t * 8192 + j]);
    float u = __bfloat162float(GU[t * 8192 + 4096 + j]);
    m[i] = __float2bfloat16(u * g / (1.f + expf(-g)));
}

// ----------------------------------------------------------- out += h
__global__ __launch_bounds__(256) void final_add_kernel(float* __restrict__ out,
                                                        const float* __restrict__ h) {
    size_t i = (size_t)blockIdx.x * 256 + threadIdx.x;
    out[i] += h[i];
}

// ---------------------------------------------------------------------------
extern "C" void kernel_launch(void* const* d_in, const int* in_sizes, int n_in,
                              void* d_out, int out_size, void* d_ws, size_t ws_size,
                              hipStream_t stream) {
    (void)in_sizes; (void)n_in; (void)out_size; (void)ws_size;
    const float* hidden     = (const float*)d_in[0];
    const float* norm1_w    = (const float*)d_in[1];
    const float* q_w        = (const float*)d_in[2];
    const float* k_w        = (const float*)d_in[3];
    const float* v_w        = (const float*)d_in[4];
    const float* g_w        = (const float*)d_in[5];
    const float* b_w        = (const float*)d_in[6];
    const float* gate_w     = (const float*)d_in[7];
    const float* o_norm_w   = (const float*)d_in[8];
    const float* o_w        = (const float*)d_in[9];
    const float* norm2_w    = (const float*)d_in[10];
    const float* mlp_gate_w = (const float*)d_in[11];
    const float* mlp_up_w   = (const float*)d_in[12];
    const float* mlp_down_w = (const float*)d_in[13];

    char* ws = (char*)d_ws;
    // workspace (~92 MiB), timeline-reused:
    const size_t OFF_WT_QKVG = 0;          // wt_qkvg_hi -> AcBuf
    const size_t OFF_WT_O    = 8650752;
    const size_t OFF_WT_GU   = 10747904;
    const size_t OFF_WT_DOWN = 27525120;
    const size_t OFF_X1      = 35913728;   // X1 f32 -> GU bf16
    const size_t OFF_R1      = 70516736;   // wt_qkvg_lo -> BcBuf -> mbf
    const size_t OFF_ATTN    = 79167488;   // UvWT_lo (A1/A2) -> attn_bf+ybf
    const size_t OFF_YBF     = 83361792;
    const size_t OFF_XHI     = 87556096;   // xhi/xlo -> UvWT_hi -> h_buf
    const size_t OFF_XLO     = 91750400;
    const size_t OFF_ROPE    = 95944704;

    __hip_bfloat16* wt_qkvg_hi = (__hip_bfloat16*)(ws + OFF_WT_QKVG);
    __hip_bfloat16* wt_qkvg_lo = (__hip_bfloat16*)(ws + OFF_R1);
    __hip_bfloat16* wt_o    = (__hip_bfloat16*)(ws + OFF_WT_O);
    __hip_bfloat16* wt_gu   = (__hip_bfloat16*)(ws + OFF_WT_GU);
    __hip_bfloat16* wt_down = (__hip_bfloat16*)(ws + OFF_WT_DOWN);
    float*          X1      = (float*)(ws + OFF_X1);
    __hip_bfloat16* GU      = (__hip_bfloat16*)(ws + OFF_X1);
    short*          AcBuf   = (short*)(ws + OFF_WT_QKVG);       // after qkv gemm
    float*          BcBuf   = (float*)(ws + OFF_R1);            // after qkv gemm
    __hip_bfloat16* mbf     = (__hip_bfloat16*)(ws + OFF_R1);   // after phase B/C
    __hip_bfloat16* attn_bf = (__hip_bfloat16*)(ws + OFF_ATTN);
    __hip_bfloat16* xhi     = (__hip_bfloat16*)(ws + OFF_XHI);
    __hip_bfloat16* xlo     = (__hip_bfloat16*)(ws + OFF_XLO);
    __hip_bfloat16* UvWT_hi = (__hip_bfloat16*)(ws + OFF_XHI);  // 8.39MB, after qkv gemm
    __hip_bfloat16* UvWT_lo = (__hip_bfloat16*)(ws + OFF_ATTN); // 8.39MB, until phaseC
    float*          h_buf   = (float*)(ws + OFF_XHI);           // after phaseA2
    __hip_bfloat16* ybf     = (__hip_bfloat16*)(ws + OFF_YBF);
    float2*         rope_cs = (float2*)(ws + OFF_ROPE);

    dim3 tb(32, 8);
    rope_table_kernel<<<256, 256, 0, stream>>>(rope_cs);
    rmsnorm_split_kernel<<<2048, 256, 0, stream>>>(hidden, norm1_w, xhi, xlo);
    transpose_split_kernel<<<dim3(32, 32), tb, 0, stream>>>(q_w,    wt_qkvg_hi,               wt_qkvg_lo,               1024, 1024, 1024);
    transpose_split_kernel<<<dim3(32, 32), tb, 0, stream>>>(k_w,    wt_qkvg_hi + 1024 * 1024, wt_qkvg_lo + 1024 * 1024, 1024, 1024, 1024);
    transpose_split_kernel<<<dim3(32, 32), tb, 0, stream>>>(v_w,    wt_qkvg_hi + 2048 * 1024, wt_qkvg_lo + 2048 * 1024, 1024, 1024, 1024);
    transpose_split_kernel<<<dim3(32, 32), tb, 0, stream>>>(gate_w, wt_qkvg_hi + 3072 * 1024, wt_qkvg_lo + 3072 * 1024, 1024, 1024, 1024);
    transpose_split_kernel<<<dim3(32, 1),  tb, 0, stream>>>(g_w,    wt_qkvg_hi + 4096 * 1024, wt_qkvg_lo + 4096 * 1024, 1024, 16,   16);
    transpose_split_kernel<<<dim3(32, 4),  tb, 0, stream>>>(b_w,    wt_qkvg_hi + 4112 * 1024, wt_qkvg_lo + 4112 * 1024, 1024, 16,   112);
    transpose_bf16_kernel<<<dim3(32, 32),  tb, 0, stream>>>(o_w,        wt_o,                1024, 1024, 1024);
    transpose_bf16_kernel<<<dim3(32, 128), tb, 0, stream>>>(mlp_gate_w, wt_gu,               1024, 4096, 4096);
    transpose_bf16_kernel<<<dim3(32, 128), tb, 0, stream>>>(mlp_up_w,   wt_gu + 4096 * 1024, 1024, 4096, 4096);
    transpose_bf16_kernel<<<dim3(128, 32), tb, 0, stream>>>(mlp_down_w, wt_down,             4096, 1024, 1024);
    // fused q|k|v|gate|g|b projection (split precision)
    gemm_bt_split<<<dim3(33, 16), 256, 0, stream>>>(xhi, xlo, wt_qkvg_hi, wt_qkvg_lo, X1, 2048, NQKV, 1024);
    rope_kernel<<<8192, 256, 0, stream>>>(X1, rope_cs);
    // chunked delta-rule scan
    phaseA1_kernel<<<512, 128, 0, stream>>>(X1, UvWT_hi, UvWT_lo);
    phaseA2_kernel<<<512, 256, 0, stream>>>(X1, UvWT_hi, UvWT_lo, AcBuf, BcBuf);
    phaseB_kernel<<<16, 256, 0, stream>>>(AcBuf, BcBuf, X1);
    phaseC_kernel<<<512, 256, 0, stream>>>(X1, o_norm_w, attn_bf);
    // attn out projection -> h
    gemm_bt<false><<<dim3(8, 16), 256, 0, stream>>>(attn_bf, wt_o, h_buf, 2048, 1024, 1024);
    add_rmsnorm_kernel<<<2048, 256, 0, stream>>>(hidden, h_buf, norm2_w, ybf);
    gemm_bt<true><<<dim3(64, 16), 256, 0, stream>>>(ybf, wt_gu, GU, 2048, 8192, 1024);
    silu_mul_kernel<<<32768, 256, 0, stream>>>(GU, mbf);
    gemm_bt<false><<<dim3(8, 16), 256, 0, stream>>>(mbf, wt_down, (float*)d_out, 2048, 1024, 4096);
    final_add_kernel<<<8192, 256, 0, stream>>>((float*)d_out, h_buf);
}

// Round 10
// 457.348 us; speedup vs baseline: 1.4192x; 1.0817x over previous
//
#include <hip/hip_runtime.h>
#include <hip/hip_bf16.h>

// ---------------------------------------------------------------------------
// DepthDeltaNetDecoderLayer: B=1, T=2048, D=1024, H=16, DK=DV=64, FF=4096
// Round 9: fix round-8 NaN. The blocked solve's corr MFMA (K=32, A zero-padded
// for k>=16) reads B from XT at k in [J*16, J*16+32) — touching the
// not-yet-written panel I. Uninitialized LDS can hold NaN bit patterns and
// 0*NaN=NaN in the MFMA accumulator. Fix: zero-init XT at kernel start.
// Everything else identical to round 8.
// ---------------------------------------------------------------------------

#define T_SEQ 2048
#define D_MODEL 1024
#define NH 16
#define DK 64
#define DV 64
#define FF 4096
#define NQKV 4224   // q(1024) k(1024) v(1024) gate(1024) g(16@4096) b(16@4112) pad->4224
#define LP 72       // padded LDS stride (shorts), 144B rows (16B-aligned)
#define MP 68       // padded stride (floats) for M^T

typedef __bf16 bf16x8 __attribute__((ext_vector_type(8)));
typedef float  fx4    __attribute__((ext_vector_type(4)));

#if defined(__has_builtin)
#if __has_builtin(__builtin_amdgcn_global_load_lds)
#define HAVE_GLOAD_LDS 1
#endif
#endif

#ifdef HAVE_GLOAD_LDS
#define ASYNC_LDS16(dst, src)                                                   \
    __builtin_amdgcn_global_load_lds(                                           \
        (__attribute__((address_space(1))) void*)(src),                         \
        (__attribute__((address_space(3))) void*)(dst), 16, 0, 0)
#else
#define ASYNC_LDS16(dst, src) (*(int4*)(dst) = *(const int4*)(src))
#endif

// ---------------------------------------------------------------- rope table
__global__ void rope_table_kernel(float2* __restrict__ cs) {
    int idx = blockIdx.x * 256 + threadIdx.x;      // t*32 + i, 65536 total
    int t = idx >> 5, i = idx & 31;
    float freq = (float)t * powf(10000.f, -(float)i / 32.f);
    cs[idx] = make_float2(cosf(freq), sinf(freq));
}

// --------------------------------------- row rmsnorm -> bf16 hi + bf16 lo
__global__ __launch_bounds__(256) void rmsnorm_split_kernel(
    const float* __restrict__ in, const float* __restrict__ w,
    __hip_bfloat16* __restrict__ hi, __hip_bfloat16* __restrict__ lo) {
    int t = blockIdx.x;
    int d = threadIdx.x * 4;
    const float4 v = *(const float4*)(in + (size_t)t * D_MODEL + d);
    float ss = v.x * v.x + v.y * v.y + v.z * v.z + v.w * v.w;
#pragma unroll
    for (int m = 32; m; m >>= 1) ss += __shfl_xor(ss, m, 64);
    __shared__ float wsum[4];
    if ((threadIdx.x & 63) == 0) wsum[threadIdx.x >> 6] = ss;
    __syncthreads();
    float tot = wsum[0] + wsum[1] + wsum[2] + wsum[3];
    float sc = rsqrtf(tot * (1.f / 1024.f) + 1e-6f);
    const float4 wv = *(const float4*)(w + d);
    float xs[4] = {v.x * sc * wv.x, v.y * sc * wv.y, v.z * sc * wv.z, v.w * sc * wv.w};
    __hip_bfloat16* hp = hi + (size_t)t * D_MODEL + d;
    __hip_bfloat16* lp = lo + (size_t)t * D_MODEL + d;
#pragma unroll
    for (int j = 0; j < 4; ++j) {
        __hip_bfloat16 h = __float2bfloat16(xs[j]);
        hp[j] = h;
        lp[j] = __float2bfloat16(xs[j] - __bfloat162float(h));
    }
}

// ------------------------------------------- W (KxN f32) -> Wt (Npad x K bf16)
__global__ void transpose_bf16_kernel(const float* __restrict__ W,
                                      __hip_bfloat16* __restrict__ Wt,
                                      int K, int N, int Npad) {
    __shared__ float tile[32][33];
    int k0 = blockIdx.x * 32, n0 = blockIdx.y * 32;
    int tx = threadIdx.x, ty = threadIdx.y;   // (32,8)
#pragma unroll
    for (int i = 0; i < 32; i += 8) {
        int n = n0 + tx;
        tile[ty + i][tx] = (n < N) ? W[(size_t)(k0 + ty + i) * N + n] : 0.f;
    }
    __syncthreads();
#pragma unroll
    for (int i = 0; i < 32; i += 8) {
        int n = n0 + ty + i;
        if (n < Npad) Wt[(size_t)n * K + k0 + tx] = __float2bfloat16(tile[tx][ty + i]);
    }
}

// ---------------------- W (KxN f32) -> Wt_hi, Wt_lo (Npad x K bf16 each)
__global__ void transpose_split_kernel(const float* __restrict__ W,
                                       __hip_bfloat16* __restrict__ Wt_hi,
                                       __hip_bfloat16* __restrict__ Wt_lo,
                                       int K, int N, int Npad) {
    __shared__ float tile[32][33];
    int k0 = blockIdx.x * 32, n0 = blockIdx.y * 32;
    int tx = threadIdx.x, ty = threadIdx.y;   // (32,8)
#pragma unroll
    for (int i = 0; i < 32; i += 8) {
        int n = n0 + tx;
        tile[ty + i][tx] = (n < N) ? W[(size_t)(k0 + ty + i) * N + n] : 0.f;
    }
    __syncthreads();
#pragma unroll
    for (int i = 0; i < 32; i += 8) {
        int n = n0 + ty + i;
        if (n < Npad) {
            float x = tile[tx][ty + i];
            __hip_bfloat16 h = __float2bfloat16(x);
            Wt_hi[(size_t)n * K + k0 + tx] = h;
            Wt_lo[(size_t)n * K + k0 + tx] = __float2bfloat16(x - __bfloat162float(h));
        }
    }
}

// ------------------------------------------------------------------- GEMM
// A: MxK bf16 row-major; Bt: NxK bf16 row-major (B transposed); C: MxN.
template <bool OUT_BF16>
__global__ __launch_bounds__(256) void gemm_bt(
    const __hip_bfloat16* __restrict__ A, const __hip_bfloat16* __restrict__ Bt,
    void* __restrict__ Cout, int M, int N, int K) {
    __shared__ short sA[128 * 32];
    __shared__ short sB[128 * 32];
    const int tid = threadIdx.x;
    const int w = tid >> 6, lane = tid & 63;
    const int bn0 = blockIdx.x * 128, bm0 = blockIdx.y * 128;
    const int wr = w >> 1, wc = w & 1;

    fx4 acc[4][4];
#pragma unroll
    for (int m = 0; m < 4; ++m)
#pragma unroll
        for (int n = 0; n < 4; ++n) acc[m][n] = {0.f, 0.f, 0.f, 0.f};

    for (int k0 = 0; k0 < K; k0 += 32) {
        __syncthreads();
#pragma unroll
        for (int i = 0; i < 2; ++i) {
            int c = i * 256 + tid;
            int r = c >> 2, kk = (c & 3) * 8;
            ASYNC_LDS16(sA + c * 8, A + (size_t)(bm0 + r) * K + k0 + kk);
            ASYNC_LDS16(sB + c * 8, Bt + (size_t)(bn0 + r) * K + k0 + kk);
        }
        __syncthreads();
        bf16x8 af[4], bfv[4];
#pragma unroll
        for (int m = 0; m < 4; ++m)
            af[m] = *(const bf16x8*)(sA + (wr * 64 + m * 16 + (lane & 15)) * 32 + (lane >> 4) * 8);
#pragma unroll
        for (int n = 0; n < 4; ++n)
            bfv[n] = *(const bf16x8*)(sB + (wc * 64 + n * 16 + (lane & 15)) * 32 + (lane >> 4) * 8);
#pragma unroll
        for (int m = 0; m < 4; ++m)
#pragma unroll
            for (int n = 0; n < 4; ++n)
                acc[m][n] = __builtin_amdgcn_mfma_f32_16x16x32_bf16(af[m], bfv[n], acc[m][n], 0, 0, 0);
    }
#pragma unroll
    for (int m = 0; m < 4; ++m) {
        int row = bm0 + wr * 64 + m * 16 + (lane >> 4) * 4;
#pragma unroll
        for (int n = 0; n < 4; ++n) {
            int col = bn0 + wc * 64 + n * 16 + (lane & 15);
#pragma unroll
            for (int j = 0; j < 4; ++j) {
                float val = acc[m][n][j];
                if (OUT_BF16)
                    ((__hip_bfloat16*)Cout)[(size_t)(row + j) * N + col] = __float2bfloat16(val);
                else
                    ((float*)Cout)[(size_t)(row + j) * N + col] = val;
            }
        }
    }
}

// ------------------------------------- split-precision GEMM (3 bf16 products)
__global__ __launch_bounds__(256) void gemm_bt_split(
    const __hip_bfloat16* __restrict__ Ah, const __hip_bfloat16* __restrict__ Al,
    const __hip_bfloat16* __restrict__ Bth, const __hip_bfloat16* __restrict__ Btl,
    float* __restrict__ Cout, int M, int N, int K) {
    __shared__ short sAh[128 * 32];
    __shared__ short sAl[128 * 32];
    __shared__ short sBh[128 * 32];
    __shared__ short sBl[128 * 32];
    const int tid = threadIdx.x;
    const int w = tid >> 6, lane = tid & 63;
    const int bn0 = blockIdx.x * 128, bm0 = blockIdx.y * 128;
    const int wr = w >> 1, wc = w & 1;

    fx4 acc[4][4];
#pragma unroll
    for (int m = 0; m < 4; ++m)
#pragma unroll
        for (int n = 0; n < 4; ++n) acc[m][n] = {0.f, 0.f, 0.f, 0.f};

    for (int k0 = 0; k0 < K; k0 += 32) {
        __syncthreads();
#pragma unroll
        for (int i = 0; i < 2; ++i) {
            int c = i * 256 + tid;
            int r = c >> 2, kk = (c & 3) * 8;
            size_t ga = (size_t)(bm0 + r) * K + k0 + kk;
            size_t gb = (size_t)(bn0 + r) * K + k0 + kk;
            ASYNC_LDS16(sAh + c * 8, Ah + ga);
            ASYNC_LDS16(sAl + c * 8, Al + ga);
            ASYNC_LDS16(sBh + c * 8, Bth + gb);
            ASYNC_LDS16(sBl + c * 8, Btl + gb);
        }
        __syncthreads();
        bf16x8 ah[4], al[4], bh[4], bl[4];
#pragma unroll
        for (int m = 0; m < 4; ++m) {
            int off = (wr * 64 + m * 16 + (lane & 15)) * 32 + (lane >> 4) * 8;
            ah[m] = *(const bf16x8*)(sAh + off);
            al[m] = *(const bf16x8*)(sAl + off);
        }
#pragma unroll
        for (int n = 0; n < 4; ++n) {
            int off = (wc * 64 + n * 16 + (lane & 15)) * 32 + (lane >> 4) * 8;
            bh[n] = *(const bf16x8*)(sBh + off);
            bl[n] = *(const bf16x8*)(sBl + off);
        }
#pragma unroll
        for (int m = 0; m < 4; ++m)
#pragma unroll
            for (int n = 0; n < 4; ++n) {
                acc[m][n] = __builtin_amdgcn_mfma_f32_16x16x32_bf16(ah[m], bh[n], acc[m][n], 0, 0, 0);
                acc[m][n] = __builtin_amdgcn_mfma_f32_16x16x32_bf16(ah[m], bl[n], acc[m][n], 0, 0, 0);
                acc[m][n] = __builtin_amdgcn_mfma_f32_16x16x32_bf16(al[m], bh[n], acc[m][n], 0, 0, 0);
            }
    }
#pragma unroll
    for (int m = 0; m < 4; ++m) {
        int row = bm0 + wr * 64 + m * 16 + (lane >> 4) * 4;
#pragma unroll
        for (int n = 0; n < 4; ++n) {
            int col = bn0 + wc * 64 + n * 16 + (lane & 15);
#pragma unroll
            for (int j = 0; j < 4; ++j)
                Cout[(size_t)(row + j) * N + col] = acc[m][n][j];
        }
    }
}

// --------------------------------------------- RoPE + L2-normalize q,k in place
__global__ __launch_bounds__(256) void rope_kernel(float* __restrict__ X1,
                                                   const float2* __restrict__ cs) {
    int w = threadIdx.x >> 6, lane = threadIdx.x & 63;
    int p = blockIdx.x * 4 + w;            // (t,h) pair, 32768 total
    int t = p >> 4, h = p & 15;
    float2 c = cs[t * 32 + (lane & 31)];
#pragma unroll
    for (int which = 0; which < 2; ++which) {
        float* base = X1 + (size_t)t * NQKV + which * 1024 + h * 64;
        float x = base[lane];
        float xo = __shfl(x, lane ^ 32, 64);
        float r = (lane < 32) ? -xo : xo;
        float y = x * c.x + r * c.y;
        float ss = y * y;
#pragma unroll
        for (int m = 32; m; m >>= 1) ss += __shfl_xor(ss, m, 64);
        base[lane] = y * rsqrtf(ss + 1e-12f);
    }
}

// ===================== chunked delta-rule: shared helpers =====================
__device__ __forceinline__ void mm64_3p(const short* Ah, const short* Al,
                                        const short* Bh, const short* Bl,
                                        int w, int lane, fx4 acc[4]) {
#pragma unroll
    for (int k0 = 0; k0 < 64; k0 += 32) {
        int ao = (w * 16 + (lane & 15)) * LP + k0 + ((lane >> 4) * 8);
        bf16x8 ah = *(const bf16x8*)(Ah + ao);
        bf16x8 al = *(const bf16x8*)(Al + ao);
#pragma unroll
        for (int n = 0; n < 4; ++n) {
            int bo = (n * 16 + (lane & 15)) * LP + k0 + ((lane >> 4) * 8);
            bf16x8 bh = *(const bf16x8*)(Bh + bo);
            bf16x8 bl = *(const bf16x8*)(Bl + bo);
            acc[n] = __builtin_amdgcn_mfma_f32_16x16x32_bf16(ah, bh, acc[n], 0, 0, 0);
            acc[n] = __builtin_amdgcn_mfma_f32_16x16x32_bf16(ah, bl, acc[n], 0, 0, 0);
            acc[n] = __builtin_amdgcn_mfma_f32_16x16x32_bf16(al, bh, acc[n], 0, 0, 0);
        }
    }
}

__device__ __forceinline__ void split_write(short* h, short* l, int off, float x) {
    __hip_bfloat16 hb = __float2bfloat16(x);
    ((__hip_bfloat16*)h)[off] = hb;
    ((__hip_bfloat16*)l)[off] = __float2bfloat16(x - __bfloat162float(hb));
}

// ------------------------------------------------ phase A1 (blocked solve)
// Per (h,c): scalars + G=KK^T (MFMA) -> M. Blocked forward substitution,
// 16-wide panels: corr_I = sum_{J<I} M_IJ @ X_J via split-bf16 MFMA (4 waves,
// K=16 zero-padded); 16-step serial in-panel solve on 128 column-threads.
// X stored transposed in LDS XT[j][t] (= MFMA B-operand layout).
__global__ __launch_bounds__(256) void phaseA1_kernel(const float* __restrict__ X1,
                                                      __hip_bfloat16* __restrict__ UvWT_hi,
                                                      __hip_bfloat16* __restrict__ UvWT_lo) {
    const int h = blockIdx.x & 15, c = blockIdx.x >> 4;
    const int tid = threadIdx.x, w = tid >> 6, lane = tid & 63;
    const int t0 = c * 64;

    __shared__ short b1h[64 * LP], b1l[64 * LP];     // K hi/lo
    __shared__ float sMT[64 * MP];                   // [s*MP+t] (s<t) = M[t][s]
    __shared__ short xth[128 * LP], xtl[128 * LP];   // XT[j][t] hi/lo (corr -> X)
    __shared__ short mbh[3][512], mbl[3][512];       // M_IJ blocks [tl][k(32)], k>=16 zero
    __shared__ float sLa[64], sB[64], sL[65], sGp[64];

    const float* k_g = X1 + (size_t)t0 * NQKV + 1024 + h * 64;
    const float* v_g = X1 + (size_t)t0 * NQKV + 2048 + h * 64;

    if (tid < 64) {
        float ga = X1[(size_t)(t0 + tid) * NQKV + 4096 + h];
        float gb = X1[(size_t)(t0 + tid) * NQKV + 4112 + h];
        float z = -ga;
        sLa[tid] = -(fmaxf(z, 0.f) + log1pf(expf(-fabsf(z))));
        sB[tid] = 1.f / (1.f + expf(-gb));
    }
    __syncthreads();
    if (tid < 64) {
        float v = sLa[tid];
#pragma unroll
        for (int off = 1; off < 64; off <<= 1) {
            float u = __shfl_up(v, off, 64);
            if (tid >= off) v += u;
        }
        sL[tid + 1] = v;
        if (tid == 0) sL[0] = 0.f;
    }
    __syncthreads();
    if (tid < 64) sGp[tid] = expf(sL[tid]);
    // zero mb (k>=16 region must stay zero)
    for (int idx = tid; idx < 1536; idx += 256) {
        ((short*)mbh)[idx] = 0;
        ((short*)mbl)[idx] = 0;
    }
    // zero-init XT: the corr MFMA's B-read spans k in [J*16, J*16+32) which
    // touches the not-yet-written next panel. A-side is zero there, but LDS
    // garbage can be NaN-pattern bf16 and 0*NaN=NaN in the MFMA accumulator.
    for (int idx = tid; idx < 128 * LP; idx += 256) {
        xth[idx] = 0;
        xtl[idx] = 0;
    }
    // stage K (split)
    for (int idx = tid; idx < 4096; idx += 256) {
        int r = idx >> 6, cc = idx & 63;
        float kv = k_g[(size_t)r * NQKV + cc];
        __hip_bfloat16 hb = __float2bfloat16(kv);
        ((__hip_bfloat16*)b1h)[r * LP + cc] = hb;
        ((__hip_bfloat16*)b1l)[r * LP + cc] = __float2bfloat16(kv - __bfloat162float(hb));
    }
    __syncthreads();

    // G = K K^T, one 16-row strip per wave; scatter sMT[s][t] = M[t][s]
    {
        const int r0 = w * 16;
        fx4 acc[4];
#pragma unroll
        for (int n = 0; n < 4; ++n) acc[n] = {0.f, 0.f, 0.f, 0.f};
#pragma unroll
        for (int k0 = 0; k0 < 64; k0 += 32) {
            int ao = (r0 + (lane & 15)) * LP + k0 + ((lane >> 4) * 8);
            bf16x8 ah = *(const bf16x8*)(b1h + ao);
            bf16x8 al = *(const bf16x8*)(b1l + ao);
#pragma unroll
            for (int n = 0; n < 4; ++n) {
                int bo = (n * 16 + (lane & 15)) * LP + k0 + ((lane >> 4) * 8);
                bf16x8 bh = *(const bf16x8*)(b1h + bo);
                bf16x8 bl = *(const bf16x8*)(b1l + bo);
                acc[n] = __builtin_amdgcn_mfma_f32_16x16x32_bf16(ah, bh, acc[n], 0, 0, 0);
                acc[n] = __builtin_amdgcn_mfma_f32_16x16x32_bf16(ah, bl, acc[n], 0, 0, 0);
                acc[n] = __builtin_amdgcn_mfma_f32_16x16x32_bf16(al, bh, acc[n], 0, 0, 0);
            }
        }
#pragma unroll
        for (int n = 0; n < 4; ++n)
#pragma unroll
            for (int jj = 0; jj < 4; ++jj) {
                int t = r0 + (lane >> 4) * 4 + jj, s = n * 16 + (lane & 15);
                if (s < t) sMT[s * MP + t] = sB[t] * expf(sL[t] - sL[s + 1]) * acc[n][jj];
            }
    }
    __syncthreads();

    // blocked forward substitution over 4 panels of 16
#pragma unroll
    for (int I = 0; I < 4; ++I) {
        // build M_{I,J} (J<I) into mb[J] (k<16 half; k>=16 stays zero)
        for (int idx = tid; idx < I * 256; idx += 256) {
            int J = idx >> 8, e = idx & 255;
            int tl = e >> 4, sl = e & 15;
            float mv = sMT[(J * 16 + sl) * MP + (I * 16 + tl)];
            __hip_bfloat16 hb = __float2bfloat16(mv);
            ((__hip_bfloat16*)&mbh[J][0])[tl * 32 + sl] = hb;
            ((__hip_bfloat16*)&mbl[J][0])[tl * 32 + sl] = __float2bfloat16(mv - __bfloat162float(hb));
        }
        __syncthreads();    // mb ready; XT panels J<I ready (prev-iter barrier)
        if (I > 0) {
            // corr_I = sum_J M_IJ @ X_J; wave w covers col groups 2w, 2w+1
            fx4 acc2[2];
            acc2[0] = {0.f, 0.f, 0.f, 0.f};
            acc2[1] = {0.f, 0.f, 0.f, 0.f};
#pragma unroll
            for (int g = 0; g < 2; ++g) {
                const int jb = (w * 2 + g) * 16;
                for (int J = 0; J < I; ++J) {
                    bf16x8 ah = *(const bf16x8*)((const short*)&mbh[J][0] + (lane & 15) * 32 + (lane >> 4) * 8);
                    bf16x8 al = *(const bf16x8*)((const short*)&mbl[J][0] + (lane & 15) * 32 + (lane >> 4) * 8);
                    int bo = (jb + (lane & 15)) * LP + J * 16 + ((lane >> 4) * 8);
                    bf16x8 bh = *(const bf16x8*)(xth + bo);
                    bf16x8 bl = *(const bf16x8*)(xtl + bo);
                    acc2[g] = __builtin_amdgcn_mfma_f32_16x16x32_bf16(ah, bh, acc2[g], 0, 0, 0);
                    acc2[g] = __builtin_amdgcn_mfma_f32_16x16x32_bf16(ah, bl, acc2[g], 0, 0, 0);
                    acc2[g] = __builtin_amdgcn_mfma_f32_16x16x32_bf16(al, bh, acc2[g], 0, 0, 0);
                }
            }
            // write corr (split) into XT panel-I slots
#pragma unroll
            for (int g = 0; g < 2; ++g) {
                const int jb = (w * 2 + g) * 16;
#pragma unroll
                for (int jj = 0; jj < 4; ++jj) {
                    int j = jb + (lane & 15);
                    int t = I * 16 + (lane >> 4) * 4 + jj;
                    split_write(xth, xtl, j * LP + t, acc2[g][jj]);
                }
            }
        }
        __syncthreads();    // corr visible to solver threads
        // serial in-panel solve; thread j owns column j
        if (tid < 128) {
            const int j = tid;
            float xs[16];
#pragma unroll
            for (int tl = 0; tl < 16; ++tl) {
                const int t = I * 16 + tl;
                float base;
                if (j < 64) {
                    base = v_g[(size_t)t * NQKV + j];
                } else {
                    int i = j - 64;
                    base = (__bfloat162float(((__hip_bfloat16*)b1h)[t * LP + i]) +
                            __bfloat162float(((__hip_bfloat16*)b1l)[t * LP + i])) * sGp[t];
                }
                float r = sB[t] * base;
                if (I > 0) {
                    r -= __bfloat162float(((__hip_bfloat16*)xth)[j * LP + t]) +
                         __bfloat162float(((__hip_bfloat16*)xtl)[j * LP + t]);
                }
#pragma unroll
                for (int sl = 0; sl < tl; ++sl)
                    r = fmaf(-sMT[(I * 16 + sl) * MP + t], xs[sl], r);
                xs[tl] = r;
                __hip_bfloat16 hb = __float2bfloat16(r);
                ((__hip_bfloat16*)xth)[j * LP + t] = hb;
                ((__hip_bfloat16*)xtl)[j * LP + t] = __float2bfloat16(r - __bfloat162float(hb));
            }
        }
        __syncthreads();    // X_I published for next panel's MFMA
    }

    // write out t-major (coalesced): UvWT[hc][t][j] = XT[j][t]
    size_t obase = (size_t)(h * 32 + c) * 8192;
    for (int idx = tid; idx < 8192; idx += 256) {
        int t = idx >> 7, j = idx & 127;
        UvWT_hi[obase + idx] = ((__hip_bfloat16*)xth)[j * LP + t];
        UvWT_lo[obase + idx] = ((__hip_bfloat16*)xtl)[j * LP + t];
    }
}

// ------------------------------------------------ phase A2 (matmuls, parallel)
__global__ __launch_bounds__(256) void phaseA2_kernel(float* __restrict__ X1,
                                                      const __hip_bfloat16* __restrict__ UvWT_hi,
                                                      const __hip_bfloat16* __restrict__ UvWT_lo,
                                                      short* __restrict__ AcBuf,
                                                      float* __restrict__ BcBuf) {
    const int h = blockIdx.x & 15, c = blockIdx.x >> 4;
    const int tid = threadIdx.x, w = tid >> 6, lane = tid & 63;
    const int t0 = c * 64;

    __shared__ short b1h[64 * LP], b1l[64 * LP];   // K
    __shared__ short b2h[64 * LP], b2l[64 * LP];   // Q -> Ptilde -> KhatT
    __shared__ short b3h[64 * LP], b3l[64 * LP];   // UvT
    __shared__ short b4h[64 * LP], b4l[64 * LP];   // WT
    __shared__ float sLa[64], sL[65], sGp[64], sRc[64];

    const float* q_g = X1 + (size_t)t0 * NQKV + h * 64;
    const float* k_g = q_g + 1024;

    if (tid < 64) {
        float ga = X1[(size_t)(t0 + tid) * NQKV + 4096 + h];
        float z = -ga;
        sLa[tid] = -(fmaxf(z, 0.f) + log1pf(expf(-fabsf(z))));
    }
    __syncthreads();
    if (tid < 64) {
        float v = sLa[tid];
#pragma unroll
        for (int off = 1; off < 64; off <<= 1) {
            float u = __shfl_up(v, off, 64);
            if (tid >= off) v += u;
        }
        sL[tid + 1] = v;
        if (tid == 0) sL[0] = 0.f;
    }
    __syncthreads();
    if (tid < 64) {
        sGp[tid] = expf(sL[tid]);
        sRc[tid] = expf(sL[64] - sL[tid + 1]);
    }
    // stage Q, K (split) and UvT/WT
    for (int idx = tid; idx < 4096; idx += 256) {
        int r = idx >> 6, cc = idx & 63;
        split_write(b2h, b2l, r * LP + cc, q_g[(size_t)r * NQKV + cc]);
        split_write(b1h, b1l, r * LP + cc, k_g[(size_t)r * NQKV + cc]);
    }
    const __hip_bfloat16* uh = UvWT_hi + (size_t)(h * 32 + c) * 8192;
    const __hip_bfloat16* ul = UvWT_lo + (size_t)(h * 32 + c) * 8192;
    for (int idx = tid; idx < 8192; idx += 256) {
        int t = idx >> 7, row = idx & 127;
        short* dh = (row < 64) ? b3h : b4h;
        short* dl = (row < 64) ? b3l : b4l;
        ((__hip_bfloat16*)dh)[(row & 63) * LP + t] = uh[idx];
        ((__hip_bfloat16*)dl)[(row & 63) * LP + t] = ul[idx];
    }
    __syncthreads();

    // P = Q K^T
    fx4 pacc[4];
#pragma unroll
    for (int n = 0; n < 4; ++n) pacc[n] = {0.f, 0.f, 0.f, 0.f};
    mm64_3p(b2h, b2l, b1h, b1l, w, lane, pacc);
    __syncthreads();
    // Ptilde -> b2 (masked, scaled)
#pragma unroll
    for (int n = 0; n < 4; ++n)
#pragma unroll
        for (int jj = 0; jj < 4; ++jj) {
            int t = w * 16 + (lane >> 4) * 4 + jj, s = n * 16 + (lane & 15);
            float pv = (s < t) ? expf(sL[t] - sL[s + 1]) * pacc[n][jj] : 0.f;
            split_write(b2h, b2l, t * LP + s, pv);
        }
    __syncthreads();

    // Olocal = Ptilde @ Uv -> overwrite k-region (f32)
    {
        fx4 acc[4];
#pragma unroll
        for (int n = 0; n < 4; ++n) acc[n] = {0.f, 0.f, 0.f, 0.f};
        mm64_3p(b2h, b2l, b3h, b3l, w, lane, acc);
        float* og = X1 + (size_t)t0 * NQKV + 1024 + h * 64;
#pragma unroll
        for (int n = 0; n < 4; ++n)
#pragma unroll
            for (int jj = 0; jj < 4; ++jj) {
                int t = w * 16 + (lane >> 4) * 4 + jj, s = n * 16 + (lane & 15);
                og[(size_t)t * NQKV + s] = acc[n][jj];
            }
    }
    // PW = Ptilde @ W ; Qeff = diag(gprev)Q - PW -> overwrite q-region (f32)
    {
        fx4 acc[4];
#pragma unroll
        for (int n = 0; n < 4; ++n) acc[n] = {0.f, 0.f, 0.f, 0.f};
        mm64_3p(b2h, b2l, b4h, b4l, w, lane, acc);
        float* qg = X1 + (size_t)t0 * NQKV + h * 64;
#pragma unroll
        for (int n = 0; n < 4; ++n)
#pragma unroll
            for (int jj = 0; jj < 4; ++jj) {
                int t = w * 16 + (lane >> 4) * 4 + jj, s = n * 16 + (lane & 15);
                float qv = qg[(size_t)t * NQKV + s];
                qg[(size_t)t * NQKV + s] = sGp[t] * qv - acc[n][jj];
            }
    }
    __syncthreads();   // all reads of b2 (Ptilde) complete
    // KhatT -> b2: [i][s] = rC[s] * K[s][i]
    for (int idx = tid; idx < 4096; idx += 256) {
        int s = idx >> 6, i = idx & 63;
        float kv = __bfloat162float(((__hip_bfloat16*)b1h)[s * LP + i]) +
                   __bfloat162float(((__hip_bfloat16*)b1l)[s * LP + i]);
        split_write(b2h, b2l, i * LP + s, sRc[s] * kv);
    }
    __syncthreads();

    // Ac = gammaEnd*I - KhatT @ W -> AcBuf (bf16 hi/lo, row-major [i][j])
    {
        fx4 acc[4];
#pragma unroll
        for (int n = 0; n < 4; ++n) acc[n] = {0.f, 0.f, 0.f, 0.f};
        mm64_3p(b2h, b2l, b4h, b4l, w, lane, acc);
        float gend = expf(sL[64]);
        size_t abase = (size_t)(h * 32 + c) * 8192;
#pragma unroll
        for (int n = 0; n < 4; ++n)
#pragma unroll
            for (int jj = 0; jj < 4; ++jj) {
                int i = w * 16 + (lane >> 4) * 4 + jj, jd = n * 16 + (lane & 15);
                float av = ((i == jd) ? gend : 0.f) - acc[n][jj];
                __hip_bfloat16 hb = __float2bfloat16(av);
                ((__hip_bfloat16*)AcBuf)[abase + i * 64 + jd] = hb;
                ((__hip_bfloat16*)AcBuf)[abase + 4096 + i * 64 + jd] =
                    __float2bfloat16(av - __bfloat162float(hb));
            }
    }
    // BcT = UvT @ KhatT' -> BcBuf (f32, [v][i])
    {
        fx4 acc[4];
#pragma unroll
        for (int n = 0; n < 4; ++n) acc[n] = {0.f, 0.f, 0.f, 0.f};
        mm64_3p(b3h, b3l, b2h, b2l, w, lane, acc);
        size_t bbase = (size_t)(h * 32 + c) * 4096;
#pragma unroll
        for (int n = 0; n < 4; ++n)
#pragma unroll
            for (int jj = 0; jj < 4; ++jj) {
                int jv = w * 16 + (lane >> 4) * 4 + jj, i = n * 16 + (lane & 15);
                BcBuf[bbase + jv * 64 + i] = acc[n][jj];
            }
    }
}

// --------------------------------------------------- phase B (state recurrence)
// 16 blocks (1/head) x 4 waves. Wave w owns v-rows [w*16, w*16+16) of S^T.
// Ac double-buffered in LDS via global_load_lds; ONE barrier per iteration.
__global__ __launch_bounds__(256) void phaseB_kernel(const short* __restrict__ AcBuf,
                                                     const float* __restrict__ BcBuf,
                                                     float* __restrict__ X1) {
    const int h = blockIdx.x;
    const int tid = threadIdx.x, w = tid >> 6, lane = tid & 63;
    const int lr = (lane >> 4) * 4;                // C-layout row offset
    const int lc = lane & 15;                      // C-layout col offset
    __shared__ short sAc[2][8192];                 // [hi 4096 | lo 4096] shorts, row stride 64
    __shared__ float sST[64 * 68];                 // S^T staging (intra-wave)

    const size_t hc0 = (size_t)h * 32;
    // prologue: async-stage Ac[0] into buf 0 (lane-linear copy, 16KB)
    {
        const char* src = (const char*)AcBuf + hc0 * 16384;
        char* dst = (char*)&sAc[0][0];
        int off = w * 4096 + lane * 16;
#pragma unroll
        for (int q = 0; q < 4; ++q) { ASYNC_LDS16(dst + off, src + off); off += 1024; }
    }
    fx4 acc[4];
#pragma unroll
    for (int n = 0; n < 4; ++n) acc[n] = {0.f, 0.f, 0.f, 0.f};
    float bcur[16];
    {
        const float* bg = BcBuf + hc0 * 4096;
#pragma unroll
        for (int n = 0; n < 4; ++n)
#pragma unroll
            for (int jj = 0; jj < 4; ++jj)
                bcur[n * 4 + jj] = bg[(w * 16 + lr + jj) * 64 + n * 16 + lc];
    }

#pragma unroll 1
    for (int c = 0; c < 32; ++c) {
        __syncthreads();
        {
            int cn = (c < 31) ? c + 1 : 31;
            const char* src = (const char*)AcBuf + (hc0 + cn) * 16384;
            char* dst = (char*)&sAc[(c + 1) & 1][0];
            int off = w * 4096 + lane * 16;
#pragma unroll
            for (int q = 0; q < 4; ++q) { ASYNC_LDS16(dst + off, src + off); off += 1024; }
        }
        float bnext[16];
        {
            int cn = (c < 31) ? c + 1 : 31;
            const float* bg = BcBuf + (hc0 + cn) * 4096;
#pragma unroll
            for (int n = 0; n < 4; ++n)
#pragma unroll
                for (int jj = 0; jj < 4; ++jj)
                    bnext[n * 4 + jj] = bg[(w * 16 + lr + jj) * 64 + n * 16 + lc];
        }
        float* stg = X1 + (size_t)(c * 64) * NQKV + 2048 + h * 64;
#pragma unroll
        for (int n = 0; n < 4; ++n)
#pragma unroll
            for (int jj = 0; jj < 4; ++jj) {
                int r = w * 16 + lr + jj, i = n * 16 + lc;
                stg[(size_t)r * NQKV + i] = acc[n][jj];
                sST[r * 68 + i] = acc[n][jj];
            }
        const short* bufc = &sAc[c & 1][0];
        fx4 nacc[4];
#pragma unroll
        for (int n = 0; n < 4; ++n)
            nacc[n] = {bcur[n * 4 + 0], bcur[n * 4 + 1], bcur[n * 4 + 2], bcur[n * 4 + 3]};
#pragma unroll
        for (int k0 = 0; k0 < 2; ++k0) {
            const float* ap = sST + (w * 16 + lc) * 68 + k0 * 32 + (lane >> 4) * 8;
            float4 f0 = *(const float4*)ap;
            float4 f1 = *(const float4*)(ap + 4);
            float fv[8] = {f0.x, f0.y, f0.z, f0.w, f1.x, f1.y, f1.z, f1.w};
            bf16x8 afh, afl;
#pragma unroll
            for (int e = 0; e < 8; ++e) {
                __hip_bfloat16 hb = __float2bfloat16(fv[e]);
                __hip_bfloat16 lb = __float2bfloat16(fv[e] - __bfloat162float(hb));
                afh[e] = *(__bf16*)&hb;
                afl[e] = *(__bf16*)&lb;
            }
#pragma unroll
            for (int n = 0; n < 4; ++n) {
                int ro = (n * 16 + lc) * 64 + k0 * 32 + (lane >> 4) * 8;   // shorts
                bf16x8 bh = *(const bf16x8*)(bufc + ro);
                bf16x8 bl = *(const bf16x8*)(bufc + 4096 + ro);
                nacc[n] = __builtin_amdgcn_mfma_f32_16x16x32_bf16(afh, bh, nacc[n], 0, 0, 0);
                nacc[n] = __builtin_amdgcn_mfma_f32_16x16x32_bf16(afh, bl, nacc[n], 0, 0, 0);
                nacc[n] = __builtin_amdgcn_mfma_f32_16x16x32_bf16(afl, bh, nacc[n], 0, 0, 0);
            }
        }
#pragma unroll
        for (int n = 0; n < 4; ++n) acc[n] = nacc[n];
#pragma unroll
        for (int e = 0; e < 16; ++e) bcur[e] = bnext[e];
    }
}

// --------------------------------------------- phase C (outputs + epilogue)
__global__ __launch_bounds__(256) void phaseC_kernel(const float* __restrict__ X1,
                                                     const float* __restrict__ onw,
                                                     __hip_bfloat16* __restrict__ attn_bf) {
    const int h = blockIdx.x & 15, c = blockIdx.x >> 4;
    const int tid = threadIdx.x, w = tid >> 6, lane = tid & 63;
    const int t0 = c * 64;
    __shared__ short qh[64 * LP], ql[64 * LP];
    __shared__ short sh_[64 * LP], sl_[64 * LP];
    __shared__ float sO[4096];
    __shared__ float part[64][4];
    const float* qe = X1 + (size_t)t0 * NQKV + h * 64;          // Qeff
    const float* stg = X1 + (size_t)t0 * NQKV + 2048 + h * 64;  // S^T (entering c)
    const float* ol = X1 + (size_t)t0 * NQKV + 1024 + h * 64;   // Olocal
    for (int idx = tid; idx < 4096; idx += 256) {
        int r = idx >> 6, i = idx & 63;
        split_write(qh, ql, r * LP + i, qe[(size_t)r * NQKV + i]);
        split_write(sh_, sl_, r * LP + i, stg[(size_t)r * NQKV + i]);
    }
    __syncthreads();
    fx4 acc[4];
#pragma unroll
    for (int n = 0; n < 4; ++n)
#pragma unroll
        for (int jj = 0; jj < 4; ++jj)
            acc[n][jj] = ol[(size_t)(w * 16 + (lane >> 4) * 4 + jj) * NQKV + n * 16 + (lane & 15)];
    mm64_3p(qh, ql, sh_, sl_, w, lane, acc);
#pragma unroll
    for (int n = 0; n < 4; ++n)
#pragma unroll
        for (int jj = 0; jj < 4; ++jj)
            sO[(w * 16 + (lane >> 4) * 4 + jj) * 64 + n * 16 + (lane & 15)] = acc[n][jj];
    __syncthreads();
    int r = tid >> 2, qq = tid & 3;
    float ss = 0.f;
#pragma unroll
    for (int i2 = 0; i2 < 16; ++i2) { float v = sO[r * 64 + qq * 16 + i2]; ss += v * v; }
    part[r][qq] = ss;
    __syncthreads();
    float tot = part[r][0] + part[r][1] + part[r][2] + part[r][3];
    float sc = rsqrtf(tot * (1.f / 64.f) + 1e-6f);
    const float* gg = X1 + (size_t)(t0 + r) * NQKV + 3072 + h * 64;
#pragma unroll
    for (int i2 = 0; i2 < 16; ++i2) {
        int j = qq * 16 + i2;
        float on = sO[r * 64 + j] * sc * onw[j];
        float g = gg[j];
        float sg = g / (1.f + expf(-g));
        attn_bf[(size_t)(t0 + r) * 1024 + h * 64 + j] = __float2bfloat16(on * sg);
    }
}

// ---------------------------- h = hidden + attn (in place); ybf = rmsnorm(h)
__global__ __launch_bounds__(256) void add_rmsnorm_kernel(
    const float* __restrict__ hidden, float* __restrict__ acc,
    const float* __restrict__ w, __hip_bfloat16* __restrict__ out) {
    int t = blockIdx.x;
    int d = threadIdx.x * 4;
    float4 a = *(const float4*)(acc + (size_t)t * D_MODEL + d);
    float4 hd = *(const float4*)(hidden + (size_t)t * D_MODEL + d);
    float4 h4 = make_float4(a.x + hd.x, a.y + hd.y, a.z + hd.z, a.w + hd.w);
    *(float4*)(acc + (size_t)t * D_MODEL + d) = h4;
    float ss = h4.x * h4.x + h4.y * h4.y + h4.z * h4.z + h4.w * h4.w;
#pragma unroll
    for (int m = 32; m; m >>= 1) ss += __shfl_xor(ss, m, 64);
    __shared__ float wsum[4];
    if ((threadIdx.x & 63) == 0) wsum[threadIdx.x >> 6] = ss;
    __syncthreads();
    float tot = wsum[0] + wsum[1] + wsum[2] + wsum[3];
    float sc = rsqrtf(tot * (1.f / 1024.f) + 1e-6f);
    const float4 wv = *(const float4*)(w + d);
    __hip_bfloat16* op = out + (size_t)t * D_MODEL + d;
    op[0] = __float2bfloat16(h4.x * sc * wv.x);
    op[1] = __float2bfloat16(h4.y * sc * wv.y);
    op[2] = __float2bfloat16(h4.z * sc * wv.z);
    op[3] = __float2bfloat16(h4.w * sc * wv.w);
}

// ---------------------------------------------- m = silu(G) * U (bf16 in/out)
__global__ __launch_bounds__(256) void silu_mul_kernel(const __hip_bfloat16* __restrict__ GU,
                                                       __hip_bfloat16* __restrict__ m) {
    size_t i = (size_t)blockIdx.x * 256 + threadIdx.x;   // 2048*4096
    size_t t = i >> 12, j = i & 4095;
    float g = __bfloat162float(GU[t * 8192 + j]);
    float u = __bfloat162float(GU[t * 8192 + 4096 + j]);
    m[i] = __float2bfloat16(u * g / (1.f + expf(-g)));
}

// ----------------------------------------------------------- out += h
__global__ __launch_bounds__(256) void final_add_kernel(float* __restrict__ out,
                                                        const float* __restrict__ h) {
    size_t i = (size_t)blockIdx.x * 256 + threadIdx.x;
    out[i] += h[i];
}

// ---------------------------------------------------------------------------
extern "C" void kernel_launch(void* const* d_in, const int* in_sizes, int n_in,
                              void* d_out, int out_size, void* d_ws, size_t ws_size,
                              hipStream_t stream) {
    (void)in_sizes; (void)n_in; (void)out_size; (void)ws_size;
    const float* hidden     = (const float*)d_in[0];
    const float* norm1_w    = (const float*)d_in[1];
    const float* q_w        = (const float*)d_in[2];
    const float* k_w        = (const float*)d_in[3];
    const float* v_w        = (const float*)d_in[4];
    const float* g_w        = (const float*)d_in[5];
    const float* b_w        = (const float*)d_in[6];
    const float* gate_w     = (const float*)d_in[7];
    const float* o_norm_w   = (const float*)d_in[8];
    const float* o_w        = (const float*)d_in[9];
    const float* norm2_w    = (const float*)d_in[10];
    const float* mlp_gate_w = (const float*)d_in[11];
    const float* mlp_up_w   = (const float*)d_in[12];
    const float* mlp_down_w = (const float*)d_in[13];

    char* ws = (char*)d_ws;
    // workspace (~92 MiB), timeline-reused:
    const size_t OFF_WT_QKVG = 0;          // wt_qkvg_hi -> AcBuf
    const size_t OFF_WT_O    = 8650752;
    const size_t OFF_WT_GU   = 10747904;
    const size_t OFF_WT_DOWN = 27525120;
    const size_t OFF_X1      = 35913728;   // X1 f32 -> GU bf16
    const size_t OFF_R1      = 70516736;   // wt_qkvg_lo -> BcBuf -> mbf
    const size_t OFF_ATTN    = 79167488;   // UvWT_lo (A1/A2) -> attn_bf+ybf
    const size_t OFF_YBF     = 83361792;
    const size_t OFF_XHI     = 87556096;   // xhi/xlo -> UvWT_hi -> h_buf
    const size_t OFF_XLO     = 91750400;
    const size_t OFF_ROPE    = 95944704;

    __hip_bfloat16* wt_qkvg_hi = (__hip_bfloat16*)(ws + OFF_WT_QKVG);
    __hip_bfloat16* wt_qkvg_lo = (__hip_bfloat16*)(ws + OFF_R1);
    __hip_bfloat16* wt_o    = (__hip_bfloat16*)(ws + OFF_WT_O);
    __hip_bfloat16* wt_gu   = (__hip_bfloat16*)(ws + OFF_WT_GU);
    __hip_bfloat16* wt_down = (__hip_bfloat16*)(ws + OFF_WT_DOWN);
    float*          X1      = (float*)(ws + OFF_X1);
    __hip_bfloat16* GU      = (__hip_bfloat16*)(ws + OFF_X1);
    short*          AcBuf   = (short*)(ws + OFF_WT_QKVG);       // after qkv gemm
    float*          BcBuf   = (float*)(ws + OFF_R1);            // after qkv gemm
    __hip_bfloat16* mbf     = (__hip_bfloat16*)(ws + OFF_R1);   // after phase B/C
    __hip_bfloat16* attn_bf = (__hip_bfloat16*)(ws + OFF_ATTN);
    __hip_bfloat16* xhi     = (__hip_bfloat16*)(ws + OFF_XHI);
    __hip_bfloat16* xlo     = (__hip_bfloat16*)(ws + OFF_XLO);
    __hip_bfloat16* UvWT_hi = (__hip_bfloat16*)(ws + OFF_XHI);  // 8.39MB, after qkv gemm
    __hip_bfloat16* UvWT_lo = (__hip_bfloat16*)(ws + OFF_ATTN); // 8.39MB, until phaseC
    float*          h_buf   = (float*)(ws + OFF_XHI);           // after phaseA2
    __hip_bfloat16* ybf     = (__hip_bfloat16*)(ws + OFF_YBF);
    float2*         rope_cs = (float2*)(ws + OFF_ROPE);

    dim3 tb(32, 8);
    rope_table_kernel<<<256, 256, 0, stream>>>(rope_cs);
    rmsnorm_split_kernel<<<2048, 256, 0, stream>>>(hidden, norm1_w, xhi, xlo);
    transpose_split_kernel<<<dim3(32, 32), tb, 0, stream>>>(q_w,    wt_qkvg_hi,               wt_qkvg_lo,               1024, 1024, 1024);
    transpose_split_kernel<<<dim3(32, 32), tb, 0, stream>>>(k_w,    wt_qkvg_hi + 1024 * 1024, wt_qkvg_lo + 1024 * 1024, 1024, 1024, 1024);
    transpose_split_kernel<<<dim3(32, 32), tb, 0, stream>>>(v_w,    wt_qkvg_hi + 2048 * 1024, wt_qkvg_lo + 2048 * 1024, 1024, 1024, 1024);
    transpose_split_kernel<<<dim3(32, 32), tb, 0, stream>>>(gate_w, wt_qkvg_hi + 3072 * 1024, wt_qkvg_lo + 3072 * 1024, 1024, 1024, 1024);
    transpose_split_kernel<<<dim3(32, 1),  tb, 0, stream>>>(g_w,    wt_qkvg_hi + 4096 * 1024, wt_qkvg_lo + 4096 * 1024, 1024, 16,   16);
    transpose_split_kernel<<<dim3(32, 4),  tb, 0, stream>>>(b_w,    wt_qkvg_hi + 4112 * 1024, wt_qkvg_lo + 4112 * 1024, 1024, 16,   112);
    transpose_bf16_kernel<<<dim3(32, 32),  tb, 0, stream>>>(o_w,        wt_o,                1024, 1024, 1024);
    transpose_bf16_kernel<<<dim3(32, 128), tb, 0, stream>>>(mlp_gate_w, wt_gu,               1024, 4096, 4096);
    transpose_bf16_kernel<<<dim3(32, 128), tb, 0, stream>>>(mlp_up_w,   wt_gu + 4096 * 1024, 1024, 4096, 4096);
    transpose_bf16_kernel<<<dim3(128, 32), tb, 0, stream>>>(mlp_down_w, wt_down,             4096, 1024, 1024);
    // fused q|k|v|gate|g|b projection (split precision)
    gemm_bt_split<<<dim3(33, 16), 256, 0, stream>>>(xhi, xlo, wt_qkvg_hi, wt_qkvg_lo, X1, 2048, NQKV, 1024);
    rope_kernel<<<8192, 256, 0, stream>>>(X1, rope_cs);
    // chunked delta-rule scan
    phaseA1_kernel<<<512, 256, 0, stream>>>(X1, UvWT_hi, UvWT_lo);
    phaseA2_kernel<<<512, 256, 0, stream>>>(X1, UvWT_hi, UvWT_lo, AcBuf, BcBuf);
    phaseB_kernel<<<16, 256, 0, stream>>>(AcBuf, BcBuf, X1);
    phaseC_kernel<<<512, 256, 0, stream>>>(X1, o_norm_w, attn_bf);
    // attn out projection -> h
    gemm_bt<false><<<dim3(8, 16), 256, 0, stream>>>(attn_bf, wt_o, h_buf, 2048, 1024, 1024);
    add_rmsnorm_kernel<<<2048, 256, 0, stream>>>(hidden, h_buf, norm2_w, ybf);
    gemm_bt<true><<<dim3(64, 16), 256, 0, stream>>>(ybf, wt_gu, GU, 2048, 8192, 1024);
    silu_mul_kernel<<<32768, 256, 0, stream>>>(GU, mbf);
    gemm_bt<false><<<dim3(8, 16), 256, 0, stream>>>(mbf, wt_down, (float*)d_out, 2048, 1024, 4096);
    final_add_kernel<<<8192, 256, 0, stream>>>((float*)d_out, h_buf);
}

// Round 11
// 454.443 us; speedup vs baseline: 1.4282x; 1.0064x over previous
//
#include <hip/hip_runtime.h>
#include <hip/hip_bf16.h>

// ---------------------------------------------------------------------------
// DepthDeltaNetDecoderLayer: B=1, T=2048, D=1024, H=16, DK=DV=64, FF=4096
// Round 11: GEMM 2-phase prefetch (T3-minimum). The 0-phase m97-style loop
// exposed full global_load_lds latency at every K-step (MfmaUtil 6.6%).
// Now: double-buffered LDS, issue tile t+1 BEFORE computing tile t; the one
// vmcnt(0)+barrier per K-step drains loads that overlapped a full compute
// phase. Numerically identical. gemm_bt: 32KB LDS; gemm_bt_split: 64KB.
// ---------------------------------------------------------------------------

#define T_SEQ 2048
#define D_MODEL 1024
#define NH 16
#define DK 64
#define DV 64
#define FF 4096
#define NQKV 4224   // q(1024) k(1024) v(1024) gate(1024) g(16@4096) b(16@4112) pad->4224
#define LP 72       // padded LDS stride (shorts), 144B rows (16B-aligned)
#define MP 68       // padded stride (floats) for M^T

typedef __bf16 bf16x8 __attribute__((ext_vector_type(8)));
typedef float  fx4    __attribute__((ext_vector_type(4)));

#if defined(__has_builtin)
#if __has_builtin(__builtin_amdgcn_global_load_lds)
#define HAVE_GLOAD_LDS 1
#endif
#endif

#ifdef HAVE_GLOAD_LDS
#define ASYNC_LDS16(dst, src)                                                   \
    __builtin_amdgcn_global_load_lds(                                           \
        (__attribute__((address_space(1))) void*)(src),                         \
        (__attribute__((address_space(3))) void*)(dst), 16, 0, 0)
#else
#define ASYNC_LDS16(dst, src) (*(int4*)(dst) = *(const int4*)(src))
#endif

// ---------------------------------------------------------------- rope table
__global__ void rope_table_kernel(float2* __restrict__ cs) {
    int idx = blockIdx.x * 256 + threadIdx.x;      // t*32 + i, 65536 total
    int t = idx >> 5, i = idx & 31;
    float freq = (float)t * powf(10000.f, -(float)i / 32.f);
    cs[idx] = make_float2(cosf(freq), sinf(freq));
}

// --------------------------------------- row rmsnorm -> bf16 hi + bf16 lo
__global__ __launch_bounds__(256) void rmsnorm_split_kernel(
    const float* __restrict__ in, const float* __restrict__ w,
    __hip_bfloat16* __restrict__ hi, __hip_bfloat16* __restrict__ lo) {
    int t = blockIdx.x;
    int d = threadIdx.x * 4;
    const float4 v = *(const float4*)(in + (size_t)t * D_MODEL + d);
    float ss = v.x * v.x + v.y * v.y + v.z * v.z + v.w * v.w;
#pragma unroll
    for (int m = 32; m; m >>= 1) ss += __shfl_xor(ss, m, 64);
    __shared__ float wsum[4];
    if ((threadIdx.x & 63) == 0) wsum[threadIdx.x >> 6] = ss;
    __syncthreads();
    float tot = wsum[0] + wsum[1] + wsum[2] + wsum[3];
    float sc = rsqrtf(tot * (1.f / 1024.f) + 1e-6f);
    const float4 wv = *(const float4*)(w + d);
    float xs[4] = {v.x * sc * wv.x, v.y * sc * wv.y, v.z * sc * wv.z, v.w * sc * wv.w};
    __hip_bfloat16* hp = hi + (size_t)t * D_MODEL + d;
    __hip_bfloat16* lp = lo + (size_t)t * D_MODEL + d;
#pragma unroll
    for (int j = 0; j < 4; ++j) {
        __hip_bfloat16 h = __float2bfloat16(xs[j]);
        hp[j] = h;
        lp[j] = __float2bfloat16(xs[j] - __bfloat162float(h));
    }
}

// ------------------------------------------- W (KxN f32) -> Wt (Npad x K bf16)
__global__ void transpose_bf16_kernel(const float* __restrict__ W,
                                      __hip_bfloat16* __restrict__ Wt,
                                      int K, int N, int Npad) {
    __shared__ float tile[32][33];
    int k0 = blockIdx.x * 32, n0 = blockIdx.y * 32;
    int tx = threadIdx.x, ty = threadIdx.y;   // (32,8)
#pragma unroll
    for (int i = 0; i < 32; i += 8) {
        int n = n0 + tx;
        tile[ty + i][tx] = (n < N) ? W[(size_t)(k0 + ty + i) * N + n] : 0.f;
    }
    __syncthreads();
#pragma unroll
    for (int i = 0; i < 32; i += 8) {
        int n = n0 + ty + i;
        if (n < Npad) Wt[(size_t)n * K + k0 + tx] = __float2bfloat16(tile[tx][ty + i]);
    }
}

// ---------------------- W (KxN f32) -> Wt_hi, Wt_lo (Npad x K bf16 each)
__global__ void transpose_split_kernel(const float* __restrict__ W,
                                       __hip_bfloat16* __restrict__ Wt_hi,
                                       __hip_bfloat16* __restrict__ Wt_lo,
                                       int K, int N, int Npad) {
    __shared__ float tile[32][33];
    int k0 = blockIdx.x * 32, n0 = blockIdx.y * 32;
    int tx = threadIdx.x, ty = threadIdx.y;   // (32,8)
#pragma unroll
    for (int i = 0; i < 32; i += 8) {
        int n = n0 + tx;
        tile[ty + i][tx] = (n < N) ? W[(size_t)(k0 + ty + i) * N + n] : 0.f;
    }
    __syncthreads();
#pragma unroll
    for (int i = 0; i < 32; i += 8) {
        int n = n0 + ty + i;
        if (n < Npad) {
            float x = tile[tx][ty + i];
            __hip_bfloat16 h = __float2bfloat16(x);
            Wt_hi[(size_t)n * K + k0 + tx] = h;
            Wt_lo[(size_t)n * K + k0 + tx] = __float2bfloat16(x - __bfloat162float(h));
        }
    }
}

// ------------------------------------------------------------------- GEMM
// A: MxK bf16 row-major; Bt: NxK bf16 row-major (B transposed); C: MxN.
// 2-phase: double-buffered LDS, prefetch tile t+1 before computing tile t.
template <bool OUT_BF16>
__global__ __launch_bounds__(256) void gemm_bt(
    const __hip_bfloat16* __restrict__ A, const __hip_bfloat16* __restrict__ Bt,
    void* __restrict__ Cout, int M, int N, int K) {
    __shared__ short sA[2][128 * 32];
    __shared__ short sB[2][128 * 32];
    const int tid = threadIdx.x;
    const int w = tid >> 6, lane = tid & 63;
    const int bn0 = blockIdx.x * 128, bm0 = blockIdx.y * 128;
    const int wr = w >> 1, wc = w & 1;

    fx4 acc[4][4];
#pragma unroll
    for (int m = 0; m < 4; ++m)
#pragma unroll
        for (int n = 0; n < 4; ++n) acc[m][n] = {0.f, 0.f, 0.f, 0.f};

    // prologue: stage tile 0 into buf 0
#pragma unroll
    for (int i = 0; i < 2; ++i) {
        int c = i * 256 + tid;
        int r = c >> 2, kk = (c & 3) * 8;
        ASYNC_LDS16(&sA[0][c * 8], A + (size_t)(bm0 + r) * K + kk);
        ASYNC_LDS16(&sB[0][c * 8], Bt + (size_t)(bn0 + r) * K + kk);
    }
    __syncthreads();   // vmcnt(0) drain + publish buf0

    const int NT = K >> 5;
    int cur = 0;
    for (int t = 0; t < NT; ++t) {
        if (t + 1 < NT) {
            int k0 = (t + 1) << 5;
#pragma unroll
            for (int i = 0; i < 2; ++i) {
                int c = i * 256 + tid;
                int r = c >> 2, kk = (c & 3) * 8;
                ASYNC_LDS16(&sA[cur ^ 1][c * 8], A + (size_t)(bm0 + r) * K + k0 + kk);
                ASYNC_LDS16(&sB[cur ^ 1][c * 8], Bt + (size_t)(bn0 + r) * K + k0 + kk);
            }
        }
        bf16x8 af[4], bfv[4];
#pragma unroll
        for (int m = 0; m < 4; ++m)
            af[m] = *(const bf16x8*)(&sA[cur][(wr * 64 + m * 16 + (lane & 15)) * 32 + (lane >> 4) * 8]);
#pragma unroll
        for (int n = 0; n < 4; ++n)
            bfv[n] = *(const bf16x8*)(&sB[cur][(wc * 64 + n * 16 + (lane & 15)) * 32 + (lane >> 4) * 8]);
#pragma unroll
        for (int m = 0; m < 4; ++m)
#pragma unroll
            for (int n = 0; n < 4; ++n)
                acc[m][n] = __builtin_amdgcn_mfma_f32_16x16x32_bf16(af[m], bfv[n], acc[m][n], 0, 0, 0);
        __syncthreads();   // drain prefetch (overlapped with the MFMAs above)
        cur ^= 1;
    }
#pragma unroll
    for (int m = 0; m < 4; ++m) {
        int row = bm0 + wr * 64 + m * 16 + (lane >> 4) * 4;
#pragma unroll
        for (int n = 0; n < 4; ++n) {
            int col = bn0 + wc * 64 + n * 16 + (lane & 15);
#pragma unroll
            for (int j = 0; j < 4; ++j) {
                float val = acc[m][n][j];
                if (OUT_BF16)
                    ((__hip_bfloat16*)Cout)[(size_t)(row + j) * N + col] = __float2bfloat16(val);
                else
                    ((float*)Cout)[(size_t)(row + j) * N + col] = val;
            }
        }
    }
}

// ------------------------------------- split-precision GEMM (3 bf16 products)
// 2-phase prefetch; 4 operand streams double-buffered (64KB LDS, 2 blk/CU).
__global__ __launch_bounds__(256) void gemm_bt_split(
    const __hip_bfloat16* __restrict__ Ah, const __hip_bfloat16* __restrict__ Al,
    const __hip_bfloat16* __restrict__ Bth, const __hip_bfloat16* __restrict__ Btl,
    float* __restrict__ Cout, int M, int N, int K) {
    __shared__ short sAh[2][128 * 32];
    __shared__ short sAl[2][128 * 32];
    __shared__ short sBh[2][128 * 32];
    __shared__ short sBl[2][128 * 32];
    const int tid = threadIdx.x;
    const int w = tid >> 6, lane = tid & 63;
    const int bn0 = blockIdx.x * 128, bm0 = blockIdx.y * 128;
    const int wr = w >> 1, wc = w & 1;

    fx4 acc[4][4];
#pragma unroll
    for (int m = 0; m < 4; ++m)
#pragma unroll
        for (int n = 0; n < 4; ++n) acc[m][n] = {0.f, 0.f, 0.f, 0.f};

#pragma unroll
    for (int i = 0; i < 2; ++i) {
        int c = i * 256 + tid;
        int r = c >> 2, kk = (c & 3) * 8;
        size_t ga = (size_t)(bm0 + r) * K + kk;
        size_t gb = (size_t)(bn0 + r) * K + kk;
        ASYNC_LDS16(&sAh[0][c * 8], Ah + ga);
        ASYNC_LDS16(&sAl[0][c * 8], Al + ga);
        ASYNC_LDS16(&sBh[0][c * 8], Bth + gb);
        ASYNC_LDS16(&sBl[0][c * 8], Btl + gb);
    }
    __syncthreads();

    const int NT = K >> 5;
    int cur = 0;
    for (int t = 0; t < NT; ++t) {
        if (t + 1 < NT) {
            int k0 = (t + 1) << 5;
#pragma unroll
            for (int i = 0; i < 2; ++i) {
                int c = i * 256 + tid;
                int r = c >> 2, kk = (c & 3) * 8;
                size_t ga = (size_t)(bm0 + r) * K + k0 + kk;
                size_t gb = (size_t)(bn0 + r) * K + k0 + kk;
                ASYNC_LDS16(&sAh[cur ^ 1][c * 8], Ah + ga);
                ASYNC_LDS16(&sAl[cur ^ 1][c * 8], Al + ga);
                ASYNC_LDS16(&sBh[cur ^ 1][c * 8], Bth + gb);
                ASYNC_LDS16(&sBl[cur ^ 1][c * 8], Btl + gb);
            }
        }
        bf16x8 ah[4], al[4], bh[4], bl[4];
#pragma unroll
        for (int m = 0; m < 4; ++m) {
            int off = (wr * 64 + m * 16 + (lane & 15)) * 32 + (lane >> 4) * 8;
            ah[m] = *(const bf16x8*)(&sAh[cur][off]);
            al[m] = *(const bf16x8*)(&sAl[cur][off]);
        }
#pragma unroll
        for (int n = 0; n < 4; ++n) {
            int off = (wc * 64 + n * 16 + (lane & 15)) * 32 + (lane >> 4) * 8;
            bh[n] = *(const bf16x8*)(&sBh[cur][off]);
            bl[n] = *(const bf16x8*)(&sBl[cur][off]);
        }
#pragma unroll
        for (int m = 0; m < 4; ++m)
#pragma unroll
            for (int n = 0; n < 4; ++n) {
                acc[m][n] = __builtin_amdgcn_mfma_f32_16x16x32_bf16(ah[m], bh[n], acc[m][n], 0, 0, 0);
                acc[m][n] = __builtin_amdgcn_mfma_f32_16x16x32_bf16(ah[m], bl[n], acc[m][n], 0, 0, 0);
                acc[m][n] = __builtin_amdgcn_mfma_f32_16x16x32_bf16(al[m], bh[n], acc[m][n], 0, 0, 0);
            }
        __syncthreads();
        cur ^= 1;
    }
#pragma unroll
    for (int m = 0; m < 4; ++m) {
        int row = bm0 + wr * 64 + m * 16 + (lane >> 4) * 4;
#pragma unroll
        for (int n = 0; n < 4; ++n) {
            int col = bn0 + wc * 64 + n * 16 + (lane & 15);
#pragma unroll
            for (int j = 0; j < 4; ++j)
                Cout[(size_t)(row + j) * N + col] = acc[m][n][j];
        }
    }
}

// --------------------------------------------- RoPE + L2-normalize q,k in place
__global__ __launch_bounds__(256) void rope_kernel(float* __restrict__ X1,
                                                   const float2* __restrict__ cs) {
    int w = threadIdx.x >> 6, lane = threadIdx.x & 63;
    int p = blockIdx.x * 4 + w;            // (t,h) pair, 32768 total
    int t = p >> 4, h = p & 15;
    float2 c = cs[t * 32 + (lane & 31)];
#pragma unroll
    for (int which = 0; which < 2; ++which) {
        float* base = X1 + (size_t)t * NQKV + which * 1024 + h * 64;
        float x = base[lane];
        float xo = __shfl(x, lane ^ 32, 64);
        float r = (lane < 32) ? -xo : xo;
        float y = x * c.x + r * c.y;
        float ss = y * y;
#pragma unroll
        for (int m = 32; m; m >>= 1) ss += __shfl_xor(ss, m, 64);
        base[lane] = y * rsqrtf(ss + 1e-12f);
    }
}

// ===================== chunked delta-rule: shared helpers =====================
__device__ __forceinline__ void mm64_3p(const short* Ah, const short* Al,
                                        const short* Bh, const short* Bl,
                                        int w, int lane, fx4 acc[4]) {
#pragma unroll
    for (int k0 = 0; k0 < 64; k0 += 32) {
        int ao = (w * 16 + (lane & 15)) * LP + k0 + ((lane >> 4) * 8);
        bf16x8 ah = *(const bf16x8*)(Ah + ao);
        bf16x8 al = *(const bf16x8*)(Al + ao);
#pragma unroll
        for (int n = 0; n < 4; ++n) {
            int bo = (n * 16 + (lane & 15)) * LP + k0 + ((lane >> 4) * 8);
            bf16x8 bh = *(const bf16x8*)(Bh + bo);
            bf16x8 bl = *(const bf16x8*)(Bl + bo);
            acc[n] = __builtin_amdgcn_mfma_f32_16x16x32_bf16(ah, bh, acc[n], 0, 0, 0);
            acc[n] = __builtin_amdgcn_mfma_f32_16x16x32_bf16(ah, bl, acc[n], 0, 0, 0);
            acc[n] = __builtin_amdgcn_mfma_f32_16x16x32_bf16(al, bh, acc[n], 0, 0, 0);
        }
    }
}

__device__ __forceinline__ void split_write(short* h, short* l, int off, float x) {
    __hip_bfloat16 hb = __float2bfloat16(x);
    ((__hip_bfloat16*)h)[off] = hb;
    ((__hip_bfloat16*)l)[off] = __float2bfloat16(x - __bfloat162float(hb));
}

// ------------------------------------------------ phase A1 (blocked solve)
__global__ __launch_bounds__(256) void phaseA1_kernel(const float* __restrict__ X1,
                                                      __hip_bfloat16* __restrict__ UvWT_hi,
                                                      __hip_bfloat16* __restrict__ UvWT_lo) {
    const int h = blockIdx.x & 15, c = blockIdx.x >> 4;
    const int tid = threadIdx.x, w = tid >> 6, lane = tid & 63;
    const int t0 = c * 64;

    __shared__ short b1h[64 * LP], b1l[64 * LP];     // K hi/lo
    __shared__ float sMT[64 * MP];                   // [s*MP+t] (s<t) = M[t][s]
    __shared__ short xth[128 * LP], xtl[128 * LP];   // XT[j][t] hi/lo (corr -> X)
    __shared__ short mbh[3][512], mbl[3][512];       // M_IJ blocks [tl][k(32)], k>=16 zero
    __shared__ float sLa[64], sB[64], sL[65], sGp[64];

    const float* k_g = X1 + (size_t)t0 * NQKV + 1024 + h * 64;
    const float* v_g = X1 + (size_t)t0 * NQKV + 2048 + h * 64;

    if (tid < 64) {
        float ga = X1[(size_t)(t0 + tid) * NQKV + 4096 + h];
        float gb = X1[(size_t)(t0 + tid) * NQKV + 4112 + h];
        float z = -ga;
        sLa[tid] = -(fmaxf(z, 0.f) + log1pf(expf(-fabsf(z))));
        sB[tid] = 1.f / (1.f + expf(-gb));
    }
    __syncthreads();
    if (tid < 64) {
        float v = sLa[tid];
#pragma unroll
        for (int off = 1; off < 64; off <<= 1) {
            float u = __shfl_up(v, off, 64);
            if (tid >= off) v += u;
        }
        sL[tid + 1] = v;
        if (tid == 0) sL[0] = 0.f;
    }
    __syncthreads();
    if (tid < 64) sGp[tid] = expf(sL[tid]);
    // zero mb (k>=16 region must stay zero)
    for (int idx = tid; idx < 1536; idx += 256) {
        ((short*)mbh)[idx] = 0;
        ((short*)mbl)[idx] = 0;
    }
    // zero-init XT (corr MFMA B-reads span the next panel; LDS garbage can be
    // NaN-pattern bf16 and 0*NaN=NaN in the MFMA accumulator).
    for (int idx = tid; idx < 128 * LP; idx += 256) {
        xth[idx] = 0;
        xtl[idx] = 0;
    }
    // stage K (split)
    for (int idx = tid; idx < 4096; idx += 256) {
        int r = idx >> 6, cc = idx & 63;
        float kv = k_g[(size_t)r * NQKV + cc];
        __hip_bfloat16 hb = __float2bfloat16(kv);
        ((__hip_bfloat16*)b1h)[r * LP + cc] = hb;
        ((__hip_bfloat16*)b1l)[r * LP + cc] = __float2bfloat16(kv - __bfloat162float(hb));
    }
    __syncthreads();

    // G = K K^T, one 16-row strip per wave; scatter sMT[s][t] = M[t][s]
    {
        const int r0 = w * 16;
        fx4 acc[4];
#pragma unroll
        for (int n = 0; n < 4; ++n) acc[n] = {0.f, 0.f, 0.f, 0.f};
#pragma unroll
        for (int k0 = 0; k0 < 64; k0 += 32) {
            int ao = (r0 + (lane & 15)) * LP + k0 + ((lane >> 4) * 8);
            bf16x8 ah = *(const bf16x8*)(b1h + ao);
            bf16x8 al = *(const bf16x8*)(b1l + ao);
#pragma unroll
            for (int n = 0; n < 4; ++n) {
                int bo = (n * 16 + (lane & 15)) * LP + k0 + ((lane >> 4) * 8);
                bf16x8 bh = *(const bf16x8*)(b1h + bo);
                bf16x8 bl = *(const bf16x8*)(b1l + bo);
                acc[n] = __builtin_amdgcn_mfma_f32_16x16x32_bf16(ah, bh, acc[n], 0, 0, 0);
                acc[n] = __builtin_amdgcn_mfma_f32_16x16x32_bf16(ah, bl, acc[n], 0, 0, 0);
                acc[n] = __builtin_amdgcn_mfma_f32_16x16x32_bf16(al, bh, acc[n], 0, 0, 0);
            }
        }
#pragma unroll
        for (int n = 0; n < 4; ++n)
#pragma unroll
            for (int jj = 0; jj < 4; ++jj) {
                int t = r0 + (lane >> 4) * 4 + jj, s = n * 16 + (lane & 15);
                if (s < t) sMT[s * MP + t] = sB[t] * expf(sL[t] - sL[s + 1]) * acc[n][jj];
            }
    }
    __syncthreads();

    // blocked forward substitution over 4 panels of 16
#pragma unroll
    for (int I = 0; I < 4; ++I) {
        for (int idx = tid; idx < I * 256; idx += 256) {
            int J = idx >> 8, e = idx & 255;
            int tl = e >> 4, sl = e & 15;
            float mv = sMT[(J * 16 + sl) * MP + (I * 16 + tl)];
            __hip_bfloat16 hb = __float2bfloat16(mv);
            ((__hip_bfloat16*)&mbh[J][0])[tl * 32 + sl] = hb;
            ((__hip_bfloat16*)&mbl[J][0])[tl * 32 + sl] = __float2bfloat16(mv - __bfloat162float(hb));
        }
        __syncthreads();    // mb ready; XT panels J<I ready (prev-iter barrier)
        if (I > 0) {
            fx4 acc2[2];
            acc2[0] = {0.f, 0.f, 0.f, 0.f};
            acc2[1] = {0.f, 0.f, 0.f, 0.f};
#pragma unroll
            for (int g = 0; g < 2; ++g) {
                const int jb = (w * 2 + g) * 16;
                for (int J = 0; J < I; ++J) {
                    bf16x8 ah = *(const bf16x8*)((const short*)&mbh[J][0] + (lane & 15) * 32 + (lane >> 4) * 8);
                    bf16x8 al = *(const bf16x8*)((const short*)&mbl[J][0] + (lane & 15) * 32 + (lane >> 4) * 8);
                    int bo = (jb + (lane & 15)) * LP + J * 16 + ((lane >> 4) * 8);
                    bf16x8 bh = *(const bf16x8*)(xth + bo);
                    bf16x8 bl = *(const bf16x8*)(xtl + bo);
                    acc2[g] = __builtin_amdgcn_mfma_f32_16x16x32_bf16(ah, bh, acc2[g], 0, 0, 0);
                    acc2[g] = __builtin_amdgcn_mfma_f32_16x16x32_bf16(ah, bl, acc2[g], 0, 0, 0);
                    acc2[g] = __builtin_amdgcn_mfma_f32_16x16x32_bf16(al, bh, acc2[g], 0, 0, 0);
                }
            }
#pragma unroll
            for (int g = 0; g < 2; ++g) {
                const int jb = (w * 2 + g) * 16;
#pragma unroll
                for (int jj = 0; jj < 4; ++jj) {
                    int j = jb + (lane & 15);
                    int t = I * 16 + (lane >> 4) * 4 + jj;
                    split_write(xth, xtl, j * LP + t, acc2[g][jj]);
                }
            }
        }
        __syncthreads();    // corr visible to solver threads
        if (tid < 128) {
            const int j = tid;
            float xs[16];
#pragma unroll
            for (int tl = 0; tl < 16; ++tl) {
                const int t = I * 16 + tl;
                float base;
                if (j < 64) {
                    base = v_g[(size_t)t * NQKV + j];
                } else {
                    int i = j - 64;
                    base = (__bfloat162float(((__hip_bfloat16*)b1h)[t * LP + i]) +
                            __bfloat162float(((__hip_bfloat16*)b1l)[t * LP + i])) * sGp[t];
                }
                float r = sB[t] * base;
                if (I > 0) {
                    r -= __bfloat162float(((__hip_bfloat16*)xth)[j * LP + t]) +
                         __bfloat162float(((__hip_bfloat16*)xtl)[j * LP + t]);
                }
#pragma unroll
                for (int sl = 0; sl < tl; ++sl)
                    r = fmaf(-sMT[(I * 16 + sl) * MP + t], xs[sl], r);
                xs[tl] = r;
                __hip_bfloat16 hb = __float2bfloat16(r);
                ((__hip_bfloat16*)xth)[j * LP + t] = hb;
                ((__hip_bfloat16*)xtl)[j * LP + t] = __float2bfloat16(r - __bfloat162float(hb));
            }
        }
        __syncthreads();    // X_I published for next panel's MFMA
    }

    // write out t-major (coalesced): UvWT[hc][t][j] = XT[j][t]
    size_t obase = (size_t)(h * 32 + c) * 8192;
    for (int idx = tid; idx < 8192; idx += 256) {
        int t = idx >> 7, j = idx & 127;
        UvWT_hi[obase + idx] = ((__hip_bfloat16*)xth)[j * LP + t];
        UvWT_lo[obase + idx] = ((__hip_bfloat16*)xtl)[j * LP + t];
    }
}

// ------------------------------------------------ phase A2 (matmuls, parallel)
__global__ __launch_bounds__(256) void phaseA2_kernel(float* __restrict__ X1,
                                                      const __hip_bfloat16* __restrict__ UvWT_hi,
                                                      const __hip_bfloat16* __restrict__ UvWT_lo,
                                                      short* __restrict__ AcBuf,
                                                      float* __restrict__ BcBuf) {
    const int h = blockIdx.x & 15, c = blockIdx.x >> 4;
    const int tid = threadIdx.x, w = tid >> 6, lane = tid & 63;
    const int t0 = c * 64;

    __shared__ short b1h[64 * LP], b1l[64 * LP];   // K
    __shared__ short b2h[64 * LP], b2l[64 * LP];   // Q -> Ptilde -> KhatT
    __shared__ short b3h[64 * LP], b3l[64 * LP];   // UvT
    __shared__ short b4h[64 * LP], b4l[64 * LP];   // WT
    __shared__ float sLa[64], sL[65], sGp[64], sRc[64];

    const float* q_g = X1 + (size_t)t0 * NQKV + h * 64;
    const float* k_g = q_g + 1024;

    if (tid < 64) {
        float ga = X1[(size_t)(t0 + tid) * NQKV + 4096 + h];
        float z = -ga;
        sLa[tid] = -(fmaxf(z, 0.f) + log1pf(expf(-fabsf(z))));
    }
    __syncthreads();
    if (tid < 64) {
        float v = sLa[tid];
#pragma unroll
        for (int off = 1; off < 64; off <<= 1) {
            float u = __shfl_up(v, off, 64);
            if (tid >= off) v += u;
        }
        sL[tid + 1] = v;
        if (tid == 0) sL[0] = 0.f;
    }
    __syncthreads();
    if (tid < 64) {
        sGp[tid] = expf(sL[tid]);
        sRc[tid] = expf(sL[64] - sL[tid + 1]);
    }
    // stage Q, K (split) and UvT/WT
    for (int idx = tid; idx < 4096; idx += 256) {
        int r = idx >> 6, cc = idx & 63;
        split_write(b2h, b2l, r * LP + cc, q_g[(size_t)r * NQKV + cc]);
        split_write(b1h, b1l, r * LP + cc, k_g[(size_t)r * NQKV + cc]);
    }
    const __hip_bfloat16* uh = UvWT_hi + (size_t)(h * 32 + c) * 8192;
    const __hip_bfloat16* ul = UvWT_lo + (size_t)(h * 32 + c) * 8192;
    for (int idx = tid; idx < 8192; idx += 256) {
        int t = idx >> 7, row = idx & 127;
        short* dh = (row < 64) ? b3h : b4h;
        short* dl = (row < 64) ? b3l : b4l;
        ((__hip_bfloat16*)dh)[(row & 63) * LP + t] = uh[idx];
        ((__hip_bfloat16*)dl)[(row & 63) * LP + t] = ul[idx];
    }
    __syncthreads();

    // P = Q K^T
    fx4 pacc[4];
#pragma unroll
    for (int n = 0; n < 4; ++n) pacc[n] = {0.f, 0.f, 0.f, 0.f};
    mm64_3p(b2h, b2l, b1h, b1l, w, lane, pacc);
    __syncthreads();
    // Ptilde -> b2 (masked, scaled)
#pragma unroll
    for (int n = 0; n < 4; ++n)
#pragma unroll
        for (int jj = 0; jj < 4; ++jj) {
            int t = w * 16 + (lane >> 4) * 4 + jj, s = n * 16 + (lane & 15);
            float pv = (s < t) ? expf(sL[t] - sL[s + 1]) * pacc[n][jj] : 0.f;
            split_write(b2h, b2l, t * LP + s, pv);
        }
    __syncthreads();

    // Olocal = Ptilde @ Uv -> overwrite k-region (f32)
    {
        fx4 acc[4];
#pragma unroll
        for (int n = 0; n < 4; ++n) acc[n] = {0.f, 0.f, 0.f, 0.f};
        mm64_3p(b2h, b2l, b3h, b3l, w, lane, acc);
        float* og = X1 + (size_t)t0 * NQKV + 1024 + h * 64;
#pragma unroll
        for (int n = 0; n < 4; ++n)
#pragma unroll
            for (int jj = 0; jj < 4; ++jj) {
                int t = w * 16 + (lane >> 4) * 4 + jj, s = n * 16 + (lane & 15);
                og[(size_t)t * NQKV + s] = acc[n][jj];
            }
    }
    // PW = Ptilde @ W ; Qeff = diag(gprev)Q - PW -> overwrite q-region (f32)
    {
        fx4 acc[4];
#pragma unroll
        for (int n = 0; n < 4; ++n) acc[n] = {0.f, 0.f, 0.f, 0.f};
        mm64_3p(b2h, b2l, b4h, b4l, w, lane, acc);
        float* qg = X1 + (size_t)t0 * NQKV + h * 64;
#pragma unroll
        for (int n = 0; n < 4; ++n)
#pragma unroll
            for (int jj = 0; jj < 4; ++jj) {
                int t = w * 16 + (lane >> 4) * 4 + jj, s = n * 16 + (lane & 15);
                float qv = qg[(size_t)t * NQKV + s];
                qg[(size_t)t * NQKV + s] = sGp[t] * qv - acc[n][jj];
            }
    }
    __syncthreads();   // all reads of b2 (Ptilde) complete
    // KhatT -> b2: [i][s] = rC[s] * K[s][i]
    for (int idx = tid; idx < 4096; idx += 256) {
        int s = idx >> 6, i = idx & 63;
        float kv = __bfloat162float(((__hip_bfloat16*)b1h)[s * LP + i]) +
                   __bfloat162float(((__hip_bfloat16*)b1l)[s * LP + i]);
        split_write(b2h, b2l, i * LP + s, sRc[s] * kv);
    }
    __syncthreads();

    // Ac = gammaEnd*I - KhatT @ W -> AcBuf (bf16 hi/lo, row-major [i][j])
    {
        fx4 acc[4];
#pragma unroll
        for (int n = 0; n < 4; ++n) acc[n] = {0.f, 0.f, 0.f, 0.f};
        mm64_3p(b2h, b2l, b4h, b4l, w, lane, acc);
        float gend = expf(sL[64]);
        size_t abase = (size_t)(h * 32 + c) * 8192;
#pragma unroll
        for (int n = 0; n < 4; ++n)
#pragma unroll
            for (int jj = 0; jj < 4; ++jj) {
                int i = w * 16 + (lane >> 4) * 4 + jj, jd = n * 16 + (lane & 15);
                float av = ((i == jd) ? gend : 0.f) - acc[n][jj];
                __hip_bfloat16 hb = __float2bfloat16(av);
                ((__hip_bfloat16*)AcBuf)[abase + i * 64 + jd] = hb;
                ((__hip_bfloat16*)AcBuf)[abase + 4096 + i * 64 + jd] =
                    __float2bfloat16(av - __bfloat162float(hb));
            }
    }
    // BcT = UvT @ KhatT' -> BcBuf (f32, [v][i])
    {
        fx4 acc[4];
#pragma unroll
        for (int n = 0; n < 4; ++n) acc[n] = {0.f, 0.f, 0.f, 0.f};
        mm64_3p(b3h, b3l, b2h, b2l, w, lane, acc);
        size_t bbase = (size_t)(h * 32 + c) * 4096;
#pragma unroll
        for (int n = 0; n < 4; ++n)
#pragma unroll
            for (int jj = 0; jj < 4; ++jj) {
                int jv = w * 16 + (lane >> 4) * 4 + jj, i = n * 16 + (lane & 15);
                BcBuf[bbase + jv * 64 + i] = acc[n][jj];
            }
    }
}

// --------------------------------------------------- phase B (state recurrence)
__global__ __launch_bounds__(256) void phaseB_kernel(const short* __restrict__ AcBuf,
                                                     const float* __restrict__ BcBuf,
                                                     float* __restrict__ X1) {
    const int h = blockIdx.x;
    const int tid = threadIdx.x, w = tid >> 6, lane = tid & 63;
    const int lr = (lane >> 4) * 4;                // C-layout row offset
    const int lc = lane & 15;                      // C-layout col offset
    __shared__ short sAc[2][8192];                 // [hi 4096 | lo 4096] shorts, row stride 64
    __shared__ float sST[64 * 68];                 // S^T staging (intra-wave)

    const size_t hc0 = (size_t)h * 32;
    {
        const char* src = (const char*)AcBuf + hc0 * 16384;
        char* dst = (char*)&sAc[0][0];
        int off = w * 4096 + lane * 16;
#pragma unroll
        for (int q = 0; q < 4; ++q) { ASYNC_LDS16(dst + off, src + off); off += 1024; }
    }
    fx4 acc[4];
#pragma unroll
    for (int n = 0; n < 4; ++n) acc[n] = {0.f, 0.f, 0.f, 0.f};
    float bcur[16];
    {
        const float* bg = BcBuf + hc0 * 4096;
#pragma unroll
        for (int n = 0; n < 4; ++n)
#pragma unroll
            for (int jj = 0; jj < 4; ++jj)
                bcur[n * 4 + jj] = bg[(w * 16 + lr + jj) * 64 + n * 16 + lc];
    }

#pragma unroll 1
    for (int c = 0; c < 32; ++c) {
        __syncthreads();
        {
            int cn = (c < 31) ? c + 1 : 31;
            const char* src = (const char*)AcBuf + (hc0 + cn) * 16384;
            char* dst = (char*)&sAc[(c + 1) & 1][0];
            int off = w * 4096 + lane * 16;
#pragma unroll
            for (int q = 0; q < 4; ++q) { ASYNC_LDS16(dst + off, src + off); off += 1024; }
        }
        float bnext[16];
        {
            int cn = (c < 31) ? c + 1 : 31;
            const float* bg = BcBuf + (hc0 + cn) * 4096;
#pragma unroll
            for (int n = 0; n < 4; ++n)
#pragma unroll
                for (int jj = 0; jj < 4; ++jj)
                    bnext[n * 4 + jj] = bg[(w * 16 + lr + jj) * 64 + n * 16 + lc];
        }
        float* stg = X1 + (size_t)(c * 64) * NQKV + 2048 + h * 64;
#pragma unroll
        for (int n = 0; n < 4; ++n)
#pragma unroll
            for (int jj = 0; jj < 4; ++jj) {
                int r = w * 16 + lr + jj, i = n * 16 + lc;
                stg[(size_t)r * NQKV + i] = acc[n][jj];
                sST[r * 68 + i] = acc[n][jj];
            }
        const short* bufc = &sAc[c & 1][0];
        fx4 nacc[4];
#pragma unroll
        for (int n = 0; n < 4; ++n)
            nacc[n] = {bcur[n * 4 + 0], bcur[n * 4 + 1], bcur[n * 4 + 2], bcur[n * 4 + 3]};
#pragma unroll
        for (int k0 = 0; k0 < 2; ++k0) {
            const float* ap = sST + (w * 16 + lc) * 68 + k0 * 32 + (lane >> 4) * 8;
            float4 f0 = *(const float4*)ap;
            float4 f1 = *(const float4*)(ap + 4);
            float fv[8] = {f0.x, f0.y, f0.z, f0.w, f1.x, f1.y, f1.z, f1.w};
            bf16x8 afh, afl;
#pragma unroll
            for (int e = 0; e < 8; ++e) {
                __hip_bfloat16 hb = __float2bfloat16(fv[e]);
                __hip_bfloat16 lb = __float2bfloat16(fv[e] - __bfloat162float(hb));
                afh[e] = *(__bf16*)&hb;
                afl[e] = *(__bf16*)&lb;
            }
#pragma unroll
            for (int n = 0; n < 4; ++n) {
                int ro = (n * 16 + lc) * 64 + k0 * 32 + (lane >> 4) * 8;   // shorts
                bf16x8 bh = *(const bf16x8*)(bufc + ro);
                bf16x8 bl = *(const bf16x8*)(bufc + 4096 + ro);
                nacc[n] = __builtin_amdgcn_mfma_f32_16x16x32_bf16(afh, bh, nacc[n], 0, 0, 0);
                nacc[n] = __builtin_amdgcn_mfma_f32_16x16x32_bf16(afh, bl, nacc[n], 0, 0, 0);
                nacc[n] = __builtin_amdgcn_mfma_f32_16x16x32_bf16(afl, bh, nacc[n], 0, 0, 0);
            }
        }
#pragma unroll
        for (int n = 0; n < 4; ++n) acc[n] = nacc[n];
#pragma unroll
        for (int e = 0; e < 16; ++e) bcur[e] = bnext[e];
    }
}

// --------------------------------------------- phase C (outputs + epilogue)
__global__ __launch_bounds__(256) void phaseC_kernel(const float* __restrict__ X1,
                                                     const float* __restrict__ onw,
                                                     __hip_bfloat16* __restrict__ attn_bf) {
    const int h = blockIdx.x & 15, c = blockIdx.x >> 4;
    const int tid = threadIdx.x, w = tid >> 6, lane = tid & 63;
    const int t0 = c * 64;
    __shared__ short qh[64 * LP], ql[64 * LP];
    __shared__ short sh_[64 * LP], sl_[64 * LP];
    __shared__ float sO[4096];
    __shared__ float part[64][4];
    const float* qe = X1 + (size_t)t0 * NQKV + h * 64;          // Qeff
    const float* stg = X1 + (size_t)t0 * NQKV + 2048 + h * 64;  // S^T (entering c)
    const float* ol = X1 + (size_t)t0 * NQKV + 1024 + h * 64;   // Olocal
    for (int idx = tid; idx < 4096; idx += 256) {
        int r = idx >> 6, i = idx & 63;
        split_write(qh, ql, r * LP + i, qe[(size_t)r * NQKV + i]);
        split_write(sh_, sl_, r * LP + i, stg[(size_t)r * NQKV + i]);
    }
    __syncthreads();
    fx4 acc[4];
#pragma unroll
    for (int n = 0; n < 4; ++n)
#pragma unroll
        for (int jj = 0; jj < 4; ++jj)
            acc[n][jj] = ol[(size_t)(w * 16 + (lane >> 4) * 4 + jj) * NQKV + n * 16 + (lane & 15)];
    mm64_3p(qh, ql, sh_, sl_, w, lane, acc);
#pragma unroll
    for (int n = 0; n < 4; ++n)
#pragma unroll
        for (int jj = 0; jj < 4; ++jj)
            sO[(w * 16 + (lane >> 4) * 4 + jj) * 64 + n * 16 + (lane & 15)] = acc[n][jj];
    __syncthreads();
    int r = tid >> 2, qq = tid & 3;
    float ss = 0.f;
#pragma unroll
    for (int i2 = 0; i2 < 16; ++i2) { float v = sO[r * 64 + qq * 16 + i2]; ss += v * v; }
    part[r][qq] = ss;
    __syncthreads();
    float tot = part[r][0] + part[r][1] + part[r][2] + part[r][3];
    float sc = rsqrtf(tot * (1.f / 64.f) + 1e-6f);
    const float* gg = X1 + (size_t)(t0 + r) * NQKV + 3072 + h * 64;
#pragma unroll
    for (int i2 = 0; i2 < 16; ++i2) {
        int j = qq * 16 + i2;
        float on = sO[r * 64 + j] * sc * onw[j];
        float g = gg[j];
        float sg = g / (1.f + expf(-g));
        attn_bf[(size_t)(t0 + r) * 1024 + h * 64 + j] = __float2bfloat16(on * sg);
    }
}

// ---------------------------- h = hidden + attn (in place); ybf = rmsnorm(h)
__global__ __launch_bounds__(256) void add_rmsnorm_kernel(
    const float* __restrict__ hidden, float* __restrict__ acc,
    const float* __restrict__ w, __hip_bfloat16* __restrict__ out) {
    int t = blockIdx.x;
    int d = threadIdx.x * 4;
    float4 a = *(const float4*)(acc + (size_t)t * D_MODEL + d);
    float4 hd = *(const float4*)(hidden + (size_t)t * D_MODEL + d);
    float4 h4 = make_float4(a.x + hd.x, a.y + hd.y, a.z + hd.z, a.w + hd.w);
    *(float4*)(acc + (size_t)t * D_MODEL + d) = h4;
    float ss = h4.x * h4.x + h4.y * h4.y + h4.z * h4.z + h4.w * h4.w;
#pragma unroll
    for (int m = 32; m; m >>= 1) ss += __shfl_xor(ss, m, 64);
    __shared__ float wsum[4];
    if ((threadIdx.x & 63) == 0) wsum[threadIdx.x >> 6] = ss;
    __syncthreads();
    float tot = wsum[0] + wsum[1] + wsum[2] + wsum[3];
    float sc = rsqrtf(tot * (1.f / 1024.f) + 1e-6f);
    const float4 wv = *(const float4*)(w + d);
    __hip_bfloat16* op = out + (size_t)t * D_MODEL + d;
    op[0] = __float2bfloat16(h4.x * sc * wv.x);
    op[1] = __float2bfloat16(h4.y * sc * wv.y);
    op[2] = __float2bfloat16(h4.z * sc * wv.z);
    op[3] = __float2bfloat16(h4.w * sc * wv.w);
}

// ---------------------------------------------- m = silu(G) * U (bf16 in/out)
__global__ __launch_bounds__(256) void silu_mul_kernel(const __hip_bfloat16* __restrict__ GU,
                                                       __hip_bfloat16* __restrict__ m) {
    size_t i = (size_t)blockIdx.x * 256 + threadIdx.x;   // 2048*4096
    size_t t = i >> 12, j = i & 4095;
    float g = __bfloat162float(GU[t * 8192 + j]);
    float u = __bfloat162float(GU[t * 8192 + 4096 + j]);
    m[i] = __float2bfloat16(u * g / (1.f + expf(-g)));
}

// ----------------------------------------------------------- out += h
__global__ __launch_bounds__(256) void final_add_kernel(float* __restrict__ out,
                                                        const float* __restrict__ h) {
    size_t i = (size_t)blockIdx.x * 256 + threadIdx.x;
    out[i] += h[i];
}

// ---------------------------------------------------------------------------
extern "C" void kernel_launch(void* const* d_in, const int* in_sizes, int n_in,
                              void* d_out, int out_size, void* d_ws, size_t ws_size,
                              hipStream_t stream) {
    (void)in_sizes; (void)n_in; (void)out_size; (void)ws_size;
    const float* hidden     = (const float*)d_in[0];
    const float* norm1_w    = (const float*)d_in[1];
    const float* q_w        = (const float*)d_in[2];
    const float* k_w        = (const float*)d_in[3];
    const float* v_w        = (const float*)d_in[4];
    const float* g_w        = (const float*)d_in[5];
    const float* b_w        = (const float*)d_in[6];
    const float* gate_w     = (const float*)d_in[7];
    const float* o_norm_w   = (const float*)d_in[8];
    const float* o_w        = (const float*)d_in[9];
    const float* norm2_w    = (const float*)d_in[10];
    const float* mlp_gate_w = (const float*)d_in[11];
    const float* mlp_up_w   = (const float*)d_in[12];
    const float* mlp_down_w = (const float*)d_in[13];

    char* ws = (char*)d_ws;
    // workspace (~92 MiB), timeline-reused:
    const size_t OFF_WT_QKVG = 0;          // wt_qkvg_hi -> AcBuf
    const size_t OFF_WT_O    = 8650752;
    const size_t OFF_WT_GU   = 10747904;
    const size_t OFF_WT_DOWN = 27525120;
    const size_t OFF_X1      = 35913728;   // X1 f32 -> GU bf16
    const size_t OFF_R1      = 70516736;   // wt_qkvg_lo -> BcBuf -> mbf
    const size_t OFF_ATTN    = 79167488;   // UvWT_lo (A1/A2) -> attn_bf+ybf
    const size_t OFF_YBF     = 83361792;
    const size_t OFF_XHI     = 87556096;   // xhi/xlo -> UvWT_hi -> h_buf
    const size_t OFF_XLO     = 91750400;
    const size_t OFF_ROPE    = 95944704;

    __hip_bfloat16* wt_qkvg_hi = (__hip_bfloat16*)(ws + OFF_WT_QKVG);
    __hip_bfloat16* wt_qkvg_lo = (__hip_bfloat16*)(ws + OFF_R1);
    __hip_bfloat16* wt_o    = (__hip_bfloat16*)(ws + OFF_WT_O);
    __hip_bfloat16* wt_gu   = (__hip_bfloat16*)(ws + OFF_WT_GU);
    __hip_bfloat16* wt_down = (__hip_bfloat16*)(ws + OFF_WT_DOWN);
    float*          X1      = (float*)(ws + OFF_X1);
    __hip_bfloat16* GU      = (__hip_bfloat16*)(ws + OFF_X1);
    short*          AcBuf   = (short*)(ws + OFF_WT_QKVG);       // after qkv gemm
    float*          BcBuf   = (float*)(ws + OFF_R1);            // after qkv gemm
    __hip_bfloat16* mbf     = (__hip_bfloat16*)(ws + OFF_R1);   // after phase B/C
    __hip_bfloat16* attn_bf = (__hip_bfloat16*)(ws + OFF_ATTN);
    __hip_bfloat16* xhi     = (__hip_bfloat16*)(ws + OFF_XHI);
    __hip_bfloat16* xlo     = (__hip_bfloat16*)(ws + OFF_XLO);
    __hip_bfloat16* UvWT_hi = (__hip_bfloat16*)(ws + OFF_XHI);  // 8.39MB, after qkv gemm
    __hip_bfloat16* UvWT_lo = (__hip_bfloat16*)(ws + OFF_ATTN); // 8.39MB, until phaseC
    float*          h_buf   = (float*)(ws + OFF_XHI);           // after phaseA2
    __hip_bfloat16* ybf     = (__hip_bfloat16*)(ws + OFF_YBF);
    float2*         rope_cs = (float2*)(ws + OFF_ROPE);

    dim3 tb(32, 8);
    rope_table_kernel<<<256, 256, 0, stream>>>(rope_cs);
    rmsnorm_split_kernel<<<2048, 256, 0, stream>>>(hidden, norm1_w, xhi, xlo);
    transpose_split_kernel<<<dim3(32, 32), tb, 0, stream>>>(q_w,    wt_qkvg_hi,               wt_qkvg_lo,               1024, 1024, 1024);
    transpose_split_kernel<<<dim3(32, 32), tb, 0, stream>>>(k_w,    wt_qkvg_hi + 1024 * 1024, wt_qkvg_lo + 1024 * 1024, 1024, 1024, 1024);
    transpose_split_kernel<<<dim3(32, 32), tb, 0, stream>>>(v_w,    wt_qkvg_hi + 2048 * 1024, wt_qkvg_lo + 2048 * 1024, 1024, 1024, 1024);
    transpose_split_kernel<<<dim3(32, 32), tb, 0, stream>>>(gate_w, wt_qkvg_hi + 3072 * 1024, wt_qkvg_lo + 3072 * 1024, 1024, 1024, 1024);
    transpose_split_kernel<<<dim3(32, 1),  tb, 0, stream>>>(g_w,    wt_qkvg_hi + 4096 * 1024, wt_qkvg_lo + 4096 * 1024, 1024, 16,   16);
    transpose_split_kernel<<<dim3(32, 4),  tb, 0, stream>>>(b_w,    wt_qkvg_hi + 4112 * 1024, wt_qkvg_lo + 4112 * 1024, 1024, 16,   112);
    transpose_bf16_kernel<<<dim3(32, 32),  tb, 0, stream>>>(o_w,        wt_o,                1024, 1024, 1024);
    transpose_bf16_kernel<<<dim3(32, 128), tb, 0, stream>>>(mlp_gate_w, wt_gu,               1024, 4096, 4096);
    transpose_bf16_kernel<<<dim3(32, 128), tb, 0, stream>>>(mlp_up_w,   wt_gu + 4096 * 1024, 1024, 4096, 4096);
    transpose_bf16_kernel<<<dim3(128, 32), tb, 0, stream>>>(mlp_down_w, wt_down,             4096, 1024, 1024);
    // fused q|k|v|gate|g|b projection (split precision)
    gemm_bt_split<<<dim3(33, 16), 256, 0, stream>>>(xhi, xlo, wt_qkvg_hi, wt_qkvg_lo, X1, 2048, NQKV, 1024);
    rope_kernel<<<8192, 256, 0, stream>>>(X1, rope_cs);
    // chunked delta-rule scan
    phaseA1_kernel<<<512, 256, 0, stream>>>(X1, UvWT_hi, UvWT_lo);
    phaseA2_kernel<<<512, 256, 0, stream>>>(X1, UvWT_hi, UvWT_lo, AcBuf, BcBuf);
    phaseB_kernel<<<16, 256, 0, stream>>>(AcBuf, BcBuf, X1);
    phaseC_kernel<<<512, 256, 0, stream>>>(X1, o_norm_w, attn_bf);
    // attn out projection -> h
    gemm_bt<false><<<dim3(8, 16), 256, 0, stream>>>(attn_bf, wt_o, h_buf, 2048, 1024, 1024);
    add_rmsnorm_kernel<<<2048, 256, 0, stream>>>(hidden, h_buf, norm2_w, ybf);
    gemm_bt<true><<<dim3(64, 16), 256, 0, stream>>>(ybf, wt_gu, GU, 2048, 8192, 1024);
    silu_mul_kernel<<<32768, 256, 0, stream>>>(GU, mbf);
    gemm_bt<false><<<dim3(8, 16), 256, 0, stream>>>(mbf, wt_down, (float*)d_out, 2048, 1024, 4096);
    final_add_kernel<<<8192, 256, 0, stream>>>((float*)d_out, h_buf);
}

// Round 12
// 433.209 us; speedup vs baseline: 1.4982x; 1.0490x over previous
//
#include <hip/hip_runtime.h>
#include <hip/hip_bf16.h>

// ---------------------------------------------------------------------------
// DepthDeltaNetDecoderLayer: B=1, T=2048, D=1024, H=16, DK=DV=64, FF=4096
// Round 12:
//  (1) XCD swizzle (T1, x-major chunked) on all GEMMs: B-panels become
//      XCD-L2-local (FETCH was 4x unique bytes from cross-XCD re-fetch).
//  (2) 128x64-tile GEMM for o-proj/down-proj: 128->256 blocks (full chip),
//      24KB LDS dbuf -> 6 blk/CU. Same k-order per element (bitwise ident).
// ---------------------------------------------------------------------------

#define T_SEQ 2048
#define D_MODEL 1024
#define NH 16
#define DK 64
#define DV 64
#define FF 4096
#define NQKV 4224   // q(1024) k(1024) v(1024) gate(1024) g(16@4096) b(16@4112) pad->4224
#define LP 72       // padded LDS stride (shorts), 144B rows (16B-aligned)
#define MP 68       // padded stride (floats) for M^T

typedef __bf16 bf16x8 __attribute__((ext_vector_type(8)));
typedef float  fx4    __attribute__((ext_vector_type(4)));

#if defined(__has_builtin)
#if __has_builtin(__builtin_amdgcn_global_load_lds)
#define HAVE_GLOAD_LDS 1
#endif
#endif

#ifdef HAVE_GLOAD_LDS
#define ASYNC_LDS16(dst, src)                                                   \
    __builtin_amdgcn_global_load_lds(                                           \
        (__attribute__((address_space(1))) void*)(src),                         \
        (__attribute__((address_space(3))) void*)(dst), 16, 0, 0)
#else
#define ASYNC_LDS16(dst, src) (*(int4*)(dst) = *(const int4*)(src))
#endif

// XCD-aware block remap: hw dispatch id (x-fastest) round-robins across the 8
// XCDs; give each XCD a contiguous x-major chunk of tiles so B-panels (x dim)
// stay XCD-L2-local. Bijective when nwg % 8 == 0 (all our grids). Pure
// permutation -> output identical regardless of mapping.
__device__ __forceinline__ void xcd_swizzle(int& bx, int& by) {
    int gx = gridDim.x, gy = gridDim.y;
    int id = blockIdx.y * gx + blockIdx.x;     // hw dispatch order
    int cpx = (gx * gy) >> 3;                  // chunk per XCD
    int lin = (id & 7) * cpx + (id >> 3);      // x-major tile index
    bx = lin / gy;
    by = lin - bx * gy;
}

// ---------------------------------------------------------------- rope table
__global__ void rope_table_kernel(float2* __restrict__ cs) {
    int idx = blockIdx.x * 256 + threadIdx.x;      // t*32 + i, 65536 total
    int t = idx >> 5, i = idx & 31;
    float freq = (float)t * powf(10000.f, -(float)i / 32.f);
    cs[idx] = make_float2(cosf(freq), sinf(freq));
}

// --------------------------------------- row rmsnorm -> bf16 hi + bf16 lo
__global__ __launch_bounds__(256) void rmsnorm_split_kernel(
    const float* __restrict__ in, const float* __restrict__ w,
    __hip_bfloat16* __restrict__ hi, __hip_bfloat16* __restrict__ lo) {
    int t = blockIdx.x;
    int d = threadIdx.x * 4;
    const float4 v = *(const float4*)(in + (size_t)t * D_MODEL + d);
    float ss = v.x * v.x + v.y * v.y + v.z * v.z + v.w * v.w;
#pragma unroll
    for (int m = 32; m; m >>= 1) ss += __shfl_xor(ss, m, 64);
    __shared__ float wsum[4];
    if ((threadIdx.x & 63) == 0) wsum[threadIdx.x >> 6] = ss;
    __syncthreads();
    float tot = wsum[0] + wsum[1] + wsum[2] + wsum[3];
    float sc = rsqrtf(tot * (1.f / 1024.f) + 1e-6f);
    const float4 wv = *(const float4*)(w + d);
    float xs[4] = {v.x * sc * wv.x, v.y * sc * wv.y, v.z * sc * wv.z, v.w * sc * wv.w};
    __hip_bfloat16* hp = hi + (size_t)t * D_MODEL + d;
    __hip_bfloat16* lp = lo + (size_t)t * D_MODEL + d;
#pragma unroll
    for (int j = 0; j < 4; ++j) {
        __hip_bfloat16 h = __float2bfloat16(xs[j]);
        hp[j] = h;
        lp[j] = __float2bfloat16(xs[j] - __bfloat162float(h));
    }
}

// ------------------------------------------- W (KxN f32) -> Wt (Npad x K bf16)
__global__ void transpose_bf16_kernel(const float* __restrict__ W,
                                      __hip_bfloat16* __restrict__ Wt,
                                      int K, int N, int Npad) {
    __shared__ float tile[32][33];
    int k0 = blockIdx.x * 32, n0 = blockIdx.y * 32;
    int tx = threadIdx.x, ty = threadIdx.y;   // (32,8)
#pragma unroll
    for (int i = 0; i < 32; i += 8) {
        int n = n0 + tx;
        tile[ty + i][tx] = (n < N) ? W[(size_t)(k0 + ty + i) * N + n] : 0.f;
    }
    __syncthreads();
#pragma unroll
    for (int i = 0; i < 32; i += 8) {
        int n = n0 + ty + i;
        if (n < Npad) Wt[(size_t)n * K + k0 + tx] = __float2bfloat16(tile[tx][ty + i]);
    }
}

// ---------------------- W (KxN f32) -> Wt_hi, Wt_lo (Npad x K bf16 each)
__global__ void transpose_split_kernel(const float* __restrict__ W,
                                       __hip_bfloat16* __restrict__ Wt_hi,
                                       __hip_bfloat16* __restrict__ Wt_lo,
                                       int K, int N, int Npad) {
    __shared__ float tile[32][33];
    int k0 = blockIdx.x * 32, n0 = blockIdx.y * 32;
    int tx = threadIdx.x, ty = threadIdx.y;   // (32,8)
#pragma unroll
    for (int i = 0; i < 32; i += 8) {
        int n = n0 + tx;
        tile[ty + i][tx] = (n < N) ? W[(size_t)(k0 + ty + i) * N + n] : 0.f;
    }
    __syncthreads();
#pragma unroll
    for (int i = 0; i < 32; i += 8) {
        int n = n0 + ty + i;
        if (n < Npad) {
            float x = tile[tx][ty + i];
            __hip_bfloat16 h = __float2bfloat16(x);
            Wt_hi[(size_t)n * K + k0 + tx] = h;
            Wt_lo[(size_t)n * K + k0 + tx] = __float2bfloat16(x - __bfloat162float(h));
        }
    }
}

// ------------------------------------------------------------------- GEMM
// A: MxK bf16 row-major; Bt: NxK bf16 row-major (B transposed); C: MxN.
// 2-phase double-buffered + XCD swizzle. 128x128 tile.
template <bool OUT_BF16>
__global__ __launch_bounds__(256) void gemm_bt(
    const __hip_bfloat16* __restrict__ A, const __hip_bfloat16* __restrict__ Bt,
    void* __restrict__ Cout, int M, int N, int K) {
    __shared__ short sA[2][128 * 32];
    __shared__ short sB[2][128 * 32];
    const int tid = threadIdx.x;
    const int w = tid >> 6, lane = tid & 63;
    int bx, by;
    xcd_swizzle(bx, by);
    const int bn0 = bx * 128, bm0 = by * 128;
    const int wr = w >> 1, wc = w & 1;

    fx4 acc[4][4];
#pragma unroll
    for (int m = 0; m < 4; ++m)
#pragma unroll
        for (int n = 0; n < 4; ++n) acc[m][n] = {0.f, 0.f, 0.f, 0.f};

#pragma unroll
    for (int i = 0; i < 2; ++i) {
        int c = i * 256 + tid;
        int r = c >> 2, kk = (c & 3) * 8;
        ASYNC_LDS16(&sA[0][c * 8], A + (size_t)(bm0 + r) * K + kk);
        ASYNC_LDS16(&sB[0][c * 8], Bt + (size_t)(bn0 + r) * K + kk);
    }
    __syncthreads();

    const int NT = K >> 5;
    int cur = 0;
    for (int t = 0; t < NT; ++t) {
        if (t + 1 < NT) {
            int k0 = (t + 1) << 5;
#pragma unroll
            for (int i = 0; i < 2; ++i) {
                int c = i * 256 + tid;
                int r = c >> 2, kk = (c & 3) * 8;
                ASYNC_LDS16(&sA[cur ^ 1][c * 8], A + (size_t)(bm0 + r) * K + k0 + kk);
                ASYNC_LDS16(&sB[cur ^ 1][c * 8], Bt + (size_t)(bn0 + r) * K + k0 + kk);
            }
        }
        bf16x8 af[4], bfv[4];
#pragma unroll
        for (int m = 0; m < 4; ++m)
            af[m] = *(const bf16x8*)(&sA[cur][(wr * 64 + m * 16 + (lane & 15)) * 32 + (lane >> 4) * 8]);
#pragma unroll
        for (int n = 0; n < 4; ++n)
            bfv[n] = *(const bf16x8*)(&sB[cur][(wc * 64 + n * 16 + (lane & 15)) * 32 + (lane >> 4) * 8]);
#pragma unroll
        for (int m = 0; m < 4; ++m)
#pragma unroll
            for (int n = 0; n < 4; ++n)
                acc[m][n] = __builtin_amdgcn_mfma_f32_16x16x32_bf16(af[m], bfv[n], acc[m][n], 0, 0, 0);
        __syncthreads();
        cur ^= 1;
    }
#pragma unroll
    for (int m = 0; m < 4; ++m) {
        int row = bm0 + wr * 64 + m * 16 + (lane >> 4) * 4;
#pragma unroll
        for (int n = 0; n < 4; ++n) {
            int col = bn0 + wc * 64 + n * 16 + (lane & 15);
#pragma unroll
            for (int j = 0; j < 4; ++j) {
                float val = acc[m][n][j];
                if (OUT_BF16)
                    ((__hip_bfloat16*)Cout)[(size_t)(row + j) * N + col] = __float2bfloat16(val);
                else
                    ((float*)Cout)[(size_t)(row + j) * N + col] = val;
            }
        }
    }
}

// ----------------------------------------- GEMM, 128x64 tile (small-N shapes)
// Full-chip grid for N=1024 GEMMs (o-proj, down-proj): 24KB LDS dbuf, 6 blk/CU.
// Per-element accumulation order identical to the 128x128 variant.
template <bool OUT_BF16>
__global__ __launch_bounds__(256) void gemm_bt_n64(
    const __hip_bfloat16* __restrict__ A, const __hip_bfloat16* __restrict__ Bt,
    void* __restrict__ Cout, int M, int N, int K) {
    __shared__ short sA[2][128 * 32];
    __shared__ short sB[2][64 * 32];
    const int tid = threadIdx.x;
    const int w = tid >> 6, lane = tid & 63;
    int bx, by;
    xcd_swizzle(bx, by);
    const int bn0 = bx * 64, bm0 = by * 128;

    fx4 acc[2][4];
#pragma unroll
    for (int m = 0; m < 2; ++m)
#pragma unroll
        for (int n = 0; n < 4; ++n) acc[m][n] = {0.f, 0.f, 0.f, 0.f};

#pragma unroll
    for (int i = 0; i < 2; ++i) {
        int c = i * 256 + tid;
        int r = c >> 2, kk = (c & 3) * 8;
        ASYNC_LDS16(&sA[0][c * 8], A + (size_t)(bm0 + r) * K + kk);
    }
    {
        int r = tid >> 2, kk = (tid & 3) * 8;
        ASYNC_LDS16(&sB[0][tid * 8], Bt + (size_t)(bn0 + r) * K + kk);
    }
    __syncthreads();

    const int NT = K >> 5;
    int cur = 0;
    for (int t = 0; t < NT; ++t) {
        if (t + 1 < NT) {
            int k0 = (t + 1) << 5;
#pragma unroll
            for (int i = 0; i < 2; ++i) {
                int c = i * 256 + tid;
                int r = c >> 2, kk = (c & 3) * 8;
                ASYNC_LDS16(&sA[cur ^ 1][c * 8], A + (size_t)(bm0 + r) * K + k0 + kk);
            }
            int r = tid >> 2, kk = (tid & 3) * 8;
            ASYNC_LDS16(&sB[cur ^ 1][tid * 8], Bt + (size_t)(bn0 + r) * K + k0 + kk);
        }
        bf16x8 af[2], bfv[4];
#pragma unroll
        for (int m = 0; m < 2; ++m)
            af[m] = *(const bf16x8*)(&sA[cur][(w * 32 + m * 16 + (lane & 15)) * 32 + (lane >> 4) * 8]);
#pragma unroll
        for (int n = 0; n < 4; ++n)
            bfv[n] = *(const bf16x8*)(&sB[cur][(n * 16 + (lane & 15)) * 32 + (lane >> 4) * 8]);
#pragma unroll
        for (int m = 0; m < 2; ++m)
#pragma unroll
            for (int n = 0; n < 4; ++n)
                acc[m][n] = __builtin_amdgcn_mfma_f32_16x16x32_bf16(af[m], bfv[n], acc[m][n], 0, 0, 0);
        __syncthreads();
        cur ^= 1;
    }
#pragma unroll
    for (int m = 0; m < 2; ++m) {
        int row = bm0 + w * 32 + m * 16 + (lane >> 4) * 4;
#pragma unroll
        for (int n = 0; n < 4; ++n) {
            int col = bn0 + n * 16 + (lane & 15);
#pragma unroll
            for (int j = 0; j < 4; ++j) {
                float val = acc[m][n][j];
                if (OUT_BF16)
                    ((__hip_bfloat16*)Cout)[(size_t)(row + j) * N + col] = __float2bfloat16(val);
                else
                    ((float*)Cout)[(size_t)(row + j) * N + col] = val;
            }
        }
    }
}

// ------------------------------------- split-precision GEMM (3 bf16 products)
// 2-phase prefetch + XCD swizzle; 4 operand streams double-buffered (64KB).
__global__ __launch_bounds__(256) void gemm_bt_split(
    const __hip_bfloat16* __restrict__ Ah, const __hip_bfloat16* __restrict__ Al,
    const __hip_bfloat16* __restrict__ Bth, const __hip_bfloat16* __restrict__ Btl,
    float* __restrict__ Cout, int M, int N, int K) {
    __shared__ short sAh[2][128 * 32];
    __shared__ short sAl[2][128 * 32];
    __shared__ short sBh[2][128 * 32];
    __shared__ short sBl[2][128 * 32];
    const int tid = threadIdx.x;
    const int w = tid >> 6, lane = tid & 63;
    int bx, by;
    xcd_swizzle(bx, by);
    const int bn0 = bx * 128, bm0 = by * 128;
    const int wr = w >> 1, wc = w & 1;

    fx4 acc[4][4];
#pragma unroll
    for (int m = 0; m < 4; ++m)
#pragma unroll
        for (int n = 0; n < 4; ++n) acc[m][n] = {0.f, 0.f, 0.f, 0.f};

#pragma unroll
    for (int i = 0; i < 2; ++i) {
        int c = i * 256 + tid;
        int r = c >> 2, kk = (c & 3) * 8;
        size_t ga = (size_t)(bm0 + r) * K + kk;
        size_t gb = (size_t)(bn0 + r) * K + kk;
        ASYNC_LDS16(&sAh[0][c * 8], Ah + ga);
        ASYNC_LDS16(&sAl[0][c * 8], Al + ga);
        ASYNC_LDS16(&sBh[0][c * 8], Bth + gb);
        ASYNC_LDS16(&sBl[0][c * 8], Btl + gb);
    }
    __syncthreads();

    const int NT = K >> 5;
    int cur = 0;
    for (int t = 0; t < NT; ++t) {
        if (t + 1 < NT) {
            int k0 = (t + 1) << 5;
#pragma unroll
            for (int i = 0; i < 2; ++i) {
                int c = i * 256 + tid;
                int r = c >> 2, kk = (c & 3) * 8;
                size_t ga = (size_t)(bm0 + r) * K + k0 + kk;
                size_t gb = (size_t)(bn0 + r) * K + k0 + kk;
                ASYNC_LDS16(&sAh[cur ^ 1][c * 8], Ah + ga);
                ASYNC_LDS16(&sAl[cur ^ 1][c * 8], Al + ga);
                ASYNC_LDS16(&sBh[cur ^ 1][c * 8], Bth + gb);
                ASYNC_LDS16(&sBl[cur ^ 1][c * 8], Btl + gb);
            }
        }
        bf16x8 ah[4], al[4], bh[4], bl[4];
#pragma unroll
        for (int m = 0; m < 4; ++m) {
            int off = (wr * 64 + m * 16 + (lane & 15)) * 32 + (lane >> 4) * 8;
            ah[m] = *(const bf16x8*)(&sAh[cur][off]);
            al[m] = *(const bf16x8*)(&sAl[cur][off]);
        }
#pragma unroll
        for (int n = 0; n < 4; ++n) {
            int off = (wc * 64 + n * 16 + (lane & 15)) * 32 + (lane >> 4) * 8;
            bh[n] = *(const bf16x8*)(&sBh[cur][off]);
            bl[n] = *(const bf16x8*)(&sBl[cur][off]);
        }
#pragma unroll
        for (int m = 0; m < 4; ++m)
#pragma unroll
            for (int n = 0; n < 4; ++n) {
                acc[m][n] = __builtin_amdgcn_mfma_f32_16x16x32_bf16(ah[m], bh[n], acc[m][n], 0, 0, 0);
                acc[m][n] = __builtin_amdgcn_mfma_f32_16x16x32_bf16(ah[m], bl[n], acc[m][n], 0, 0, 0);
                acc[m][n] = __builtin_amdgcn_mfma_f32_16x16x32_bf16(al[m], bh[n], acc[m][n], 0, 0, 0);
            }
        __syncthreads();
        cur ^= 1;
    }
#pragma unroll
    for (int m = 0; m < 4; ++m) {
        int row = bm0 + wr * 64 + m * 16 + (lane >> 4) * 4;
#pragma unroll
        for (int n = 0; n < 4; ++n) {
            int col = bn0 + wc * 64 + n * 16 + (lane & 15);
#pragma unroll
            for (int j = 0; j < 4; ++j)
                Cout[(size_t)(row + j) * N + col] = acc[m][n][j];
        }
    }
}

// --------------------------------------------- RoPE + L2-normalize q,k in place
__global__ __launch_bounds__(256) void rope_kernel(float* __restrict__ X1,
                                                   const float2* __restrict__ cs) {
    int w = threadIdx.x >> 6, lane = threadIdx.x & 63;
    int p = blockIdx.x * 4 + w;            // (t,h) pair, 32768 total
    int t = p >> 4, h = p & 15;
    float2 c = cs[t * 32 + (lane & 31)];
#pragma unroll
    for (int which = 0; which < 2; ++which) {
        float* base = X1 + (size_t)t * NQKV + which * 1024 + h * 64;
        float x = base[lane];
        float xo = __shfl(x, lane ^ 32, 64);
        float r = (lane < 32) ? -xo : xo;
        float y = x * c.x + r * c.y;
        float ss = y * y;
#pragma unroll
        for (int m = 32; m; m >>= 1) ss += __shfl_xor(ss, m, 64);
        base[lane] = y * rsqrtf(ss + 1e-12f);
    }
}

// ===================== chunked delta-rule: shared helpers =====================
__device__ __forceinline__ void mm64_3p(const short* Ah, const short* Al,
                                        const short* Bh, const short* Bl,
                                        int w, int lane, fx4 acc[4]) {
#pragma unroll
    for (int k0 = 0; k0 < 64; k0 += 32) {
        int ao = (w * 16 + (lane & 15)) * LP + k0 + ((lane >> 4) * 8);
        bf16x8 ah = *(const bf16x8*)(Ah + ao);
        bf16x8 al = *(const bf16x8*)(Al + ao);
#pragma unroll
        for (int n = 0; n < 4; ++n) {
            int bo = (n * 16 + (lane & 15)) * LP + k0 + ((lane >> 4) * 8);
            bf16x8 bh = *(const bf16x8*)(Bh + bo);
            bf16x8 bl = *(const bf16x8*)(Bl + bo);
            acc[n] = __builtin_amdgcn_mfma_f32_16x16x32_bf16(ah, bh, acc[n], 0, 0, 0);
            acc[n] = __builtin_amdgcn_mfma_f32_16x16x32_bf16(ah, bl, acc[n], 0, 0, 0);
            acc[n] = __builtin_amdgcn_mfma_f32_16x16x32_bf16(al, bh, acc[n], 0, 0, 0);
        }
    }
}

__device__ __forceinline__ void split_write(short* h, short* l, int off, float x) {
    __hip_bfloat16 hb = __float2bfloat16(x);
    ((__hip_bfloat16*)h)[off] = hb;
    ((__hip_bfloat16*)l)[off] = __float2bfloat16(x - __bfloat162float(hb));
}

// ------------------------------------------------ phase A1 (blocked solve)
__global__ __launch_bounds__(256) void phaseA1_kernel(const float* __restrict__ X1,
                                                      __hip_bfloat16* __restrict__ UvWT_hi,
                                                      __hip_bfloat16* __restrict__ UvWT_lo) {
    const int h = blockIdx.x & 15, c = blockIdx.x >> 4;
    const int tid = threadIdx.x, w = tid >> 6, lane = tid & 63;
    const int t0 = c * 64;

    __shared__ short b1h[64 * LP], b1l[64 * LP];     // K hi/lo
    __shared__ float sMT[64 * MP];                   // [s*MP+t] (s<t) = M[t][s]
    __shared__ short xth[128 * LP], xtl[128 * LP];   // XT[j][t] hi/lo (corr -> X)
    __shared__ short mbh[3][512], mbl[3][512];       // M_IJ blocks [tl][k(32)], k>=16 zero
    __shared__ float sLa[64], sB[64], sL[65], sGp[64];

    const float* k_g = X1 + (size_t)t0 * NQKV + 1024 + h * 64;
    const float* v_g = X1 + (size_t)t0 * NQKV + 2048 + h * 64;

    if (tid < 64) {
        float ga = X1[(size_t)(t0 + tid) * NQKV + 4096 + h];
        float gb = X1[(size_t)(t0 + tid) * NQKV + 4112 + h];
        float z = -ga;
        sLa[tid] = -(fmaxf(z, 0.f) + log1pf(expf(-fabsf(z))));
        sB[tid] = 1.f / (1.f + expf(-gb));
    }
    __syncthreads();
    if (tid < 64) {
        float v = sLa[tid];
#pragma unroll
        for (int off = 1; off < 64; off <<= 1) {
            float u = __shfl_up(v, off, 64);
            if (tid >= off) v += u;
        }
        sL[tid + 1] = v;
        if (tid == 0) sL[0] = 0.f;
    }
    __syncthreads();
    if (tid < 64) sGp[tid] = expf(sL[tid]);
    for (int idx = tid; idx < 1536; idx += 256) {
        ((short*)mbh)[idx] = 0;
        ((short*)mbl)[idx] = 0;
    }
    // zero-init XT (corr MFMA B-reads span the next panel; LDS garbage can be
    // NaN-pattern bf16 and 0*NaN=NaN in the MFMA accumulator).
    for (int idx = tid; idx < 128 * LP; idx += 256) {
        xth[idx] = 0;
        xtl[idx] = 0;
    }
    for (int idx = tid; idx < 4096; idx += 256) {
        int r = idx >> 6, cc = idx & 63;
        float kv = k_g[(size_t)r * NQKV + cc];
        __hip_bfloat16 hb = __float2bfloat16(kv);
        ((__hip_bfloat16*)b1h)[r * LP + cc] = hb;
        ((__hip_bfloat16*)b1l)[r * LP + cc] = __float2bfloat16(kv - __bfloat162float(hb));
    }
    __syncthreads();

    // G = K K^T, one 16-row strip per wave; scatter sMT[s][t] = M[t][s]
    {
        const int r0 = w * 16;
        fx4 acc[4];
#pragma unroll
        for (int n = 0; n < 4; ++n) acc[n] = {0.f, 0.f, 0.f, 0.f};
#pragma unroll
        for (int k0 = 0; k0 < 64; k0 += 32) {
            int ao = (r0 + (lane & 15)) * LP + k0 + ((lane >> 4) * 8);
            bf16x8 ah = *(const bf16x8*)(b1h + ao);
            bf16x8 al = *(const bf16x8*)(b1l + ao);
#pragma unroll
            for (int n = 0; n < 4; ++n) {
                int bo = (n * 16 + (lane & 15)) * LP + k0 + ((lane >> 4) * 8);
                bf16x8 bh = *(const bf16x8*)(b1h + bo);
                bf16x8 bl = *(const bf16x8*)(b1l + bo);
                acc[n] = __builtin_amdgcn_mfma_f32_16x16x32_bf16(ah, bh, acc[n], 0, 0, 0);
                acc[n] = __builtin_amdgcn_mfma_f32_16x16x32_bf16(ah, bl, acc[n], 0, 0, 0);
                acc[n] = __builtin_amdgcn_mfma_f32_16x16x32_bf16(al, bh, acc[n], 0, 0, 0);
            }
        }
#pragma unroll
        for (int n = 0; n < 4; ++n)
#pragma unroll
            for (int jj = 0; jj < 4; ++jj) {
                int t = r0 + (lane >> 4) * 4 + jj, s = n * 16 + (lane & 15);
                if (s < t) sMT[s * MP + t] = sB[t] * expf(sL[t] - sL[s + 1]) * acc[n][jj];
            }
    }
    __syncthreads();

    // blocked forward substitution over 4 panels of 16
#pragma unroll
    for (int I = 0; I < 4; ++I) {
        for (int idx = tid; idx < I * 256; idx += 256) {
            int J = idx >> 8, e = idx & 255;
            int tl = e >> 4, sl = e & 15;
            float mv = sMT[(J * 16 + sl) * MP + (I * 16 + tl)];
            __hip_bfloat16 hb = __float2bfloat16(mv);
            ((__hip_bfloat16*)&mbh[J][0])[tl * 32 + sl] = hb;
            ((__hip_bfloat16*)&mbl[J][0])[tl * 32 + sl] = __float2bfloat16(mv - __bfloat162float(hb));
        }
        __syncthreads();
        if (I > 0) {
            fx4 acc2[2];
            acc2[0] = {0.f, 0.f, 0.f, 0.f};
            acc2[1] = {0.f, 0.f, 0.f, 0.f};
#pragma unroll
            for (int g = 0; g < 2; ++g) {
                const int jb = (w * 2 + g) * 16;
                for (int J = 0; J < I; ++J) {
                    bf16x8 ah = *(const bf16x8*)((const short*)&mbh[J][0] + (lane & 15) * 32 + (lane >> 4) * 8);
                    bf16x8 al = *(const bf16x8*)((const short*)&mbl[J][0] + (lane & 15) * 32 + (lane >> 4) * 8);
                    int bo = (jb + (lane & 15)) * LP + J * 16 + ((lane >> 4) * 8);
                    bf16x8 bh = *(const bf16x8*)(xth + bo);
                    bf16x8 bl = *(const bf16x8*)(xtl + bo);
                    acc2[g] = __builtin_amdgcn_mfma_f32_16x16x32_bf16(ah, bh, acc2[g], 0, 0, 0);
                    acc2[g] = __builtin_amdgcn_mfma_f32_16x16x32_bf16(ah, bl, acc2[g], 0, 0, 0);
                    acc2[g] = __builtin_amdgcn_mfma_f32_16x16x32_bf16(al, bh, acc2[g], 0, 0, 0);
                }
            }
#pragma unroll
            for (int g = 0; g < 2; ++g) {
                const int jb = (w * 2 + g) * 16;
#pragma unroll
                for (int jj = 0; jj < 4; ++jj) {
                    int j = jb + (lane & 15);
                    int t = I * 16 + (lane >> 4) * 4 + jj;
                    split_write(xth, xtl, j * LP + t, acc2[g][jj]);
                }
            }
        }
        __syncthreads();
        if (tid < 128) {
            const int j = tid;
            float xs[16];
#pragma unroll
            for (int tl = 0; tl < 16; ++tl) {
                const int t = I * 16 + tl;
                float base;
                if (j < 64) {
                    base = v_g[(size_t)t * NQKV + j];
                } else {
                    int i = j - 64;
                    base = (__bfloat162float(((__hip_bfloat16*)b1h)[t * LP + i]) +
                            __bfloat162float(((__hip_bfloat16*)b1l)[t * LP + i])) * sGp[t];
                }
                float r = sB[t] * base;
                if (I > 0) {
                    r -= __bfloat162float(((__hip_bfloat16*)xth)[j * LP + t]) +
                         __bfloat162float(((__hip_bfloat16*)xtl)[j * LP + t]);
                }
#pragma unroll
                for (int sl = 0; sl < tl; ++sl)
                    r = fmaf(-sMT[(I * 16 + sl) * MP + t], xs[sl], r);
                xs[tl] = r;
                __hip_bfloat16 hb = __float2bfloat16(r);
                ((__hip_bfloat16*)xth)[j * LP + t] = hb;
                ((__hip_bfloat16*)xtl)[j * LP + t] = __float2bfloat16(r - __bfloat162float(hb));
            }
        }
        __syncthreads();
    }

    // write out t-major (coalesced): UvWT[hc][t][j] = XT[j][t]
    size_t obase = (size_t)(h * 32 + c) * 8192;
    for (int idx = tid; idx < 8192; idx += 256) {
        int t = idx >> 7, j = idx & 127;
        UvWT_hi[obase + idx] = ((__hip_bfloat16*)xth)[j * LP + t];
        UvWT_lo[obase + idx] = ((__hip_bfloat16*)xtl)[j * LP + t];
    }
}

// ------------------------------------------------ phase A2 (matmuls, parallel)
__global__ __launch_bounds__(256) void phaseA2_kernel(float* __restrict__ X1,
                                                      const __hip_bfloat16* __restrict__ UvWT_hi,
                                                      const __hip_bfloat16* __restrict__ UvWT_lo,
                                                      short* __restrict__ AcBuf,
                                                      float* __restrict__ BcBuf) {
    const int h = blockIdx.x & 15, c = blockIdx.x >> 4;
    const int tid = threadIdx.x, w = tid >> 6, lane = tid & 63;
    const int t0 = c * 64;

    __shared__ short b1h[64 * LP], b1l[64 * LP];   // K
    __shared__ short b2h[64 * LP], b2l[64 * LP];   // Q -> Ptilde -> KhatT
    __shared__ short b3h[64 * LP], b3l[64 * LP];   // UvT
    __shared__ short b4h[64 * LP], b4l[64 * LP];   // WT
    __shared__ float sLa[64], sL[65], sGp[64], sRc[64];

    const float* q_g = X1 + (size_t)t0 * NQKV + h * 64;
    const float* k_g = q_g + 1024;

    if (tid < 64) {
        float ga = X1[(size_t)(t0 + tid) * NQKV + 4096 + h];
        float z = -ga;
        sLa[tid] = -(fmaxf(z, 0.f) + log1pf(expf(-fabsf(z))));
    }
    __syncthreads();
    if (tid < 64) {
        float v = sLa[tid];
#pragma unroll
        for (int off = 1; off < 64; off <<= 1) {
            float u = __shfl_up(v, off, 64);
            if (tid >= off) v += u;
        }
        sL[tid + 1] = v;
        if (tid == 0) sL[0] = 0.f;
    }
    __syncthreads();
    if (tid < 64) {
        sGp[tid] = expf(sL[tid]);
        sRc[tid] = expf(sL[64] - sL[tid + 1]);
    }
    for (int idx = tid; idx < 4096; idx += 256) {
        int r = idx >> 6, cc = idx & 63;
        split_write(b2h, b2l, r * LP + cc, q_g[(size_t)r * NQKV + cc]);
        split_write(b1h, b1l, r * LP + cc, k_g[(size_t)r * NQKV + cc]);
    }
    const __hip_bfloat16* uh = UvWT_hi + (size_t)(h * 32 + c) * 8192;
    const __hip_bfloat16* ul = UvWT_lo + (size_t)(h * 32 + c) * 8192;
    for (int idx = tid; idx < 8192; idx += 256) {
        int t = idx >> 7, row = idx & 127;
        short* dh = (row < 64) ? b3h : b4h;
        short* dl = (row < 64) ? b3l : b4l;
        ((__hip_bfloat16*)dh)[(row & 63) * LP + t] = uh[idx];
        ((__hip_bfloat16*)dl)[(row & 63) * LP + t] = ul[idx];
    }
    __syncthreads();

    // P = Q K^T
    fx4 pacc[4];
#pragma unroll
    for (int n = 0; n < 4; ++n) pacc[n] = {0.f, 0.f, 0.f, 0.f};
    mm64_3p(b2h, b2l, b1h, b1l, w, lane, pacc);
    __syncthreads();
#pragma unroll
    for (int n = 0; n < 4; ++n)
#pragma unroll
        for (int jj = 0; jj < 4; ++jj) {
            int t = w * 16 + (lane >> 4) * 4 + jj, s = n * 16 + (lane & 15);
            float pv = (s < t) ? expf(sL[t] - sL[s + 1]) * pacc[n][jj] : 0.f;
            split_write(b2h, b2l, t * LP + s, pv);
        }
    __syncthreads();

    // Olocal = Ptilde @ Uv -> overwrite k-region (f32)
    {
        fx4 acc[4];
#pragma unroll
        for (int n = 0; n < 4; ++n) acc[n] = {0.f, 0.f, 0.f, 0.f};
        mm64_3p(b2h, b2l, b3h, b3l, w, lane, acc);
        float* og = X1 + (size_t)t0 * NQKV + 1024 + h * 64;
#pragma unroll
        for (int n = 0; n < 4; ++n)
#pragma unroll
            for (int jj = 0; jj < 4; ++jj) {
                int t = w * 16 + (lane >> 4) * 4 + jj, s = n * 16 + (lane & 15);
                og[(size_t)t * NQKV + s] = acc[n][jj];
            }
    }
    // PW = Ptilde @ W ; Qeff = diag(gprev)Q - PW -> overwrite q-region (f32)
    {
        fx4 acc[4];
#pragma unroll
        for (int n = 0; n < 4; ++n) acc[n] = {0.f, 0.f, 0.f, 0.f};
        mm64_3p(b2h, b2l, b4h, b4l, w, lane, acc);
        float* qg = X1 + (size_t)t0 * NQKV + h * 64;
#pragma unroll
        for (int n = 0; n < 4; ++n)
#pragma unroll
            for (int jj = 0; jj < 4; ++jj) {
                int t = w * 16 + (lane >> 4) * 4 + jj, s = n * 16 + (lane & 15);
                float qv = qg[(size_t)t * NQKV + s];
                qg[(size_t)t * NQKV + s] = sGp[t] * qv - acc[n][jj];
            }
    }
    __syncthreads();
    // KhatT -> b2: [i][s] = rC[s] * K[s][i]
    for (int idx = tid; idx < 4096; idx += 256) {
        int s = idx >> 6, i = idx & 63;
        float kv = __bfloat162float(((__hip_bfloat16*)b1h)[s * LP + i]) +
                   __bfloat162float(((__hip_bfloat16*)b1l)[s * LP + i]);
        split_write(b2h, b2l, i * LP + s, sRc[s] * kv);
    }
    __syncthreads();

    // Ac = gammaEnd*I - KhatT @ W -> AcBuf (bf16 hi/lo, row-major [i][j])
    {
        fx4 acc[4];
#pragma unroll
        for (int n = 0; n < 4; ++n) acc[n] = {0.f, 0.f, 0.f, 0.f};
        mm64_3p(b2h, b2l, b4h, b4l, w, lane, acc);
        float gend = expf(sL[64]);
        size_t abase = (size_t)(h * 32 + c) * 8192;
#pragma unroll
        for (int n = 0; n < 4; ++n)
#pragma unroll
            for (int jj = 0; jj < 4; ++jj) {
                int i = w * 16 + (lane >> 4) * 4 + jj, jd = n * 16 + (lane & 15);
                float av = ((i == jd) ? gend : 0.f) - acc[n][jj];
                __hip_bfloat16 hb = __float2bfloat16(av);
                ((__hip_bfloat16*)AcBuf)[abase + i * 64 + jd] = hb;
                ((__hip_bfloat16*)AcBuf)[abase + 4096 + i * 64 + jd] =
                    __float2bfloat16(av - __bfloat162float(hb));
            }
    }
    // BcT = UvT @ KhatT' -> BcBuf (f32, [v][i])
    {
        fx4 acc[4];
#pragma unroll
        for (int n = 0; n < 4; ++n) acc[n] = {0.f, 0.f, 0.f, 0.f};
        mm64_3p(b3h, b3l, b2h, b2l, w, lane, acc);
        size_t bbase = (size_t)(h * 32 + c) * 4096;
#pragma unroll
        for (int n = 0; n < 4; ++n)
#pragma unroll
            for (int jj = 0; jj < 4; ++jj) {
                int jv = w * 16 + (lane >> 4) * 4 + jj, i = n * 16 + (lane & 15);
                BcBuf[bbase + jv * 64 + i] = acc[n][jj];
            }
    }
}

// --------------------------------------------------- phase B (state recurrence)
__global__ __launch_bounds__(256) void phaseB_kernel(const short* __restrict__ AcBuf,
                                                     const float* __restrict__ BcBuf,
                                                     float* __restrict__ X1) {
    const int h = blockIdx.x;
    const int tid = threadIdx.x, w = tid >> 6, lane = tid & 63;
    const int lr = (lane >> 4) * 4;                // C-layout row offset
    const int lc = lane & 15;                      // C-layout col offset
    __shared__ short sAc[2][8192];                 // [hi 4096 | lo 4096] shorts, row stride 64
    __shared__ float sST[64 * 68];                 // S^T staging (intra-wave)

    const size_t hc0 = (size_t)h * 32;
    {
        const char* src = (const char*)AcBuf + hc0 * 16384;
        char* dst = (char*)&sAc[0][0];
        int off = w * 4096 + lane * 16;
#pragma unroll
        for (int q = 0; q < 4; ++q) { ASYNC_LDS16(dst + off, src + off); off += 1024; }
    }
    fx4 acc[4];
#pragma unroll
    for (int n = 0; n < 4; ++n) acc[n] = {0.f, 0.f, 0.f, 0.f};
    float bcur[16];
    {
        const float* bg = BcBuf + hc0 * 4096;
#pragma unroll
        for (int n = 0; n < 4; ++n)
#pragma unroll
            for (int jj = 0; jj < 4; ++jj)
                bcur[n * 4 + jj] = bg[(w * 16 + lr + jj) * 64 + n * 16 + lc];
    }

#pragma unroll 1
    for (int c = 0; c < 32; ++c) {
        __syncthreads();
        {
            int cn = (c < 31) ? c + 1 : 31;
            const char* src = (const char*)AcBuf + (hc0 + cn) * 16384;
            char* dst = (char*)&sAc[(c + 1) & 1][0];
            int off = w * 4096 + lane * 16;
#pragma unroll
            for (int q = 0; q < 4; ++q) { ASYNC_LDS16(dst + off, src + off); off += 1024; }
        }
        float bnext[16];
        {
            int cn = (c < 31) ? c + 1 : 31;
            const float* bg = BcBuf + (hc0 + cn) * 4096;
#pragma unroll
            for (int n = 0; n < 4; ++n)
#pragma unroll
                for (int jj = 0; jj < 4; ++jj)
                    bnext[n * 4 + jj] = bg[(w * 16 + lr + jj) * 64 + n * 16 + lc];
        }
        float* stg = X1 + (size_t)(c * 64) * NQKV + 2048 + h * 64;
#pragma unroll
        for (int n = 0; n < 4; ++n)
#pragma unroll
            for (int jj = 0; jj < 4; ++jj) {
                int r = w * 16 + lr + jj, i = n * 16 + lc;
                stg[(size_t)r * NQKV + i] = acc[n][jj];
                sST[r * 68 + i] = acc[n][jj];
            }
        const short* bufc = &sAc[c & 1][0];
        fx4 nacc[4];
#pragma unroll
        for (int n = 0; n < 4; ++n)
            nacc[n] = {bcur[n * 4 + 0], bcur[n * 4 + 1], bcur[n * 4 + 2], bcur[n * 4 + 3]};
#pragma unroll
        for (int k0 = 0; k0 < 2; ++k0) {
            const float* ap = sST + (w * 16 + lc) * 68 + k0 * 32 + (lane >> 4) * 8;
            float4 f0 = *(const float4*)ap;
            float4 f1 = *(const float4*)(ap + 4);
            float fv[8] = {f0.x, f0.y, f0.z, f0.w, f1.x, f1.y, f1.z, f1.w};
            bf16x8 afh, afl;
#pragma unroll
            for (int e = 0; e < 8; ++e) {
                __hip_bfloat16 hb = __float2bfloat16(fv[e]);
                __hip_bfloat16 lb = __float2bfloat16(fv[e] - __bfloat162float(hb));
                afh[e] = *(__bf16*)&hb;
                afl[e] = *(__bf16*)&lb;
            }
#pragma unroll
            for (int n = 0; n < 4; ++n) {
                int ro = (n * 16 + lc) * 64 + k0 * 32 + (lane >> 4) * 8;   // shorts
                bf16x8 bh = *(const bf16x8*)(bufc + ro);
                bf16x8 bl = *(const bf16x8*)(bufc + 4096 + ro);
                nacc[n] = __builtin_amdgcn_mfma_f32_16x16x32_bf16(afh, bh, nacc[n], 0, 0, 0);
                nacc[n] = __builtin_amdgcn_mfma_f32_16x16x32_bf16(afh, bl, nacc[n], 0, 0, 0);
                nacc[n] = __builtin_amdgcn_mfma_f32_16x16x32_bf16(afl, bh, nacc[n], 0, 0, 0);
            }
        }
#pragma unroll
        for (int n = 0; n < 4; ++n) acc[n] = nacc[n];
#pragma unroll
        for (int e = 0; e < 16; ++e) bcur[e] = bnext[e];
    }
}

// --------------------------------------------- phase C (outputs + epilogue)
__global__ __launch_bounds__(256) void phaseC_kernel(const float* __restrict__ X1,
                                                     const float* __restrict__ onw,
                                                     __hip_bfloat16* __restrict__ attn_bf) {
    const int h = blockIdx.x & 15, c = blockIdx.x >> 4;
    const int tid = threadIdx.x, w = tid >> 6, lane = tid & 63;
    const int t0 = c * 64;
    __shared__ short qh[64 * LP], ql[64 * LP];
    __shared__ short sh_[64 * LP], sl_[64 * LP];
    __shared__ float sO[4096];
    __shared__ float part[64][4];
    const float* qe = X1 + (size_t)t0 * NQKV + h * 64;          // Qeff
    const float* stg = X1 + (size_t)t0 * NQKV + 2048 + h * 64;  // S^T (entering c)
    const float* ol = X1 + (size_t)t0 * NQKV + 1024 + h * 64;   // Olocal
    for (int idx = tid; idx < 4096; idx += 256) {
        int r = idx >> 6, i = idx & 63;
        split_write(qh, ql, r * LP + i, qe[(size_t)r * NQKV + i]);
        split_write(sh_, sl_, r * LP + i, stg[(size_t)r * NQKV + i]);
    }
    __syncthreads();
    fx4 acc[4];
#pragma unroll
    for (int n = 0; n < 4; ++n)
#pragma unroll
        for (int jj = 0; jj < 4; ++jj)
            acc[n][jj] = ol[(size_t)(w * 16 + (lane >> 4) * 4 + jj) * NQKV + n * 16 + (lane & 15)];
    mm64_3p(qh, ql, sh_, sl_, w, lane, acc);
#pragma unroll
    for (int n = 0; n < 4; ++n)
#pragma unroll
        for (int jj = 0; jj < 4; ++jj)
            sO[(w * 16 + (lane >> 4) * 4 + jj) * 64 + n * 16 + (lane & 15)] = acc[n][jj];
    __syncthreads();
    int r = tid >> 2, qq = tid & 3;
    float ss = 0.f;
#pragma unroll
    for (int i2 = 0; i2 < 16; ++i2) { float v = sO[r * 64 + qq * 16 + i2]; ss += v * v; }
    part[r][qq] = ss;
    __syncthreads();
    float tot = part[r][0] + part[r][1] + part[r][2] + part[r][3];
    float sc = rsqrtf(tot * (1.f / 64.f) + 1e-6f);
    const float* gg = X1 + (size_t)(t0 + r) * NQKV + 3072 + h * 64;
#pragma unroll
    for (int i2 = 0; i2 < 16; ++i2) {
        int j = qq * 16 + i2;
        float on = sO[r * 64 + j] * sc * onw[j];
        float g = gg[j];
        float sg = g / (1.f + expf(-g));
        attn_bf[(size_t)(t0 + r) * 1024 + h * 64 + j] = __float2bfloat16(on * sg);
    }
}

// ---------------------------- h = hidden + attn (in place); ybf = rmsnorm(h)
__global__ __launch_bounds__(256) void add_rmsnorm_kernel(
    const float* __restrict__ hidden, float* __restrict__ acc,
    const float* __restrict__ w, __hip_bfloat16* __restrict__ out) {
    int t = blockIdx.x;
    int d = threadIdx.x * 4;
    float4 a = *(const float4*)(acc + (size_t)t * D_MODEL + d);
    float4 hd = *(const float4*)(hidden + (size_t)t * D_MODEL + d);
    float4 h4 = make_float4(a.x + hd.x, a.y + hd.y, a.z + hd.z, a.w + hd.w);
    *(float4*)(acc + (size_t)t * D_MODEL + d) = h4;
    float ss = h4.x * h4.x + h4.y * h4.y + h4.z * h4.z + h4.w * h4.w;
#pragma unroll
    for (int m = 32; m; m >>= 1) ss += __shfl_xor(ss, m, 64);
    __shared__ float wsum[4];
    if ((threadIdx.x & 63) == 0) wsum[threadIdx.x >> 6] = ss;
    __syncthreads();
    float tot = wsum[0] + wsum[1] + wsum[2] + wsum[3];
    float sc = rsqrtf(tot * (1.f / 1024.f) + 1e-6f);
    const float4 wv = *(const float4*)(w + d);
    __hip_bfloat16* op = out + (size_t)t * D_MODEL + d;
    op[0] = __float2bfloat16(h4.x * sc * wv.x);
    op[1] = __float2bfloat16(h4.y * sc * wv.y);
    op[2] = __float2bfloat16(h4.z * sc * wv.z);
    op[3] = __float2bfloat16(h4.w * sc * wv.w);
}

// ---------------------------------------------- m = silu(G) * U (bf16 in/out)
__global__ __launch_bounds__(256) void silu_mul_kernel(const __hip_bfloat16* __restrict__ GU,
                                                       __hip_bfloat16* __restrict__ m) {
    size_t i = (size_t)blockIdx.x * 256 + threadIdx.x;   // 2048*4096
    size_t t = i >> 12, j = i & 4095;
    float g = __bfloat162float(GU[t * 8192 + j]);
    float u = __bfloat162float(GU[t * 8192 + 4096 + j]);
    m[i] = __float2bfloat16(u * g / (1.f + expf(-g)));
}

// ----------------------------------------------------------- out += h
__global__ __launch_bounds__(256) void final_add_kernel(float* __restrict__ out,
                                                        const float* __restrict__ h) {
    size_t i = (size_t)blockIdx.x * 256 + threadIdx.x;
    out[i] += h[i];
}

// ---------------------------------------------------------------------------
extern "C" void kernel_launch(void* const* d_in, const int* in_sizes, int n_in,
                              void* d_out, int out_size, void* d_ws, size_t ws_size,
                              hipStream_t stream) {
    (void)in_sizes; (void)n_in; (void)out_size; (void)ws_size;
    const float* hidden     = (const float*)d_in[0];
    const float* norm1_w    = (const float*)d_in[1];
    const float* q_w        = (const float*)d_in[2];
    const float* k_w        = (const float*)d_in[3];
    const float* v_w        = (const float*)d_in[4];
    const float* g_w        = (const float*)d_in[5];
    const float* b_w        = (const float*)d_in[6];
    const float* gate_w     = (const float*)d_in[7];
    const float* o_norm_w   = (const float*)d_in[8];
    const float* o_w        = (const float*)d_in[9];
    const float* norm2_w    = (const float*)d_in[10];
    const float* mlp_gate_w = (const float*)d_in[11];
    const float* mlp_up_w   = (const float*)d_in[12];
    const float* mlp_down_w = (const float*)d_in[13];

    char* ws = (char*)d_ws;
    // workspace (~92 MiB), timeline-reused:
    const size_t OFF_WT_QKVG = 0;          // wt_qkvg_hi -> AcBuf
    const size_t OFF_WT_O    = 8650752;
    const size_t OFF_WT_GU   = 10747904;
    const size_t OFF_WT_DOWN = 27525120;
    const size_t OFF_X1      = 35913728;   // X1 f32 -> GU bf16
    const size_t OFF_R1      = 70516736;   // wt_qkvg_lo -> BcBuf -> mbf
    const size_t OFF_ATTN    = 79167488;   // UvWT_lo (A1/A2) -> attn_bf+ybf
    const size_t OFF_YBF     = 83361792;
    const size_t OFF_XHI     = 87556096;   // xhi/xlo -> UvWT_hi -> h_buf
    const size_t OFF_XLO     = 91750400;
    const size_t OFF_ROPE    = 95944704;

    __hip_bfloat16* wt_qkvg_hi = (__hip_bfloat16*)(ws + OFF_WT_QKVG);
    __hip_bfloat16* wt_qkvg_lo = (__hip_bfloat16*)(ws + OFF_R1);
    __hip_bfloat16* wt_o    = (__hip_bfloat16*)(ws + OFF_WT_O);
    __hip_bfloat16* wt_gu   = (__hip_bfloat16*)(ws + OFF_WT_GU);
    __hip_bfloat16* wt_down = (__hip_bfloat16*)(ws + OFF_WT_DOWN);
    float*          X1      = (float*)(ws + OFF_X1);
    __hip_bfloat16* GU      = (__hip_bfloat16*)(ws + OFF_X1);
    short*          AcBuf   = (short*)(ws + OFF_WT_QKVG);       // after qkv gemm
    float*          BcBuf   = (float*)(ws + OFF_R1);            // after qkv gemm
    __hip_bfloat16* mbf     = (__hip_bfloat16*)(ws + OFF_R1);   // after phase B/C
    __hip_bfloat16* attn_bf = (__hip_bfloat16*)(ws + OFF_ATTN);
    __hip_bfloat16* xhi     = (__hip_bfloat16*)(ws + OFF_XHI);
    __hip_bfloat16* xlo     = (__hip_bfloat16*)(ws + OFF_XLO);
    __hip_bfloat16* UvWT_hi = (__hip_bfloat16*)(ws + OFF_XHI);  // 8.39MB, after qkv gemm
    __hip_bfloat16* UvWT_lo = (__hip_bfloat16*)(ws + OFF_ATTN); // 8.39MB, until phaseC
    float*          h_buf   = (float*)(ws + OFF_XHI);           // after phaseA2
    __hip_bfloat16* ybf     = (__hip_bfloat16*)(ws + OFF_YBF);
    float2*         rope_cs = (float2*)(ws + OFF_ROPE);

    dim3 tb(32, 8);
    rope_table_kernel<<<256, 256, 0, stream>>>(rope_cs);
    rmsnorm_split_kernel<<<2048, 256, 0, stream>>>(hidden, norm1_w, xhi, xlo);
    transpose_split_kernel<<<dim3(32, 32), tb, 0, stream>>>(q_w,    wt_qkvg_hi,               wt_qkvg_lo,               1024, 1024, 1024);
    transpose_split_kernel<<<dim3(32, 32), tb, 0, stream>>>(k_w,    wt_qkvg_hi + 1024 * 1024, wt_qkvg_lo + 1024 * 1024, 1024, 1024, 1024);
    transpose_split_kernel<<<dim3(32, 32), tb, 0, stream>>>(v_w,    wt_qkvg_hi + 2048 * 1024, wt_qkvg_lo + 2048 * 1024, 1024, 1024, 1024);
    transpose_split_kernel<<<dim3(32, 32), tb, 0, stream>>>(gate_w, wt_qkvg_hi + 3072 * 1024, wt_qkvg_lo + 3072 * 1024, 1024, 1024, 1024);
    transpose_split_kernel<<<dim3(32, 1),  tb, 0, stream>>>(g_w,    wt_qkvg_hi + 4096 * 1024, wt_qkvg_lo + 4096 * 1024, 1024, 16,   16);
    transpose_split_kernel<<<dim3(32, 4),  tb, 0, stream>>>(b_w,    wt_qkvg_hi + 4112 * 1024, wt_qkvg_lo + 4112 * 1024, 1024, 16,   112);
    transpose_bf16_kernel<<<dim3(32, 32),  tb, 0, stream>>>(o_w,        wt_o,                1024, 1024, 1024);
    transpose_bf16_kernel<<<dim3(32, 128), tb, 0, stream>>>(mlp_gate_w, wt_gu,               1024, 4096, 4096);
    transpose_bf16_kernel<<<dim3(32, 128), tb, 0, stream>>>(mlp_up_w,   wt_gu + 4096 * 1024, 1024, 4096, 4096);
    transpose_bf16_kernel<<<dim3(128, 32), tb, 0, stream>>>(mlp_down_w, wt_down,             4096, 1024, 1024);
    // fused q|k|v|gate|g|b projection (split precision)
    gemm_bt_split<<<dim3(33, 16), 256, 0, stream>>>(xhi, xlo, wt_qkvg_hi, wt_qkvg_lo, X1, 2048, NQKV, 1024);
    rope_kernel<<<8192, 256, 0, stream>>>(X1, rope_cs);
    // chunked delta-rule scan
    phaseA1_kernel<<<512, 256, 0, stream>>>(X1, UvWT_hi, UvWT_lo);
    phaseA2_kernel<<<512, 256, 0, stream>>>(X1, UvWT_hi, UvWT_lo, AcBuf, BcBuf);
    phaseB_kernel<<<16, 256, 0, stream>>>(AcBuf, BcBuf, X1);
    phaseC_kernel<<<512, 256, 0, stream>>>(X1, o_norm_w, attn_bf);
    // attn out projection -> h (128x64 tiles: 256 blocks, full chip)
    gemm_bt_n64<false><<<dim3(16, 16), 256, 0, stream>>>(attn_bf, wt_o, h_buf, 2048, 1024, 1024);
    add_rmsnorm_kernel<<<2048, 256, 0, stream>>>(hidden, h_buf, norm2_w, ybf);
    gemm_bt<true><<<dim3(64, 16), 256, 0, stream>>>(ybf, wt_gu, GU, 2048, 8192, 1024);
    silu_mul_kernel<<<32768, 256, 0, stream>>>(GU, mbf);
    // down projection -> d_out (128x64 tiles)
    gemm_bt_n64<false><<<dim3(16, 16), 256, 0, stream>>>(mbf, wt_down, (float*)d_out, 2048, 1024, 4096);
    final_add_kernel<<<8192, 256, 0, stream>>>((float*)d_out, h_buf);
}